// Round 7
// baseline (616.748 us; speedup 1.0000x reference)
//
#include <hip/hip_runtime.h>

#define HIDDEN 1152
#define HEADS  16
#define HDIM   72
#define DPAD   96
#define NB     2
#define TT     4096
#define BT     (NB*TT)  // 8192

#define KSTR2  80      // Ks row stride (shorts): 10 granules of 8
#define VOFF   5120    // Vs offset inside KV buffer (shorts)

typedef float  f32x4   __attribute__((ext_vector_type(4)));
typedef __bf16 bf16x8  __attribute__((ext_vector_type(8)));

static __device__ __forceinline__ unsigned pkbf(float a, float b){
    unsigned r;
    asm("v_cvt_pk_bf16_f32 %0, %1, %2" : "=v"(r) : "v"(a), "v"(b));
    return r;
}
static __device__ __forceinline__ unsigned short f2b(float f){
    return (unsigned short)pkbf(f, f);
}
static __device__ __forceinline__ void gld16(const unsigned short* g, unsigned short* l){
    __builtin_amdgcn_global_load_lds((const __attribute__((address_space(1))) void*)g,
                                     (__attribute__((address_space(3))) void*)l, 16, 0, 0);
}

__global__ __launch_bounds__(256) void k_convert_x(const float* __restrict__ x, unsigned short* __restrict__ xb){
    int i = (blockIdx.x*256 + threadIdx.x) * 4;
    float4 v = *reinterpret_cast<const float4*>(x + i);
    uint2 p; p.x = pkbf(v.x, v.y); p.y = pkbf(v.z, v.w);
    *reinterpret_cast<uint2*>(xb + i) = p;
}

// tiled transpose+convert: w[k][n] (fp32) -> wt[n][k] (bf16)
__global__ __launch_bounds__(256) void k_wtrans(const float* __restrict__ w, unsigned short* __restrict__ wt){
    __shared__ __align__(16) unsigned short Ws[64][72];
    const int r0 = (blockIdx.x / 18) * 64, c0 = (blockIdx.x % 18) * 64;
    #pragma unroll
    for(int it=0; it<4; ++it){
        int idx = threadIdx.x + it*256;
        int r = idx >> 4, cq = (idx & 15) * 4;
        float4 v = *reinterpret_cast<const float4*>(w + (size_t)(r0+r)*HIDDEN + c0 + cq);
        uint2 p; p.x = pkbf(v.x, v.y); p.y = pkbf(v.z, v.w);
        *reinterpret_cast<uint2*>(&Ws[r][cq]) = p;
    }
    __syncthreads();
    #pragma unroll
    for(int it=0; it<4; ++it){
        int idx = threadIdx.x + it*256;
        int rr = idx >> 4, cq = (idx & 15) * 4;
        ushort4 o;
        o.x = Ws[cq+0][rr]; o.y = Ws[cq+1][rr]; o.z = Ws[cq+2][rr]; o.w = Ws[cq+3][rr];
        *reinterpret_cast<ushort4*>(wt + (size_t)(c0+rr)*HIDDEN + r0 + cq) = o;
    }
}

// MODE 0: Q -> [b][h][t][96] *scale; 1: K -> same; 2: V -> [b][h][96][t]; 3: fp32 out+bias
template<int MODE>
__global__ __launch_bounds__(256, 3) void k_gemm(const unsigned short* __restrict__ A,
                                                 const unsigned short* __restrict__ Bt,
                                                 const float* __restrict__ bias,
                                                 void* __restrict__ out, float scale){
    __shared__ __align__(16) unsigned short As[128*32];
    __shared__ __align__(16) unsigned short Bs[128*32];
    const int tid = threadIdx.x, lane = tid & 63, wid = tid >> 6;
    const int wm = wid >> 1, wn = wid & 1;
    const int half = lane >> 4, q16 = lane & 15;
    int lb = (blockIdx.x & 7) * 72 + (blockIdx.x >> 3);       // XCD-chunked swizzle (576 = 8*72)
    const int n0 = (lb % 9) * 128, m0 = (lb / 9) * 128;
    const int lr = lane >> 2, lc = (lane & 3) * 8;
    const unsigned short* ap = A  + (size_t)(m0 + wid*32 + lr)*HIDDEN + lc;
    const unsigned short* bp = Bt + (size_t)(n0 + wid*32 + lr)*HIDDEN + lc;
    unsigned short* as0 = As + (wid*32     )*32 + lane*8;
    unsigned short* as1 = As + (wid*32 + 16)*32 + lane*8;
    unsigned short* bs0 = Bs + (wid*32     )*32 + lane*8;
    unsigned short* bs1 = Bs + (wid*32 + 16)*32 + lane*8;

    f32x4 acc[4][4] = {};
    for(int k0 = 0; k0 < HIDDEN; k0 += 32){
        gld16(ap + k0,             as0);
        gld16(ap + k0 + 16*HIDDEN, as1);
        gld16(bp + k0,             bs0);
        gld16(bp + k0 + 16*HIDDEN, bs1);
        __syncthreads();
        bf16x8 af[4], bf[4];
        #pragma unroll
        for(int mi=0;mi<4;++mi) af[mi] = *reinterpret_cast<const bf16x8*>(As + (wm*64+mi*16+q16)*32 + half*8);
        #pragma unroll
        for(int ni=0;ni<4;++ni) bf[ni] = *reinterpret_cast<const bf16x8*>(Bs + (wn*64+ni*16+q16)*32 + half*8);
        #pragma unroll
        for(int mi=0;mi<4;++mi)
            #pragma unroll
            for(int ni=0;ni<4;++ni)
                acc[mi][ni] = __builtin_amdgcn_mfma_f32_16x16x32_bf16(af[mi], bf[ni], acc[mi][ni], 0,0,0);
        __syncthreads();
    }
    #pragma unroll
    for(int mi=0;mi<4;++mi)
        #pragma unroll
        for(int ni=0;ni<4;++ni)
            #pragma unroll
            for(int j=0;j<4;++j){
                int row = m0 + wm*64 + mi*16 + half*4 + j;   // token index
                int col = n0 + wn*64 + ni*16 + q16;          // output feature
                float v = acc[mi][ni][j] + bias[col];
                if(MODE==0) v *= scale;
                if(MODE==0 || MODE==1){
                    int bb = row >> 12, t = row & 4095;
                    int hh = col / HDIM, d = col % HDIM;
                    ((unsigned short*)out)[((size_t)((bb*HEADS + hh)*TT) + t)*DPAD + d] = f2b(v);
                } else if(MODE==2){
                    int bb = row >> 12, t = row & 4095;
                    int hh = col / HDIM, d = col % HDIM;
                    ((unsigned short*)out)[((size_t)((bb*HEADS + hh)*DPAD) + d)*TT + t] = f2b(v);
                } else {
                    ((float*)out)[(size_t)row*HIDDEN + col] = v;
                }
            }
}

// flash attention: swapped QK^T 16x16 core, async-staged double-buffered K/V (1 barrier/iter),
// pure-XOR conflict-free LDS layouts, defer-max, 128 q-rows/block.
__global__ __launch_bounds__(256, 3) void k_attn(const unsigned short* __restrict__ Qp,
                                                 const unsigned short* __restrict__ Kp,
                                                 const unsigned short* __restrict__ Vt,
                                                 unsigned short* __restrict__ AO){
    __shared__ __align__(16) unsigned short KV[2][10240];   // [K 64x80 | V 80x64] per buf = 40 KB
    __shared__ __align__(16) unsigned int   PsT[4][512];    // per-wave P^T: 16 q-rows x 32 dwords, XOR-swz
    __shared__ __align__(16) unsigned short Zs[16];         // zero granules (kk=2, g>=2)
    const int tid  = threadIdx.x;
    const int lane = tid & 63, wid = tid >> 6;
    const int g    = lane >> 4, q16 = lane & 15;
    const int sw7  = q16 & 7;

    int lb = ((blockIdx.x & 7) << 7) | (blockIdx.x >> 3);   // XCD-chunked (1024 = 8*128)
    const int qt = lb & 31, h = (lb >> 5) & 15, b = lb >> 9;
    const int qbase = qt * 128;
    const int bh = b*HEADS + h;

    const unsigned short* kbase = Kp + (size_t)(bh*TT) * DPAD;
    const unsigned short* vbase = Vt + (size_t)(bh*DPAD) * TT;

    // per-thread staging slots (loop-invariant): 640 K chunks + 640 V chunks of 16B
    const unsigned short* gp[5]; int lo[5], adv[5];
    #pragma unroll
    for(int i=0;i<5;++i){
        int c = tid + i*256;
        if(c < 640){
            int r = c/10, ch = c - r*10;
            int phys = (ch < 8) ? (ch ^ (r&7)) : (8 + ((ch&1) ^ (r&1)));
            lo[i]  = r*KSTR2 + (phys<<3);
            gp[i]  = kbase + (size_t)r*DPAD + ch*8;
            adv[i] = 64*DPAD;
        } else {
            int c2 = c - 640, d = c2>>3, ch = c2&7;
            lo[i]  = VOFF + d*64 + ((ch ^ (d&7))<<3);
            gp[i]  = vbase + (size_t)d*TT + ch*8;
            adv[i] = 64;
        }
    }
    if(tid < 2){ uint4 z = {0,0,0,0}; reinterpret_cast<uint4*>(Zs)[tid] = z; }

    // Q fragments: 2 q-subtiles x 16 rows; B-operand row q=q16, k-slot g*8+e -> d = kk*32+g*8+e
    bf16x8 qf[2][3];
    #pragma unroll
    for(int u=0;u<2;++u){
        const unsigned short* qptr = Qp + ((size_t)(bh*TT) + qbase + u*64 + wid*16 + q16) * DPAD;
        #pragma unroll
        for(int kk=0;kk<3;++kk) qf[u][kk] = *reinterpret_cast<const bf16x8*>(qptr + kk*32 + g*8);
    }

    f32x4 accO[2][5] = {};
    float m[2] = {-1e30f, -1e30f};
    float l[2] = {0.f, 0.f};

    // prologue: stage tile 0 into buf 0
    uint4 stg[5];
    #pragma unroll
    for(int i=0;i<5;++i) stg[i] = *reinterpret_cast<const uint4*>(gp[i]);
    #pragma unroll
    for(int i=0;i<5;++i){ *reinterpret_cast<uint4*>(&KV[0][lo[i]]) = stg[i]; gp[i] += adv[i]; }
    __syncthreads();

    for(int kt = 0; kt < 64; ++kt){
        const int cur = kt & 1;
        if(kt < 63){
            #pragma unroll
            for(int i=0;i<5;++i) stg[i] = *reinterpret_cast<const uint4*>(gp[i]);   // issue early
        }
        const unsigned short* Kb = KV[cur];
        const unsigned short* Vb = KV[cur] + VOFF;

        // S^T[kv][q] = mfma(A=K, B=Q): lane holds col q=q16, rows kv = 16t + 4g + j
        f32x4 s[2][4] = {};
        #pragma unroll
        for(int t=0;t<4;++t){
            const int row = t*16 + q16;
            bf16x8 kf0 = *reinterpret_cast<const bf16x8*>(&Kb[row*KSTR2 + ((g        ^ sw7)<<3)]);
            bf16x8 kf1 = *reinterpret_cast<const bf16x8*>(&Kb[row*KSTR2 + (((4+g)    ^ sw7)<<3)]);
            const unsigned short* k2p = (g < 2) ? &Kb[row*KSTR2 + ((8 + (g ^ (row&1)))<<3)]
                                                : &Zs[(g&1)<<3];
            bf16x8 kf2 = *reinterpret_cast<const bf16x8*>(k2p);
            s[0][t] = __builtin_amdgcn_mfma_f32_16x16x32_bf16(kf0, qf[0][0], s[0][t], 0,0,0);
            s[1][t] = __builtin_amdgcn_mfma_f32_16x16x32_bf16(kf0, qf[1][0], s[1][t], 0,0,0);
            s[0][t] = __builtin_amdgcn_mfma_f32_16x16x32_bf16(kf1, qf[0][1], s[0][t], 0,0,0);
            s[1][t] = __builtin_amdgcn_mfma_f32_16x16x32_bf16(kf1, qf[1][1], s[1][t], 0,0,0);
            s[0][t] = __builtin_amdgcn_mfma_f32_16x16x32_bf16(kf2, qf[0][2], s[0][t], 0,0,0);
            s[1][t] = __builtin_amdgcn_mfma_f32_16x16x32_bf16(kf2, qf[1][2], s[1][t], 0,0,0);
        }

        #pragma unroll
        for(int u=0;u<2;++u){
            float t0 = fmaxf(fmaxf(s[u][0][0],s[u][0][1]), fmaxf(s[u][0][2],s[u][0][3]));
            float t1 = fmaxf(fmaxf(s[u][1][0],s[u][1][1]), fmaxf(s[u][1][2],s[u][1][3]));
            float t2 = fmaxf(fmaxf(s[u][2][0],s[u][2][1]), fmaxf(s[u][2][2],s[u][2][3]));
            float t3 = fmaxf(fmaxf(s[u][3][0],s[u][3][1]), fmaxf(s[u][3][2],s[u][3][3]));
            float tm = fmaxf(fmaxf(t0,t1), fmaxf(t2,t3));
            tm = fmaxf(tm, __shfl_xor(tm, 16, 64));
            tm = fmaxf(tm, __shfl_xor(tm, 32, 64));
            if(__any(tm > m[u] + 8.0f)){                       // defer-max rescale (log2 domain)
                float mn = fmaxf(m[u], tm);
                float al = __builtin_amdgcn_exp2f(m[u] - mn);
                l[u] *= al;  m[u] = mn;
                float aj[4];
                #pragma unroll
                for(int j=0;j<4;++j) aj[j] = __shfl(al, (lane & 48) | (4*g + j), 64);
                #pragma unroll
                for(int nt=0;nt<5;++nt)
                    #pragma unroll
                    for(int j=0;j<4;++j) accO[u][nt][j] *= aj[j];
            }
            // P = exp2(S-m); kv-linear P^T row q16: dword D = 8t+2g(+1); granule gi=D>>2 at gi^sw7
            float sum = 0.f;
            #pragma unroll
            for(int t4=0;t4<4;++t4){
                float p0 = __builtin_amdgcn_exp2f(s[u][t4][0] - m[u]);
                float p1 = __builtin_amdgcn_exp2f(s[u][t4][1] - m[u]);
                float p2 = __builtin_amdgcn_exp2f(s[u][t4][2] - m[u]);
                float p3 = __builtin_amdgcn_exp2f(s[u][t4][3] - m[u]);
                sum += (p0 + p1) + (p2 + p3);
                uint2 w; w.x = pkbf(p0, p1); w.y = pkbf(p2, p3);
                int gi = 2*t4 + (g>>1);
                *reinterpret_cast<uint2*>(&PsT[wid][q16*32 + ((gi ^ sw7)<<2) + 2*(g&1)]) = w;
            }
            sum += __shfl_xor(sum, 16, 64);
            sum += __shfl_xor(sum, 32, 64);
            l[u] += sum;

            // PV: A = P[q][kv] (granule 4kh+g at (4kh+g)^sw7), B = V^T[d][kv]
            #pragma unroll
            for(int kh=0; kh<2; ++kh){
                bf16x8 pf = *reinterpret_cast<const bf16x8*>(&PsT[wid][q16*32 + (((4*kh+g) ^ sw7)<<2)]);
                #pragma unroll
                for(int nt=0; nt<5; ++nt){
                    bf16x8 vf = *reinterpret_cast<const bf16x8*>(&Vb[(nt*16+q16)*64 + (((kh*4+g) ^ sw7)<<3)]);
                    accO[u][nt] = __builtin_amdgcn_mfma_f32_16x16x32_bf16(pf, vf, accO[u][nt], 0,0,0);
                }
            }
        }

        if(kt < 63){
            #pragma unroll
            for(int i=0;i<5;++i){ *reinterpret_cast<uint4*>(&KV[cur^1][lo[i]]) = stg[i]; gp[i] += adv[i]; }
        }
        __syncthreads();
    }

    // epilogue: accO row q' = 4g+j needs l of q' (lives at lanes with lane&15 = q')
    #pragma unroll
    for(int u=0;u<2;++u){
        float linv[4];
        #pragma unroll
        for(int j=0;j<4;++j){
            float lj = __shfl(l[u], (lane & 48) | (4*g + j), 64);
            linv[j] = 1.0f / lj;
        }
        #pragma unroll
        for(int nt=0;nt<5;++nt){
            int d = nt*16 + q16;
            if(d < HDIM){
                #pragma unroll
                for(int j=0;j<4;++j){
                    int t = qbase + u*64 + wid*16 + 4*g + j;
                    AO[((size_t)(b*TT + t))*HIDDEN + h*HDIM + d] = f2b(accO[u][nt][j] * linv[j]);
                }
            }
        }
    }
}

extern "C" void kernel_launch(void* const* d_in, const int* in_sizes, int n_in,
                              void* d_out, int out_size, void* d_ws, size_t ws_size,
                              hipStream_t stream) {
    const float* x  = (const float*)d_in[0];
    const float* wq = (const float*)d_in[1];
    const float* bq = (const float*)d_in[2];
    const float* wk = (const float*)d_in[3];
    const float* bk = (const float*)d_in[4];
    const float* wv = (const float*)d_in[5];
    const float* bv = (const float*)d_in[6];
    const float* wo = (const float*)d_in[7];
    const float* bo = (const float*)d_in[8];

    char* ws = (char*)d_ws;
    const size_t szXb = (size_t)BT*HIDDEN*2;          // 18874368
    const size_t szW  = (size_t)HIDDEN*HIDDEN*2;      // 2654208
    const size_t szQp = (size_t)NB*HEADS*TT*DPAD*2;   // 25165824

    unsigned short* Xb  = (unsigned short*)(ws);
    unsigned short* WTq = (unsigned short*)(ws + szXb);
    unsigned short* WTk = (unsigned short*)(ws + szXb + szW);
    unsigned short* WTv = (unsigned short*)(ws + szXb + 2*szW);
    unsigned short* WTo = (unsigned short*)(ws + szXb + 3*szW);
    unsigned short* Qp  = (unsigned short*)(ws + szXb + 4*szW);
    unsigned short* Kp  = (unsigned short*)(ws + szXb + 4*szW + szQp);
    unsigned short* Vt  = (unsigned short*)(ws + szXb + 4*szW + 2*szQp);
    unsigned short* AO  = (unsigned short*)(ws + szXb + 4*szW + 3*szQp);

    hipMemsetAsync(Qp, 0, 3*szQp, stream);            // zero d-padding of Q, K, V (contiguous)

    k_convert_x<<<BT*HIDDEN/1024, 256, 0, stream>>>(x, Xb);
    k_wtrans<<<324, 256, 0, stream>>>(wq, WTq);
    k_wtrans<<<324, 256, 0, stream>>>(wk, WTk);
    k_wtrans<<<324, 256, 0, stream>>>(wv, WTv);
    k_wtrans<<<324, 256, 0, stream>>>(wo, WTo);

    const float qscale = (1.0f / sqrtf(72.0f)) * 1.44269504f;  // fold log2(e) for exp2 softmax
    k_gemm<0><<<576, 256, 0, stream>>>(Xb, WTq, bq, Qp, qscale);
    k_gemm<1><<<576, 256, 0, stream>>>(Xb, WTk, bk, Kp, 1.0f);
    k_gemm<2><<<576, 256, 0, stream>>>(Xb, WTv, bv, Vt, 1.0f);

    k_attn<<<NB*HEADS*(TT/128), 256, 0, stream>>>(Qp, Kp, Vt, AO);

    k_gemm<3><<<576, 256, 0, stream>>>(AO, WTo, bo, d_out, 1.0f);
}

// Round 9
// 447.361 us; speedup vs baseline: 1.3786x; 1.3786x over previous
//
#include <hip/hip_runtime.h>

#define HIDDEN 1152
#define HEADS  16
#define HDIM   72
#define DPAD   96
#define NB     2
#define TT     4096
#define BT     (NB*TT)  // 8192

#define KSTR2  80      // Ks row stride (shorts): 10 granules of 8
#define VOFF   5120    // Vs offset inside KV buffer (shorts)

typedef float  f32x4   __attribute__((ext_vector_type(4)));
typedef __bf16 bf16x8  __attribute__((ext_vector_type(8)));
typedef unsigned u32x4 __attribute__((ext_vector_type(4)));

static __device__ __forceinline__ unsigned pkbf(float a, float b){
    unsigned r;
    asm("v_cvt_pk_bf16_f32 %0, %1, %2" : "=v"(r) : "v"(a), "v"(b));
    return r;
}
static __device__ __forceinline__ unsigned short f2b(float f){
    return (unsigned short)pkbf(f, f);
}
static __device__ __forceinline__ void gld16(const unsigned short* g, unsigned short* l){
    __builtin_amdgcn_global_load_lds((const __attribute__((address_space(1))) void*)g,
                                     (__attribute__((address_space(3))) void*)l, 16, 0, 0);
}

__global__ __launch_bounds__(256) void k_convert_x(const float* __restrict__ x, unsigned short* __restrict__ xb){
    int i = (blockIdx.x*256 + threadIdx.x) * 4;
    float4 v = *reinterpret_cast<const float4*>(x + i);
    uint2 p; p.x = pkbf(v.x, v.y); p.y = pkbf(v.z, v.w);
    *reinterpret_cast<uint2*>(xb + i) = p;
}

// tiled transpose+convert: w[k][n] (fp32) -> wt[n][k] (bf16)
__global__ __launch_bounds__(256) void k_wtrans(const float* __restrict__ w, unsigned short* __restrict__ wt){
    __shared__ __align__(16) unsigned short Ws[64][72];
    const int r0 = (blockIdx.x / 18) * 64, c0 = (blockIdx.x % 18) * 64;
    #pragma unroll
    for(int it=0; it<4; ++it){
        int idx = threadIdx.x + it*256;
        int r = idx >> 4, cq = (idx & 15) * 4;
        float4 v = *reinterpret_cast<const float4*>(w + (size_t)(r0+r)*HIDDEN + c0 + cq);
        uint2 p; p.x = pkbf(v.x, v.y); p.y = pkbf(v.z, v.w);
        *reinterpret_cast<uint2*>(&Ws[r][cq]) = p;
    }
    __syncthreads();
    #pragma unroll
    for(int it=0; it<4; ++it){
        int idx = threadIdx.x + it*256;
        int rr = idx >> 4, cq = (idx & 15) * 4;
        ushort4 o;
        o.x = Ws[cq+0][rr]; o.y = Ws[cq+1][rr]; o.z = Ws[cq+2][rr]; o.w = Ws[cq+3][rr];
        *reinterpret_cast<ushort4*>(wt + (size_t)(c0+rr)*HIDDEN + r0 + cq) = o;
    }
}

// MODE 0: Q -> [b][h][t][96] *scale; 1: K -> same; 2: V -> [b][h][96][t]; 3: fp32 out+bias
template<int MODE>
__global__ __launch_bounds__(256, 3) void k_gemm(const unsigned short* __restrict__ A,
                                                 const unsigned short* __restrict__ Bt,
                                                 const float* __restrict__ bias,
                                                 void* __restrict__ out, float scale){
    __shared__ __align__(16) unsigned short As[128*32];
    __shared__ __align__(16) unsigned short Bs[128*32];
    const int tid = threadIdx.x, lane = tid & 63, wid = tid >> 6;
    const int wm = wid >> 1, wn = wid & 1;
    const int half = lane >> 4, q16 = lane & 15;
    int lb = (blockIdx.x & 7) * 72 + (blockIdx.x >> 3);       // XCD-chunked swizzle (576 = 8*72)
    const int n0 = (lb % 9) * 128, m0 = (lb / 9) * 128;
    const int lr = lane >> 2, lc = (lane & 3) * 8;
    const unsigned short* ap = A  + (size_t)(m0 + wid*32 + lr)*HIDDEN + lc;
    const unsigned short* bp = Bt + (size_t)(n0 + wid*32 + lr)*HIDDEN + lc;
    unsigned short* as0 = As + (wid*32     )*32 + lane*8;
    unsigned short* as1 = As + (wid*32 + 16)*32 + lane*8;
    unsigned short* bs0 = Bs + (wid*32     )*32 + lane*8;
    unsigned short* bs1 = Bs + (wid*32 + 16)*32 + lane*8;

    f32x4 acc[4][4] = {};
    for(int k0 = 0; k0 < HIDDEN; k0 += 32){
        gld16(ap + k0,             as0);
        gld16(ap + k0 + 16*HIDDEN, as1);
        gld16(bp + k0,             bs0);
        gld16(bp + k0 + 16*HIDDEN, bs1);
        __syncthreads();
        bf16x8 af[4], bf[4];
        #pragma unroll
        for(int mi=0;mi<4;++mi) af[mi] = *reinterpret_cast<const bf16x8*>(As + (wm*64+mi*16+q16)*32 + half*8);
        #pragma unroll
        for(int ni=0;ni<4;++ni) bf[ni] = *reinterpret_cast<const bf16x8*>(Bs + (wn*64+ni*16+q16)*32 + half*8);
        #pragma unroll
        for(int mi=0;mi<4;++mi)
            #pragma unroll
            for(int ni=0;ni<4;++ni)
                acc[mi][ni] = __builtin_amdgcn_mfma_f32_16x16x32_bf16(af[mi], bf[ni], acc[mi][ni], 0,0,0);
        __syncthreads();
    }
    #pragma unroll
    for(int mi=0;mi<4;++mi)
        #pragma unroll
        for(int ni=0;ni<4;++ni)
            #pragma unroll
            for(int j=0;j<4;++j){
                int row = m0 + wm*64 + mi*16 + half*4 + j;   // token index
                int col = n0 + wn*64 + ni*16 + q16;          // output feature
                float v = acc[mi][ni][j] + bias[col];
                if(MODE==0) v *= scale;
                if(MODE==0 || MODE==1){
                    int bb = row >> 12, t = row & 4095;
                    int hh = col / HDIM, d = col % HDIM;
                    ((unsigned short*)out)[((size_t)((bb*HEADS + hh)*TT) + t)*DPAD + d] = f2b(v);
                } else if(MODE==2){
                    int bb = row >> 12, t = row & 4095;
                    int hh = col / HDIM, d = col % HDIM;
                    ((unsigned short*)out)[((size_t)((bb*HEADS + hh)*DPAD) + d)*TT + t] = f2b(v);
                } else {
                    ((float*)out)[(size_t)row*HIDDEN + col] = v;
                }
            }
}

// flash attention: swapped QK^T 16x16 core, double-buffered K/V with INLINE-ASM pinned
// early-issue loads (T14 async-STAGE split), late vmcnt(0)+ds_write, 1 barrier/iter.
__global__ __launch_bounds__(256, 3) void k_attn(const unsigned short* __restrict__ Qp,
                                                 const unsigned short* __restrict__ Kp,
                                                 const unsigned short* __restrict__ Vt,
                                                 unsigned short* __restrict__ AO){
    __shared__ __align__(16) unsigned short KV[2][10240];   // [K 64x80 | V 80x64] per buf = 40 KB
    __shared__ __align__(16) unsigned int   PsT[4][512];    // per-wave P^T: 16 q-rows x 32 dwords, XOR-swz
    __shared__ __align__(16) unsigned short Zs[16];         // zero granules (kk=2, g>=2)
    const int tid  = threadIdx.x;
    const int lane = tid & 63, wid = tid >> 6;
    const int g    = lane >> 4, q16 = lane & 15;
    const int sw7  = q16 & 7;

    int lb = ((blockIdx.x & 7) << 7) | (blockIdx.x >> 3);   // XCD-chunked (1024 = 8*128)
    const int qt = lb & 31, h = (lb >> 5) & 15, b = lb >> 9;
    const int qbase = qt * 128;
    const int bh = b*HEADS + h;

    const unsigned short* kbase = Kp + (size_t)(bh*TT) * DPAD;
    const unsigned short* vbase = Vt + (size_t)(bh*DPAD) * TT;

    // per-thread staging slots (loop-invariant): 640 K chunks + 640 V chunks of 16B
    const unsigned short* gp[5]; int lo[5], adv[5];
    #pragma unroll
    for(int i=0;i<5;++i){
        int c = tid + i*256;
        if(c < 640){
            int r = c/10, ch = c - r*10;
            int phys = (ch < 8) ? (ch ^ (r&7)) : (8 + ((ch&1) ^ (r&1)));
            lo[i]  = r*KSTR2 + (phys<<3);
            gp[i]  = kbase + (size_t)r*DPAD + ch*8;
            adv[i] = 64*DPAD;
        } else {
            int c2 = c - 640, d = c2>>3, ch = c2&7;
            lo[i]  = VOFF + d*64 + ((ch ^ (d&7))<<3);
            gp[i]  = vbase + (size_t)d*TT + ch*8;
            adv[i] = 64;
        }
    }
    if(tid < 2){ uint4 z = {0,0,0,0}; reinterpret_cast<uint4*>(Zs)[tid] = z; }

    // Q fragments: 2 q-subtiles x 16 rows; B-operand row q=q16, k-slot g*8+e -> d = kk*32+g*8+e
    bf16x8 qf[2][3];
    #pragma unroll
    for(int u=0;u<2;++u){
        const unsigned short* qptr = Qp + ((size_t)(bh*TT) + qbase + u*64 + wid*16 + q16) * DPAD;
        #pragma unroll
        for(int kk=0;kk<3;++kk) qf[u][kk] = *reinterpret_cast<const bf16x8*>(qptr + kk*32 + g*8);
    }

    f32x4 accO[2][5] = {};
    float m[2] = {-1e30f, -1e30f};
    float l[2] = {0.f, 0.f};

    // prologue: stage tile 0 into buf 0 (plain loads; compiler-managed waitcnt)
    u32x4 stg[5];
    #pragma unroll
    for(int i=0;i<5;++i) stg[i] = *reinterpret_cast<const u32x4*>(gp[i]);
    #pragma unroll
    for(int i=0;i<5;++i){ *reinterpret_cast<u32x4*>(&KV[0][lo[i]]) = stg[i]; gp[i] += adv[i]; }
    __syncthreads();

    for(int kt = 0; kt < 64; ++kt){
        const int cur = kt & 1;
        if(kt < 63){
            // pinned early issue: volatile asm cannot be sunk; "memory" orders before compute ds_reads
            #pragma unroll
            for(int i=0;i<5;++i)
                asm volatile("global_load_dwordx4 %0, %1, off"
                             : "=v"(stg[i]) : "v"(gp[i]) : "memory");
        }
        const unsigned short* Kb = KV[cur];
        const unsigned short* Vb = KV[cur] + VOFF;

        // S^T[kv][q] = mfma(A=K, B=Q): lane holds col q=q16, rows kv = 16t + 4g + j
        f32x4 s[2][4] = {};
        #pragma unroll
        for(int t=0;t<4;++t){
            const int row = t*16 + q16;
            bf16x8 kf0 = *reinterpret_cast<const bf16x8*>(&Kb[row*KSTR2 + ((g        ^ sw7)<<3)]);
            bf16x8 kf1 = *reinterpret_cast<const bf16x8*>(&Kb[row*KSTR2 + (((4+g)    ^ sw7)<<3)]);
            const unsigned short* k2p = (g < 2) ? &Kb[row*KSTR2 + ((8 + (g ^ (row&1)))<<3)]
                                                : &Zs[(g&1)<<3];
            bf16x8 kf2 = *reinterpret_cast<const bf16x8*>(k2p);
            s[0][t] = __builtin_amdgcn_mfma_f32_16x16x32_bf16(kf0, qf[0][0], s[0][t], 0,0,0);
            s[1][t] = __builtin_amdgcn_mfma_f32_16x16x32_bf16(kf0, qf[1][0], s[1][t], 0,0,0);
            s[0][t] = __builtin_amdgcn_mfma_f32_16x16x32_bf16(kf1, qf[0][1], s[0][t], 0,0,0);
            s[1][t] = __builtin_amdgcn_mfma_f32_16x16x32_bf16(kf1, qf[1][1], s[1][t], 0,0,0);
            s[0][t] = __builtin_amdgcn_mfma_f32_16x16x32_bf16(kf2, qf[0][2], s[0][t], 0,0,0);
            s[1][t] = __builtin_amdgcn_mfma_f32_16x16x32_bf16(kf2, qf[1][2], s[1][t], 0,0,0);
        }

        #pragma unroll
        for(int u=0;u<2;++u){
            float t0 = fmaxf(fmaxf(s[u][0][0],s[u][0][1]), fmaxf(s[u][0][2],s[u][0][3]));
            float t1 = fmaxf(fmaxf(s[u][1][0],s[u][1][1]), fmaxf(s[u][1][2],s[u][1][3]));
            float t2 = fmaxf(fmaxf(s[u][2][0],s[u][2][1]), fmaxf(s[u][2][2],s[u][2][3]));
            float t3 = fmaxf(fmaxf(s[u][3][0],s[u][3][1]), fmaxf(s[u][3][2],s[u][3][3]));
            float tm = fmaxf(fmaxf(t0,t1), fmaxf(t2,t3));
            tm = fmaxf(tm, __shfl_xor(tm, 16, 64));
            tm = fmaxf(tm, __shfl_xor(tm, 32, 64));
            if(__any(tm > m[u] + 8.0f)){                       // defer-max rescale (log2 domain)
                float mn = fmaxf(m[u], tm);
                float al = __builtin_amdgcn_exp2f(m[u] - mn);
                l[u] *= al;  m[u] = mn;
                float aj[4];
                #pragma unroll
                for(int j=0;j<4;++j) aj[j] = __shfl(al, (lane & 48) | (4*g + j), 64);
                #pragma unroll
                for(int nt=0;nt<5;++nt)
                    #pragma unroll
                    for(int j=0;j<4;++j) accO[u][nt][j] *= aj[j];
            }
            // P = exp2(S-m); kv-linear P^T row q16: dword D = 8t+2g(+1); granule gi=D>>2 at gi^sw7
            float sum = 0.f;
            #pragma unroll
            for(int t4=0;t4<4;++t4){
                float p0 = __builtin_amdgcn_exp2f(s[u][t4][0] - m[u]);
                float p1 = __builtin_amdgcn_exp2f(s[u][t4][1] - m[u]);
                float p2 = __builtin_amdgcn_exp2f(s[u][t4][2] - m[u]);
                float p3 = __builtin_amdgcn_exp2f(s[u][t4][3] - m[u]);
                sum += (p0 + p1) + (p2 + p3);
                uint2 w; w.x = pkbf(p0, p1); w.y = pkbf(p2, p3);
                int gi = 2*t4 + (g>>1);
                *reinterpret_cast<uint2*>(&PsT[wid][q16*32 + ((gi ^ sw7)<<2) + 2*(g&1)]) = w;
            }
            sum += __shfl_xor(sum, 16, 64);
            sum += __shfl_xor(sum, 32, 64);
            l[u] += sum;

            // PV: A = P[q][kv] (granule 4kh+g at (4kh+g)^sw7), B = V^T[d][kv]
            #pragma unroll
            for(int kh=0; kh<2; ++kh){
                bf16x8 pf = *reinterpret_cast<const bf16x8*>(&PsT[wid][q16*32 + (((4*kh+g) ^ sw7)<<2)]);
                #pragma unroll
                for(int nt=0; nt<5; ++nt){
                    bf16x8 vf = *reinterpret_cast<const bf16x8*>(&Vb[(nt*16+q16)*64 + (((kh*4+g) ^ sw7)<<3)]);
                    accO[u][nt] = __builtin_amdgcn_mfma_f32_16x16x32_bf16(pf, vf, accO[u][nt], 0,0,0);
                }
            }
        }

        if(kt < 63){
            // late write-back: wait for the pinned loads (issued ~1100 cyc ago), then ds_write
            asm volatile("s_waitcnt vmcnt(0)" ::: "memory");
            __builtin_amdgcn_sched_barrier(0);
            #pragma unroll
            for(int i=0;i<5;++i){ *reinterpret_cast<u32x4*>(&KV[cur^1][lo[i]]) = stg[i]; gp[i] += adv[i]; }
        }
        __syncthreads();
    }

    // epilogue: accO row q' = 4g+j needs l of q' (lives at lanes with lane&15 = q')
    #pragma unroll
    for(int u=0;u<2;++u){
        float linv[4];
        #pragma unroll
        for(int j=0;j<4;++j){
            float lj = __shfl(l[u], (lane & 48) | (4*g + j), 64);
            linv[j] = 1.0f / lj;
        }
        #pragma unroll
        for(int nt=0;nt<5;++nt){
            int d = nt*16 + q16;
            if(d < HDIM){
                #pragma unroll
                for(int j=0;j<4;++j){
                    int t = qbase + u*64 + wid*16 + 4*g + j;
                    AO[((size_t)(b*TT + t))*HIDDEN + h*HDIM + d] = f2b(accO[u][nt][j] * linv[j]);
                }
            }
        }
    }
}

extern "C" void kernel_launch(void* const* d_in, const int* in_sizes, int n_in,
                              void* d_out, int out_size, void* d_ws, size_t ws_size,
                              hipStream_t stream) {
    const float* x  = (const float*)d_in[0];
    const float* wq = (const float*)d_in[1];
    const float* bq = (const float*)d_in[2];
    const float* wk = (const float*)d_in[3];
    const float* bk = (const float*)d_in[4];
    const float* wv = (const float*)d_in[5];
    const float* bv = (const float*)d_in[6];
    const float* wo = (const float*)d_in[7];
    const float* bo = (const float*)d_in[8];

    char* ws = (char*)d_ws;
    const size_t szXb = (size_t)BT*HIDDEN*2;          // 18874368
    const size_t szW  = (size_t)HIDDEN*HIDDEN*2;      // 2654208
    const size_t szQp = (size_t)NB*HEADS*TT*DPAD*2;   // 25165824

    unsigned short* Xb  = (unsigned short*)(ws);
    unsigned short* WTq = (unsigned short*)(ws + szXb);
    unsigned short* WTk = (unsigned short*)(ws + szXb + szW);
    unsigned short* WTv = (unsigned short*)(ws + szXb + 2*szW);
    unsigned short* WTo = (unsigned short*)(ws + szXb + 3*szW);
    unsigned short* Qp  = (unsigned short*)(ws + szXb + 4*szW);
    unsigned short* Kp  = (unsigned short*)(ws + szXb + 4*szW + szQp);
    unsigned short* Vt  = (unsigned short*)(ws + szXb + 4*szW + 2*szQp);
    unsigned short* AO  = (unsigned short*)(ws + szXb + 4*szW + 3*szQp);

    hipMemsetAsync(Qp, 0, 3*szQp, stream);            // zero d-padding of Q, K, V (contiguous)

    k_convert_x<<<BT*HIDDEN/1024, 256, 0, stream>>>(x, Xb);
    k_wtrans<<<324, 256, 0, stream>>>(wq, WTq);
    k_wtrans<<<324, 256, 0, stream>>>(wk, WTk);
    k_wtrans<<<324, 256, 0, stream>>>(wv, WTv);
    k_wtrans<<<324, 256, 0, stream>>>(wo, WTo);

    const float qscale = (1.0f / sqrtf(72.0f)) * 1.44269504f;  // fold log2(e) for exp2 softmax
    k_gemm<0><<<576, 256, 0, stream>>>(Xb, WTq, bq, Qp, qscale);
    k_gemm<1><<<576, 256, 0, stream>>>(Xb, WTk, bk, Kp, 1.0f);
    k_gemm<2><<<576, 256, 0, stream>>>(Xb, WTv, bv, Vt, 1.0f);

    k_attn<<<NB*HEADS*(TT/128), 256, 0, stream>>>(Qp, Kp, Vt, AO);

    k_gemm<3><<<576, 256, 0, stream>>>(AO, WTo, bo, d_out, 1.0f);
}

// Round 10
// 426.793 us; speedup vs baseline: 1.4451x; 1.0482x over previous
//
#include <hip/hip_runtime.h>

#define HIDDEN 1152
#define HEADS  16
#define HDIM   72
#define DPAD   96
#define NB     2
#define TT     4096
#define BT     (NB*TT)  // 8192

#define KSTR2  80      // Ks row stride (shorts): 10 granules of 8
#define VOFF   5120    // Vs offset inside KV buffer (shorts)

typedef float  f32x4   __attribute__((ext_vector_type(4)));
typedef __bf16 bf16x8  __attribute__((ext_vector_type(8)));
typedef unsigned u32x4 __attribute__((ext_vector_type(4)));

static __device__ __forceinline__ unsigned pkbf(float a, float b){
    unsigned r;
    asm("v_cvt_pk_bf16_f32 %0, %1, %2" : "=v"(r) : "v"(a), "v"(b));
    return r;
}
static __device__ __forceinline__ unsigned short f2b(float f){
    return (unsigned short)pkbf(f, f);
}
static __device__ __forceinline__ void gld16(const unsigned short* g, unsigned short* l){
    __builtin_amdgcn_global_load_lds((const __attribute__((address_space(1))) void*)g,
                                     (__attribute__((address_space(3))) void*)l, 16, 0, 0);
}

__global__ __launch_bounds__(256) void k_convert_x(const float* __restrict__ x, unsigned short* __restrict__ xb){
    int i = (blockIdx.x*256 + threadIdx.x) * 4;
    float4 v = *reinterpret_cast<const float4*>(x + i);
    uint2 p; p.x = pkbf(v.x, v.y); p.y = pkbf(v.z, v.w);
    *reinterpret_cast<uint2*>(xb + i) = p;
}

// tiled transpose+convert: w[k][n] (fp32) -> wt[n][k] (bf16)
__global__ __launch_bounds__(256) void k_wtrans(const float* __restrict__ w, unsigned short* __restrict__ wt){
    __shared__ __align__(16) unsigned short Ws[64][72];
    const int r0 = (blockIdx.x / 18) * 64, c0 = (blockIdx.x % 18) * 64;
    #pragma unroll
    for(int it=0; it<4; ++it){
        int idx = threadIdx.x + it*256;
        int r = idx >> 4, cq = (idx & 15) * 4;
        float4 v = *reinterpret_cast<const float4*>(w + (size_t)(r0+r)*HIDDEN + c0 + cq);
        uint2 p; p.x = pkbf(v.x, v.y); p.y = pkbf(v.z, v.w);
        *reinterpret_cast<uint2*>(&Ws[r][cq]) = p;
    }
    __syncthreads();
    #pragma unroll
    for(int it=0; it<4; ++it){
        int idx = threadIdx.x + it*256;
        int rr = idx >> 4, cq = (idx & 15) * 4;
        ushort4 o;
        o.x = Ws[cq+0][rr]; o.y = Ws[cq+1][rr]; o.z = Ws[cq+2][rr]; o.w = Ws[cq+3][rr];
        *reinterpret_cast<ushort4*>(wt + (size_t)(c0+rr)*HIDDEN + r0 + cq) = o;
    }
}

// MODE 0: Q -> [b][h][t][96] *scale; 1: K -> same; 2: V -> [b][h][96][t]; 3: fp32 out+bias
template<int MODE>
__global__ __launch_bounds__(256, 3) void k_gemm(const unsigned short* __restrict__ A,
                                                 const unsigned short* __restrict__ Bt,
                                                 const float* __restrict__ bias,
                                                 void* __restrict__ out, float scale){
    __shared__ __align__(16) unsigned short As[128*32];
    __shared__ __align__(16) unsigned short Bs[128*32];
    const int tid = threadIdx.x, lane = tid & 63, wid = tid >> 6;
    const int wm = wid >> 1, wn = wid & 1;
    const int half = lane >> 4, q16 = lane & 15;
    int lb = (blockIdx.x & 7) * 72 + (blockIdx.x >> 3);       // XCD-chunked swizzle (576 = 8*72)
    const int n0 = (lb % 9) * 128, m0 = (lb / 9) * 128;
    const int lr = lane >> 2, lc = (lane & 3) * 8;
    const unsigned short* ap = A  + (size_t)(m0 + wid*32 + lr)*HIDDEN + lc;
    const unsigned short* bp = Bt + (size_t)(n0 + wid*32 + lr)*HIDDEN + lc;
    unsigned short* as0 = As + (wid*32     )*32 + lane*8;
    unsigned short* as1 = As + (wid*32 + 16)*32 + lane*8;
    unsigned short* bs0 = Bs + (wid*32     )*32 + lane*8;
    unsigned short* bs1 = Bs + (wid*32 + 16)*32 + lane*8;

    f32x4 acc[4][4] = {};
    for(int k0 = 0; k0 < HIDDEN; k0 += 32){
        gld16(ap + k0,             as0);
        gld16(ap + k0 + 16*HIDDEN, as1);
        gld16(bp + k0,             bs0);
        gld16(bp + k0 + 16*HIDDEN, bs1);
        __syncthreads();
        bf16x8 af[4], bf[4];
        #pragma unroll
        for(int mi=0;mi<4;++mi) af[mi] = *reinterpret_cast<const bf16x8*>(As + (wm*64+mi*16+q16)*32 + half*8);
        #pragma unroll
        for(int ni=0;ni<4;++ni) bf[ni] = *reinterpret_cast<const bf16x8*>(Bs + (wn*64+ni*16+q16)*32 + half*8);
        #pragma unroll
        for(int mi=0;mi<4;++mi)
            #pragma unroll
            for(int ni=0;ni<4;++ni)
                acc[mi][ni] = __builtin_amdgcn_mfma_f32_16x16x32_bf16(af[mi], bf[ni], acc[mi][ni], 0,0,0);
        __syncthreads();
    }
    #pragma unroll
    for(int mi=0;mi<4;++mi)
        #pragma unroll
        for(int ni=0;ni<4;++ni)
            #pragma unroll
            for(int j=0;j<4;++j){
                int row = m0 + wm*64 + mi*16 + half*4 + j;   // token index
                int col = n0 + wn*64 + ni*16 + q16;          // output feature
                float v = acc[mi][ni][j] + bias[col];
                if(MODE==0) v *= scale;
                if(MODE==0 || MODE==1){
                    int bb = row >> 12, t = row & 4095;
                    int hh = col / HDIM, d = col % HDIM;
                    ((unsigned short*)out)[((size_t)((bb*HEADS + hh)*TT) + t)*DPAD + d] = f2b(v);
                } else if(MODE==2){
                    int bb = row >> 12, t = row & 4095;
                    int hh = col / HDIM, d = col % HDIM;
                    ((unsigned short*)out)[((size_t)((bb*HEADS + hh)*DPAD) + d)*TT + t] = f2b(v);
                } else {
                    ((float*)out)[(size_t)row*HIDDEN + col] = v;
                }
            }
}

// flash attention: swapped QK^T 16x16 core, asm-pinned async staging (1 barrier/iter),
// launch_bounds(256,2) for address-hoist headroom, vf shared across q-subtiles via pf regs.
__global__ __launch_bounds__(256, 2) void k_attn(const unsigned short* __restrict__ Qp,
                                                 const unsigned short* __restrict__ Kp,
                                                 const unsigned short* __restrict__ Vt,
                                                 unsigned short* __restrict__ AO){
    __shared__ __align__(16) unsigned short KV[2][10240];   // [K 64x80 | V 80x64] per buf = 40 KB
    __shared__ __align__(16) unsigned int   PsT[4][512];    // per-wave P^T: 16 q-rows x 32 dwords, XOR-swz
    __shared__ __align__(16) unsigned short Zs[16];         // zero granules (kk=2, g>=2)
    const int tid  = threadIdx.x;
    const int lane = tid & 63, wid = tid >> 6;
    const int g    = lane >> 4, q16 = lane & 15;
    const int sw7  = q16 & 7;

    int lb = ((blockIdx.x & 7) << 7) | (blockIdx.x >> 3);   // XCD-chunked (1024 = 8*128)
    const int qt = lb & 31, h = (lb >> 5) & 15, b = lb >> 9;
    const int qbase = qt * 128;
    const int bh = b*HEADS + h;

    const unsigned short* kbase = Kp + (size_t)(bh*TT) * DPAD;
    const unsigned short* vbase = Vt + (size_t)(bh*DPAD) * TT;

    // per-thread staging slots (loop-invariant): 640 K chunks + 640 V chunks of 16B
    const unsigned short* gp[5]; int lo[5], adv[5];
    #pragma unroll
    for(int i=0;i<5;++i){
        int c = tid + i*256;
        if(c < 640){
            int r = c/10, ch = c - r*10;
            int phys = (ch < 8) ? (ch ^ (r&7)) : (8 + ((ch&1) ^ (r&1)));
            lo[i]  = r*KSTR2 + (phys<<3);
            gp[i]  = kbase + (size_t)r*DPAD + ch*8;
            adv[i] = 64*DPAD;
        } else {
            int c2 = c - 640, d = c2>>3, ch = c2&7;
            lo[i]  = VOFF + d*64 + ((ch ^ (d&7))<<3);
            gp[i]  = vbase + (size_t)d*TT + ch*8;
            adv[i] = 64;
        }
    }
    if(tid < 2){ uint4 z = {0,0,0,0}; reinterpret_cast<uint4*>(Zs)[tid] = z; }

    // Q fragments: 2 q-subtiles x 16 rows; B-operand row q=q16, k-slot g*8+e -> d = kk*32+g*8+e
    bf16x8 qf[2][3];
    #pragma unroll
    for(int u=0;u<2;++u){
        const unsigned short* qptr = Qp + ((size_t)(bh*TT) + qbase + u*64 + wid*16 + q16) * DPAD;
        #pragma unroll
        for(int kk=0;kk<3;++kk) qf[u][kk] = *reinterpret_cast<const bf16x8*>(qptr + kk*32 + g*8);
    }

    f32x4 accO[2][5] = {};
    float m[2] = {-1e30f, -1e30f};
    float l[2] = {0.f, 0.f};

    // prologue: stage tile 0 into buf 0 (plain loads; compiler-managed waitcnt)
    u32x4 stg[5];
    #pragma unroll
    for(int i=0;i<5;++i) stg[i] = *reinterpret_cast<const u32x4*>(gp[i]);
    #pragma unroll
    for(int i=0;i<5;++i){ *reinterpret_cast<u32x4*>(&KV[0][lo[i]]) = stg[i]; gp[i] += adv[i]; }
    __syncthreads();

    for(int kt = 0; kt < 64; ++kt){
        const int cur = kt & 1;
        if(kt < 63){
            // pinned early issue: volatile asm cannot be sunk; "memory" orders before compute ds_reads
            #pragma unroll
            for(int i=0;i<5;++i)
                asm volatile("global_load_dwordx4 %0, %1, off"
                             : "=v"(stg[i]) : "v"(gp[i]) : "memory");
        }
        const unsigned short* Kb = KV[cur];
        const unsigned short* Vb = KV[cur] + VOFF;

        // S^T[kv][q] = mfma(A=K, B=Q): lane holds col q=q16, rows kv = 16t + 4g + j
        f32x4 s[2][4] = {};
        #pragma unroll
        for(int t=0;t<4;++t){
            const int row = t*16 + q16;
            bf16x8 kf0 = *reinterpret_cast<const bf16x8*>(&Kb[row*KSTR2 + ((g        ^ sw7)<<3)]);
            bf16x8 kf1 = *reinterpret_cast<const bf16x8*>(&Kb[row*KSTR2 + (((4+g)    ^ sw7)<<3)]);
            const unsigned short* k2p = (g < 2) ? &Kb[row*KSTR2 + ((8 + (g ^ (row&1)))<<3)]
                                                : &Zs[(g&1)<<3];
            bf16x8 kf2 = *reinterpret_cast<const bf16x8*>(k2p);
            s[0][t] = __builtin_amdgcn_mfma_f32_16x16x32_bf16(kf0, qf[0][0], s[0][t], 0,0,0);
            s[1][t] = __builtin_amdgcn_mfma_f32_16x16x32_bf16(kf0, qf[1][0], s[1][t], 0,0,0);
            s[0][t] = __builtin_amdgcn_mfma_f32_16x16x32_bf16(kf1, qf[0][1], s[0][t], 0,0,0);
            s[1][t] = __builtin_amdgcn_mfma_f32_16x16x32_bf16(kf1, qf[1][1], s[1][t], 0,0,0);
            s[0][t] = __builtin_amdgcn_mfma_f32_16x16x32_bf16(kf2, qf[0][2], s[0][t], 0,0,0);
            s[1][t] = __builtin_amdgcn_mfma_f32_16x16x32_bf16(kf2, qf[1][2], s[1][t], 0,0,0);
        }

        bf16x8 pf[2][2];
        #pragma unroll
        for(int u=0;u<2;++u){
            float t0 = fmaxf(fmaxf(s[u][0][0],s[u][0][1]), fmaxf(s[u][0][2],s[u][0][3]));
            float t1 = fmaxf(fmaxf(s[u][1][0],s[u][1][1]), fmaxf(s[u][1][2],s[u][1][3]));
            float t2 = fmaxf(fmaxf(s[u][2][0],s[u][2][1]), fmaxf(s[u][2][2],s[u][2][3]));
            float t3 = fmaxf(fmaxf(s[u][3][0],s[u][3][1]), fmaxf(s[u][3][2],s[u][3][3]));
            float tm = fmaxf(fmaxf(t0,t1), fmaxf(t2,t3));
            tm = fmaxf(tm, __shfl_xor(tm, 16, 64));
            tm = fmaxf(tm, __shfl_xor(tm, 32, 64));
            if(__any(tm > m[u] + 8.0f)){                       // defer-max rescale (log2 domain)
                float mn = fmaxf(m[u], tm);
                float al = __builtin_amdgcn_exp2f(m[u] - mn);
                l[u] *= al;  m[u] = mn;
                float aj[4];
                #pragma unroll
                for(int j=0;j<4;++j) aj[j] = __shfl(al, (lane & 48) | (4*g + j), 64);
                #pragma unroll
                for(int nt=0;nt<5;++nt)
                    #pragma unroll
                    for(int j=0;j<4;++j) accO[u][nt][j] *= aj[j];
            }
            // P = exp2(S-m); kv-linear P^T row q16: dword D = 8t+2g(+1); granule gi=D>>2 at gi^sw7
            float sum = 0.f;
            #pragma unroll
            for(int t4=0;t4<4;++t4){
                float p0 = __builtin_amdgcn_exp2f(s[u][t4][0] - m[u]);
                float p1 = __builtin_amdgcn_exp2f(s[u][t4][1] - m[u]);
                float p2 = __builtin_amdgcn_exp2f(s[u][t4][2] - m[u]);
                float p3 = __builtin_amdgcn_exp2f(s[u][t4][3] - m[u]);
                sum += (p0 + p1) + (p2 + p3);
                uint2 w; w.x = pkbf(p0, p1); w.y = pkbf(p2, p3);
                int gi = 2*t4 + (g>>1);
                *reinterpret_cast<uint2*>(&PsT[wid][q16*32 + ((gi ^ sw7)<<2) + 2*(g&1)]) = w;
            }
            sum += __shfl_xor(sum, 16, 64);
            sum += __shfl_xor(sum, 32, 64);
            l[u] += sum;
            // read back this u's P-fragments before u=1 overwrites the per-wave buffer
            #pragma unroll
            for(int kh=0; kh<2; ++kh)
                pf[u][kh] = *reinterpret_cast<const bf16x8*>(&PsT[wid][q16*32 + (((4*kh+g) ^ sw7)<<2)]);
        }

        // PV: vf loaded ONCE per (kh,nt), feeds both q-subtiles
        #pragma unroll
        for(int kh=0; kh<2; ++kh)
            #pragma unroll
            for(int nt=0; nt<5; ++nt){
                bf16x8 vf = *reinterpret_cast<const bf16x8*>(&Vb[(nt*16+q16)*64 + (((kh*4+g) ^ sw7)<<3)]);
                accO[0][nt] = __builtin_amdgcn_mfma_f32_16x16x32_bf16(pf[0][kh], vf, accO[0][nt], 0,0,0);
                accO[1][nt] = __builtin_amdgcn_mfma_f32_16x16x32_bf16(pf[1][kh], vf, accO[1][nt], 0,0,0);
            }

        if(kt < 63){
            // late write-back: wait for the pinned loads (issued ~1100 cyc ago), then ds_write
            asm volatile("s_waitcnt vmcnt(0)" ::: "memory");
            __builtin_amdgcn_sched_barrier(0);
            #pragma unroll
            for(int i=0;i<5;++i){ *reinterpret_cast<u32x4*>(&KV[cur^1][lo[i]]) = stg[i]; gp[i] += adv[i]; }
        }
        __syncthreads();
    }

    // epilogue: accO row q' = 4g+j needs l of q' (lives at lanes with lane&15 = q')
    #pragma unroll
    for(int u=0;u<2;++u){
        float linv[4];
        #pragma unroll
        for(int j=0;j<4;++j){
            float lj = __shfl(l[u], (lane & 48) | (4*g + j), 64);
            linv[j] = 1.0f / lj;
        }
        #pragma unroll
        for(int nt=0;nt<5;++nt){
            int d = nt*16 + q16;
            if(d < HDIM){
                #pragma unroll
                for(int j=0;j<4;++j){
                    int t = qbase + u*64 + wid*16 + 4*g + j;
                    AO[((size_t)(b*TT + t))*HIDDEN + h*HDIM + d] = f2b(accO[u][nt][j] * linv[j]);
                }
            }
        }
    }
}

extern "C" void kernel_launch(void* const* d_in, const int* in_sizes, int n_in,
                              void* d_out, int out_size, void* d_ws, size_t ws_size,
                              hipStream_t stream) {
    const float* x  = (const float*)d_in[0];
    const float* wq = (const float*)d_in[1];
    const float* bq = (const float*)d_in[2];
    const float* wk = (const float*)d_in[3];
    const float* bk = (const float*)d_in[4];
    const float* wv = (const float*)d_in[5];
    const float* bv = (const float*)d_in[6];
    const float* wo = (const float*)d_in[7];
    const float* bo = (const float*)d_in[8];

    char* ws = (char*)d_ws;
    const size_t szXb = (size_t)BT*HIDDEN*2;          // 18874368
    const size_t szW  = (size_t)HIDDEN*HIDDEN*2;      // 2654208
    const size_t szQp = (size_t)NB*HEADS*TT*DPAD*2;   // 25165824

    unsigned short* Xb  = (unsigned short*)(ws);
    unsigned short* WTq = (unsigned short*)(ws + szXb);
    unsigned short* WTk = (unsigned short*)(ws + szXb + szW);
    unsigned short* WTv = (unsigned short*)(ws + szXb + 2*szW);
    unsigned short* WTo = (unsigned short*)(ws + szXb + 3*szW);
    unsigned short* Qp  = (unsigned short*)(ws + szXb + 4*szW);
    unsigned short* Kp  = (unsigned short*)(ws + szXb + 4*szW + szQp);
    unsigned short* Vt  = (unsigned short*)(ws + szXb + 4*szW + 2*szQp);
    unsigned short* AO  = (unsigned short*)(ws + szXb + 4*szW + 3*szQp);

    hipMemsetAsync(Qp, 0, 3*szQp, stream);            // zero d-padding of Q, K, V (contiguous)

    k_convert_x<<<BT*HIDDEN/1024, 256, 0, stream>>>(x, Xb);
    k_wtrans<<<324, 256, 0, stream>>>(wq, WTq);
    k_wtrans<<<324, 256, 0, stream>>>(wk, WTk);
    k_wtrans<<<324, 256, 0, stream>>>(wv, WTv);
    k_wtrans<<<324, 256, 0, stream>>>(wo, WTo);

    const float qscale = (1.0f / sqrtf(72.0f)) * 1.44269504f;  // fold log2(e) for exp2 softmax
    k_gemm<0><<<576, 256, 0, stream>>>(Xb, WTq, bq, Qp, qscale);
    k_gemm<1><<<576, 256, 0, stream>>>(Xb, WTk, bk, Kp, 1.0f);
    k_gemm<2><<<576, 256, 0, stream>>>(Xb, WTv, bv, Vt, 1.0f);

    k_attn<<<NB*HEADS*(TT/128), 256, 0, stream>>>(Qp, Kp, Vt, AO);

    k_gemm<3><<<576, 256, 0, stream>>>(AO, WTo, bo, d_out, 1.0f);
}

// Round 12
// 398.975 us; speedup vs baseline: 1.5458x; 1.0697x over previous
//
#include <hip/hip_runtime.h>

#define HIDDEN 1152
#define HEADS  16
#define HDIM   72
#define DPAD   96
#define NB     2
#define TT     4096
#define BT     (NB*TT)  // 8192

#define KSTR2  80      // Ks row stride (shorts): 10 granules of 8
#define VOFF   5120    // Vs offset inside KV buffer (shorts)

typedef float  f32x4   __attribute__((ext_vector_type(4)));
typedef __bf16 bf16x8  __attribute__((ext_vector_type(8)));
typedef unsigned u32x4 __attribute__((ext_vector_type(4)));

static __device__ __forceinline__ unsigned pkbf(float a, float b){
    unsigned r;
    asm("v_cvt_pk_bf16_f32 %0, %1, %2" : "=v"(r) : "v"(a), "v"(b));
    return r;
}
static __device__ __forceinline__ unsigned short f2b(float f){
    return (unsigned short)pkbf(f, f);
}
static __device__ __forceinline__ void gld16(const unsigned short* g, unsigned short* l){
    __builtin_amdgcn_global_load_lds((const __attribute__((address_space(1))) void*)g,
                                     (__attribute__((address_space(3))) void*)l, 16, 0, 0);
}

__global__ __launch_bounds__(256) void k_convert_x(const float* __restrict__ x, unsigned short* __restrict__ xb){
    int i = (blockIdx.x*256 + threadIdx.x) * 4;
    float4 v = *reinterpret_cast<const float4*>(x + i);
    uint2 p; p.x = pkbf(v.x, v.y); p.y = pkbf(v.z, v.w);
    *reinterpret_cast<uint2*>(xb + i) = p;
}

// tiled transpose+convert: w[k][n] (fp32) -> wt[n][k] (bf16)
__global__ __launch_bounds__(256) void k_wtrans(const float* __restrict__ w, unsigned short* __restrict__ wt){
    __shared__ __align__(16) unsigned short Ws[64][72];
    const int r0 = (blockIdx.x / 18) * 64, c0 = (blockIdx.x % 18) * 64;
    #pragma unroll
    for(int it=0; it<4; ++it){
        int idx = threadIdx.x + it*256;
        int r = idx >> 4, cq = (idx & 15) * 4;
        float4 v = *reinterpret_cast<const float4*>(w + (size_t)(r0+r)*HIDDEN + c0 + cq);
        uint2 p; p.x = pkbf(v.x, v.y); p.y = pkbf(v.z, v.w);
        *reinterpret_cast<uint2*>(&Ws[r][cq]) = p;
    }
    __syncthreads();
    #pragma unroll
    for(int it=0; it<4; ++it){
        int idx = threadIdx.x + it*256;
        int rr = idx >> 4, cq = (idx & 15) * 4;
        ushort4 o;
        o.x = Ws[cq+0][rr]; o.y = Ws[cq+1][rr]; o.z = Ws[cq+2][rr]; o.w = Ws[cq+3][rr];
        *reinterpret_cast<ushort4*>(wt + (size_t)(c0+rr)*HIDDEN + r0 + cq) = o;
    }
}

// MODE 0: Q -> [b][h][t][96] *scale; 1: K -> same; 2: V -> [b][h][96][t]; 3: fp32 out+bias
template<int MODE>
__global__ __launch_bounds__(256, 3) void k_gemm(const unsigned short* __restrict__ A,
                                                 const unsigned short* __restrict__ Bt,
                                                 const float* __restrict__ bias,
                                                 void* __restrict__ out, float scale){
    __shared__ __align__(16) unsigned short As[128*32];
    __shared__ __align__(16) unsigned short Bs[128*32];
    const int tid = threadIdx.x, lane = tid & 63, wid = tid >> 6;
    const int wm = wid >> 1, wn = wid & 1;
    const int half = lane >> 4, q16 = lane & 15;
    int lb = (blockIdx.x & 7) * 72 + (blockIdx.x >> 3);       // XCD-chunked swizzle (576 = 8*72)
    const int n0 = (lb % 9) * 128, m0 = (lb / 9) * 128;
    const int lr = lane >> 2, lc = (lane & 3) * 8;
    const unsigned short* ap = A  + (size_t)(m0 + wid*32 + lr)*HIDDEN + lc;
    const unsigned short* bp = Bt + (size_t)(n0 + wid*32 + lr)*HIDDEN + lc;
    unsigned short* as0 = As + (wid*32     )*32 + lane*8;
    unsigned short* as1 = As + (wid*32 + 16)*32 + lane*8;
    unsigned short* bs0 = Bs + (wid*32     )*32 + lane*8;
    unsigned short* bs1 = Bs + (wid*32 + 16)*32 + lane*8;

    f32x4 acc[4][4] = {};
    for(int k0 = 0; k0 < HIDDEN; k0 += 32){
        gld16(ap + k0,             as0);
        gld16(ap + k0 + 16*HIDDEN, as1);
        gld16(bp + k0,             bs0);
        gld16(bp + k0 + 16*HIDDEN, bs1);
        __syncthreads();
        bf16x8 af[4], bf[4];
        #pragma unroll
        for(int mi=0;mi<4;++mi) af[mi] = *reinterpret_cast<const bf16x8*>(As + (wm*64+mi*16+q16)*32 + half*8);
        #pragma unroll
        for(int ni=0;ni<4;++ni) bf[ni] = *reinterpret_cast<const bf16x8*>(Bs + (wn*64+ni*16+q16)*32 + half*8);
        #pragma unroll
        for(int mi=0;mi<4;++mi)
            #pragma unroll
            for(int ni=0;ni<4;++ni)
                acc[mi][ni] = __builtin_amdgcn_mfma_f32_16x16x32_bf16(af[mi], bf[ni], acc[mi][ni], 0,0,0);
        __syncthreads();
    }
    #pragma unroll
    for(int mi=0;mi<4;++mi)
        #pragma unroll
        for(int ni=0;ni<4;++ni)
            #pragma unroll
            for(int j=0;j<4;++j){
                int row = m0 + wm*64 + mi*16 + half*4 + j;   // token index
                int col = n0 + wn*64 + ni*16 + q16;          // output feature
                float v = acc[mi][ni][j] + bias[col];
                if(MODE==0) v *= scale;
                if(MODE==0 || MODE==1){
                    int bb = row >> 12, t = row & 4095;
                    int hh = col / HDIM, d = col % HDIM;
                    ((unsigned short*)out)[((size_t)((bb*HEADS + hh)*TT) + t)*DPAD + d] = f2b(v);
                } else if(MODE==2){
                    int bb = row >> 12, t = row & 4095;
                    int hh = col / HDIM, d = col % HDIM;
                    ((unsigned short*)out)[((size_t)((bb*HEADS + hh)*DPAD) + d)*TT + t] = f2b(v);
                } else {
                    ((float*)out)[(size_t)row*HIDDEN + col] = v;
                }
            }
}

// flash attention: swapped QK^T 16x16 core, asm-pinned async staging, 1 barrier/iter.
// Zero-shuffle PV via sigma-permuted V columns; LDS exactly 40 KB.
// launch_bounds(256,2): no forced spill of async-load destinations (round-11 NaN root cause);
// VGPR lands ~96-120 -> 4 blocks/CU via LDS+VGPR naturally.
__global__ __launch_bounds__(256, 2) void k_attn(const unsigned short* __restrict__ Qp,
                                                 const unsigned short* __restrict__ Kp,
                                                 const unsigned short* __restrict__ Vt,
                                                 unsigned short* __restrict__ AO){
    __shared__ __align__(16) unsigned short KV[2][10240];   // [K 64x80 | V 80x64] per buf = 40 KB total
    const int tid  = threadIdx.x;
    const int lane = tid & 63, wid = tid >> 6;
    const int g    = lane >> 4, q16 = lane & 15;
    const int sw7  = q16 & 7;

    int lb = ((blockIdx.x & 7) << 7) | (blockIdx.x >> 3);   // XCD-chunked (1024 = 8*128)
    const int qt = lb & 31, h = (lb >> 5) & 15, b = lb >> 9;
    const int qbase = qt * 128;
    const int bh = b*HEADS + h;

    const unsigned short* kbase = Kp + (size_t)(bh*TT) * DPAD;
    const unsigned short* vbase = Vt + (size_t)(bh*DPAD) * TT;

    // per-thread staging slots: 640 K chunks (b128) + 640 V chunks (2x b64, sigma-permuted+swizzled)
    const unsigned short* gp[5]; int lo[5], lo2[5], adv[5];
    #pragma unroll
    for(int i=0;i<5;++i){
        int c = tid + i*256;
        if(c < 640){
            int r = c/10, ch = c - r*10;
            int phys = (ch < 8) ? (ch ^ (r&7)) : (8 + ((ch&1) ^ (r&1)));
            lo[i]  = r*KSTR2 + (phys<<3);
            lo2[i] = lo[i];
            gp[i]  = kbase + (size_t)r*DPAD + ch*8;
            adv[i] = 64*DPAD;
        } else {
            int c2 = c - 640, d = c2>>3, ch = c2&7;
            int kh = ch>>2, thi = (ch>>1)&1, g0 = 4*kh + 2*(ch&1);
            lo[i]  = VOFF + d*64 + (((g0  ) ^ (d&7))<<3) + 4*thi;   // kv pairs (w=0..3)
            lo2[i] = VOFF + d*64 + (((g0+1) ^ (d&7))<<3) + 4*thi;   // kv pairs (w=4..7)
            gp[i]  = vbase + (size_t)d*TT + ch*8;
            adv[i] = 64;
        }
    }

    // Q fragments: 2 q-subtiles x 16 rows; B-operand row q=q16, k-slot g*8+e -> d = kk*32+g*8+e
    bf16x8 qf[2][3];
    #pragma unroll
    for(int u=0;u<2;++u){
        const unsigned short* qptr = Qp + ((size_t)(bh*TT) + qbase + u*64 + wid*16 + q16) * DPAD;
        #pragma unroll
        for(int kk=0;kk<3;++kk) qf[u][kk] = *reinterpret_cast<const bf16x8*>(qptr + kk*32 + g*8);
    }

    f32x4 accO[2][5] = {};
    float m[2] = {-1e30f, -1e30f};
    float l[2] = {0.f, 0.f};

    // prologue: stage tile 0 into buf 0
    u32x4 stg[5];
    #pragma unroll
    for(int i=0;i<5;++i) stg[i] = *reinterpret_cast<const u32x4*>(gp[i]);
    #pragma unroll
    for(int i=0;i<5;++i){
        if(tid + i*256 < 640){
            *reinterpret_cast<u32x4*>(&KV[0][lo[i]]) = stg[i];
        } else {
            uint2 a; a.x = stg[i].x; a.y = stg[i].y;
            uint2 bq; bq.x = stg[i].z; bq.y = stg[i].w;
            *reinterpret_cast<uint2*>(&KV[0][lo[i]])  = a;
            *reinterpret_cast<uint2*>(&KV[0][lo2[i]]) = bq;
        }
        gp[i] += adv[i];
    }
    __syncthreads();

    for(int kt = 0; kt < 64; ++kt){
        const int cur = kt & 1;
        if(kt < 63){
            // pinned early issue: volatile asm cannot be sunk; "memory" orders before compute ds_reads
            #pragma unroll
            for(int i=0;i<5;++i)
                asm volatile("global_load_dwordx4 %0, %1, off"
                             : "=v"(stg[i]) : "v"(gp[i]) : "memory");
        }
        const unsigned short* Kb = KV[cur];
        const unsigned short* Vb = KV[cur] + VOFF;

        // S^T[kv][q] = mfma(A=K, B=Q): lane holds col q=q16, rows kv = 16t + 4g + j
        f32x4 s[2][4] = {};
        #pragma unroll
        for(int t=0;t<4;++t){
            const int row = t*16 + q16;
            bf16x8 kf0 = *reinterpret_cast<const bf16x8*>(&Kb[row*KSTR2 + ((g     ^ sw7)<<3)]);
            bf16x8 kf1 = *reinterpret_cast<const bf16x8*>(&Kb[row*KSTR2 + (((4+g) ^ sw7)<<3)]);
            // g>=2 reads K d in [64,80) here, but qf[u][2] rows d in [80,96) are memset-zero -> product 0
            bf16x8 kf2 = *reinterpret_cast<const bf16x8*>(&Kb[row*KSTR2 + ((8 + ((g&1) ^ (row&1)))<<3)]);
            s[0][t] = __builtin_amdgcn_mfma_f32_16x16x32_bf16(kf0, qf[0][0], s[0][t], 0,0,0);
            s[1][t] = __builtin_amdgcn_mfma_f32_16x16x32_bf16(kf0, qf[1][0], s[1][t], 0,0,0);
            s[0][t] = __builtin_amdgcn_mfma_f32_16x16x32_bf16(kf1, qf[0][1], s[0][t], 0,0,0);
            s[1][t] = __builtin_amdgcn_mfma_f32_16x16x32_bf16(kf1, qf[1][1], s[1][t], 0,0,0);
            s[0][t] = __builtin_amdgcn_mfma_f32_16x16x32_bf16(kf2, qf[0][2], s[0][t], 0,0,0);
            s[1][t] = __builtin_amdgcn_mfma_f32_16x16x32_bf16(kf2, qf[1][2], s[1][t], 0,0,0);
        }

        bf16x8 pf[2][2];
        #pragma unroll
        for(int u=0;u<2;++u){
            float t0 = fmaxf(fmaxf(s[u][0][0],s[u][0][1]), fmaxf(s[u][0][2],s[u][0][3]));
            float t1 = fmaxf(fmaxf(s[u][1][0],s[u][1][1]), fmaxf(s[u][1][2],s[u][1][3]));
            float t2 = fmaxf(fmaxf(s[u][2][0],s[u][2][1]), fmaxf(s[u][2][2],s[u][2][3]));
            float t3 = fmaxf(fmaxf(s[u][3][0],s[u][3][1]), fmaxf(s[u][3][2],s[u][3][3]));
            float tm = fmaxf(fmaxf(t0,t1), fmaxf(t2,t3));
            tm = fmaxf(tm, __shfl_xor(tm, 16, 64));
            tm = fmaxf(tm, __shfl_xor(tm, 32, 64));
            if(__any(tm > m[u] + 8.0f)){                       // defer-max rescale (log2 domain)
                float mn = fmaxf(m[u], tm);
                float al = __builtin_amdgcn_exp2f(m[u] - mn);
                l[u] *= al;  m[u] = mn;
                float aj[4];
                #pragma unroll
                for(int j=0;j<4;++j) aj[j] = __shfl(al, (lane & 48) | (4*g + j), 64);
                #pragma unroll
                for(int nt=0;nt<5;++nt)
                    #pragma unroll
                    for(int j=0;j<4;++j) accO[u][nt][j] *= aj[j];
            }
            // P = exp2(S-m), packed per t: dwA = kv pair (16t+4g, +1), dwB = (16t+4g+2, +3)
            unsigned dwA[4], dwB[4];
            float sum = 0.f;
            #pragma unroll
            for(int t4=0;t4<4;++t4){
                float p0 = __builtin_amdgcn_exp2f(s[u][t4][0] - m[u]);
                float p1 = __builtin_amdgcn_exp2f(s[u][t4][1] - m[u]);
                float p2 = __builtin_amdgcn_exp2f(s[u][t4][2] - m[u]);
                float p3 = __builtin_amdgcn_exp2f(s[u][t4][3] - m[u]);
                sum += (p0 + p1) + (p2 + p3);
                dwA[t4] = pkbf(p0, p1);
                dwB[t4] = pkbf(p2, p3);
            }
            sum += __shfl_xor(sum, 16, 64);
            sum += __shfl_xor(sum, 32, 64);
            l[u] += sum;
            // zero-shuffle A-fragments: sigma-permuted V columns make these the lane's own dwords
            union { unsigned w[4]; bf16x8 v; } pu0, pu1;
            pu0.w[0]=dwA[0]; pu0.w[1]=dwB[0]; pu0.w[2]=dwA[1]; pu0.w[3]=dwB[1];
            pu1.w[0]=dwA[2]; pu1.w[1]=dwB[2]; pu1.w[2]=dwA[3]; pu1.w[3]=dwB[3];
            pf[u][0] = pu0.v;  pf[u][1] = pu1.v;
        }

        // PV: vf loaded ONCE per (kh,nt), feeds both q-subtiles
        #pragma unroll
        for(int kh=0; kh<2; ++kh)
            #pragma unroll
            for(int nt=0; nt<5; ++nt){
                bf16x8 vf = *reinterpret_cast<const bf16x8*>(&Vb[(nt*16+q16)*64 + (((kh*4+g) ^ sw7)<<3)]);
                accO[0][nt] = __builtin_amdgcn_mfma_f32_16x16x32_bf16(pf[0][kh], vf, accO[0][nt], 0,0,0);
                accO[1][nt] = __builtin_amdgcn_mfma_f32_16x16x32_bf16(pf[1][kh], vf, accO[1][nt], 0,0,0);
            }

        if(kt < 63){
            // late write-back: wait for the pinned loads (issued ~1000 cyc ago), then ds_write
            asm volatile("s_waitcnt vmcnt(0)" ::: "memory");
            __builtin_amdgcn_sched_barrier(0);
            #pragma unroll
            for(int i=0;i<5;++i){
                if(tid + i*256 < 640){
                    *reinterpret_cast<u32x4*>(&KV[cur^1][lo[i]]) = stg[i];
                } else {
                    uint2 a; a.x = stg[i].x; a.y = stg[i].y;
                    uint2 bq; bq.x = stg[i].z; bq.y = stg[i].w;
                    *reinterpret_cast<uint2*>(&KV[cur^1][lo[i]])  = a;
                    *reinterpret_cast<uint2*>(&KV[cur^1][lo2[i]]) = bq;
                }
                gp[i] += adv[i];
            }
        }
        __syncthreads();
    }

    // epilogue: accO row q' = 4g+j needs l of q' (lives at lanes with lane&15 = q')
    #pragma unroll
    for(int u=0;u<2;++u){
        float linv[4];
        #pragma unroll
        for(int j=0;j<4;++j){
            float lj = __shfl(l[u], (lane & 48) | (4*g + j), 64);
            linv[j] = 1.0f / lj;
        }
        #pragma unroll
        for(int nt=0;nt<5;++nt){
            int d = nt*16 + q16;
            if(d < HDIM){
                #pragma unroll
                for(int j=0;j<4;++j){
                    int t = qbase + u*64 + wid*16 + 4*g + j;
                    AO[((size_t)(b*TT + t))*HIDDEN + h*HDIM + d] = f2b(accO[u][nt][j] * linv[j]);
                }
            }
        }
    }
}

extern "C" void kernel_launch(void* const* d_in, const int* in_sizes, int n_in,
                              void* d_out, int out_size, void* d_ws, size_t ws_size,
                              hipStream_t stream) {
    const float* x  = (const float*)d_in[0];
    const float* wq = (const float*)d_in[1];
    const float* bq = (const float*)d_in[2];
    const float* wk = (const float*)d_in[3];
    const float* bk = (const float*)d_in[4];
    const float* wv = (const float*)d_in[5];
    const float* bv = (const float*)d_in[6];
    const float* wo = (const float*)d_in[7];
    const float* bo = (const float*)d_in[8];

    char* ws = (char*)d_ws;
    const size_t szXb = (size_t)BT*HIDDEN*2;          // 18874368
    const size_t szW  = (size_t)HIDDEN*HIDDEN*2;      // 2654208
    const size_t szQp = (size_t)NB*HEADS*TT*DPAD*2;   // 25165824

    unsigned short* Xb  = (unsigned short*)(ws);
    unsigned short* WTq = (unsigned short*)(ws + szXb);
    unsigned short* WTk = (unsigned short*)(ws + szXb + szW);
    unsigned short* WTv = (unsigned short*)(ws + szXb + 2*szW);
    unsigned short* WTo = (unsigned short*)(ws + szXb + 3*szW);
    unsigned short* Qp  = (unsigned short*)(ws + szXb + 4*szW);
    unsigned short* Kp  = (unsigned short*)(ws + szXb + 4*szW + szQp);
    unsigned short* Vt  = (unsigned short*)(ws + szXb + 4*szW + 2*szQp);
    unsigned short* AO  = (unsigned short*)(ws + szXb + 4*szW + 3*szQp);

    hipMemsetAsync(Qp, 0, 3*szQp, stream);            // zero d-padding of Q, K, V (contiguous)

    k_convert_x<<<BT*HIDDEN/1024, 256, 0, stream>>>(x, Xb);
    k_wtrans<<<324, 256, 0, stream>>>(wq, WTq);
    k_wtrans<<<324, 256, 0, stream>>>(wk, WTk);
    k_wtrans<<<324, 256, 0, stream>>>(wv, WTv);
    k_wtrans<<<324, 256, 0, stream>>>(wo, WTo);

    const float qscale = (1.0f / sqrtf(72.0f)) * 1.44269504f;  // fold log2(e) for exp2 softmax
    k_gemm<0><<<576, 256, 0, stream>>>(Xb, WTq, bq, Qp, qscale);
    k_gemm<1><<<576, 256, 0, stream>>>(Xb, WTk, bk, Kp, 1.0f);
    k_gemm<2><<<576, 256, 0, stream>>>(Xb, WTv, bv, Vt, 1.0f);

    k_attn<<<NB*HEADS*(TT/128), 256, 0, stream>>>(Qp, Kp, Vt, AO);

    k_gemm<3><<<576, 256, 0, stream>>>(AO, WTo, bo, d_out, 1.0f);
}

// Round 14
// 393.699 us; speedup vs baseline: 1.5665x; 1.0134x over previous
//
#include <hip/hip_runtime.h>

#define HIDDEN 1152
#define HEADS  16
#define HDIM   72
#define DPAD   96
#define NB     2
#define TT     4096
#define BT     (NB*TT)  // 8192

#define KSTR2  80      // Ks row stride (shorts): 10 granules of 8
#define VOFF   5120    // Vs offset inside KV buffer (shorts)

typedef float  f32x4   __attribute__((ext_vector_type(4)));
typedef __bf16 bf16x8  __attribute__((ext_vector_type(8)));
typedef unsigned u32x4 __attribute__((ext_vector_type(4)));

static __device__ __forceinline__ unsigned pkbf(float a, float b){
    unsigned r;
    asm("v_cvt_pk_bf16_f32 %0, %1, %2" : "=v"(r) : "v"(a), "v"(b));
    return r;
}
static __device__ __forceinline__ unsigned short f2b(float f){
    return (unsigned short)pkbf(f, f);
}
static __device__ __forceinline__ void gld16(const unsigned short* g, unsigned short* l){
    __builtin_amdgcn_global_load_lds((const __attribute__((address_space(1))) void*)g,
                                     (__attribute__((address_space(3))) void*)l, 16, 0, 0);
}

__global__ __launch_bounds__(256) void k_convert_x(const float* __restrict__ x, unsigned short* __restrict__ xb){
    int i = (blockIdx.x*256 + threadIdx.x) * 4;
    float4 v = *reinterpret_cast<const float4*>(x + i);
    uint2 p; p.x = pkbf(v.x, v.y); p.y = pkbf(v.z, v.w);
    *reinterpret_cast<uint2*>(xb + i) = p;
}

// tiled transpose+convert: w[k][n] (fp32) -> wt[n][k] (bf16)
__global__ __launch_bounds__(256) void k_wtrans(const float* __restrict__ w, unsigned short* __restrict__ wt){
    __shared__ __align__(16) unsigned short Ws[64][72];
    const int r0 = (blockIdx.x / 18) * 64, c0 = (blockIdx.x % 18) * 64;
    #pragma unroll
    for(int it=0; it<4; ++it){
        int idx = threadIdx.x + it*256;
        int r = idx >> 4, cq = (idx & 15) * 4;
        float4 v = *reinterpret_cast<const float4*>(w + (size_t)(r0+r)*HIDDEN + c0 + cq);
        uint2 p; p.x = pkbf(v.x, v.y); p.y = pkbf(v.z, v.w);
        *reinterpret_cast<uint2*>(&Ws[r][cq]) = p;
    }
    __syncthreads();
    #pragma unroll
    for(int it=0; it<4; ++it){
        int idx = threadIdx.x + it*256;
        int rr = idx >> 4, cq = (idx & 15) * 4;
        ushort4 o;
        o.x = Ws[cq+0][rr]; o.y = Ws[cq+1][rr]; o.z = Ws[cq+2][rr]; o.w = Ws[cq+3][rr];
        *reinterpret_cast<ushort4*>(wt + (size_t)(c0+rr)*HIDDEN + r0 + cq) = o;
    }
}

// MODE 0: Q -> [b][h][t][96] *scale; 1: K -> same; 2: V -> [b][h][96][t]; 3: fp32 out+bias
template<int MODE>
__global__ __launch_bounds__(256, 3) void k_gemm(const unsigned short* __restrict__ A,
                                                 const unsigned short* __restrict__ Bt,
                                                 const float* __restrict__ bias,
                                                 void* __restrict__ out, float scale){
    __shared__ __align__(16) unsigned short As[128*32];
    __shared__ __align__(16) unsigned short Bs[128*32];
    const int tid = threadIdx.x, lane = tid & 63, wid = tid >> 6;
    const int wm = wid >> 1, wn = wid & 1;
    const int half = lane >> 4, q16 = lane & 15;
    int lb = (blockIdx.x & 7) * 72 + (blockIdx.x >> 3);       // XCD-chunked swizzle (576 = 8*72)
    const int n0 = (lb % 9) * 128, m0 = (lb / 9) * 128;
    const int lr = lane >> 2, lc = (lane & 3) * 8;
    const unsigned short* ap = A  + (size_t)(m0 + wid*32 + lr)*HIDDEN + lc;
    const unsigned short* bp = Bt + (size_t)(n0 + wid*32 + lr)*HIDDEN + lc;
    unsigned short* as0 = As + (wid*32     )*32 + lane*8;
    unsigned short* as1 = As + (wid*32 + 16)*32 + lane*8;
    unsigned short* bs0 = Bs + (wid*32     )*32 + lane*8;
    unsigned short* bs1 = Bs + (wid*32 + 16)*32 + lane*8;

    f32x4 acc[4][4] = {};
    for(int k0 = 0; k0 < HIDDEN; k0 += 32){
        gld16(ap + k0,             as0);
        gld16(ap + k0 + 16*HIDDEN, as1);
        gld16(bp + k0,             bs0);
        gld16(bp + k0 + 16*HIDDEN, bs1);
        __syncthreads();
        bf16x8 af[4], bf[4];
        #pragma unroll
        for(int mi=0;mi<4;++mi) af[mi] = *reinterpret_cast<const bf16x8*>(As + (wm*64+mi*16+q16)*32 + half*8);
        #pragma unroll
        for(int ni=0;ni<4;++ni) bf[ni] = *reinterpret_cast<const bf16x8*>(Bs + (wn*64+ni*16+q16)*32 + half*8);
        #pragma unroll
        for(int mi=0;mi<4;++mi)
            #pragma unroll
            for(int ni=0;ni<4;++ni)
                acc[mi][ni] = __builtin_amdgcn_mfma_f32_16x16x32_bf16(af[mi], bf[ni], acc[mi][ni], 0,0,0);
        __syncthreads();
    }
    #pragma unroll
    for(int mi=0;mi<4;++mi)
        #pragma unroll
        for(int ni=0;ni<4;++ni)
            #pragma unroll
            for(int j=0;j<4;++j){
                int row = m0 + wm*64 + mi*16 + half*4 + j;   // token index
                int col = n0 + wn*64 + ni*16 + q16;          // output feature
                float v = acc[mi][ni][j] + bias[col];
                if(MODE==0) v *= scale;
                if(MODE==0 || MODE==1){
                    int bb = row >> 12, t = row & 4095;
                    int hh = col / HDIM, d = col % HDIM;
                    ((unsigned short*)out)[((size_t)((bb*HEADS + hh)*TT) + t)*DPAD + d] = f2b(v);
                } else if(MODE==2){
                    int bb = row >> 12, t = row & 4095;
                    int hh = col / HDIM, d = col % HDIM;
                    ((unsigned short*)out)[((size_t)((bb*HEADS + hh)*DPAD) + d)*TT + t] = f2b(v);
                } else {
                    ((float*)out)[(size_t)row*HIDDEN + col] = v;
                }
            }
}

// flash attention: swapped QK^T 16x16 core, asm-pinned async staging, 1 barrier/iter.
// Zero-shuffle PV via sigma-permuted V columns; 8 waves x 256 q-rows/block so each staged
// K/V tile serves 2x the q-rows (staging per thread: 2.5 chunks vs 5). Grid 512 = 2 blocks/CU.
__global__ __launch_bounds__(512, 2) void k_attn(const unsigned short* __restrict__ Qp,
                                                 const unsigned short* __restrict__ Kp,
                                                 const unsigned short* __restrict__ Vt,
                                                 unsigned short* __restrict__ AO){
    __shared__ __align__(16) unsigned short KV[2][10240];   // [K 64x80 | V 80x64] per buf = 40 KB total
    const int tid  = threadIdx.x;
    const int lane = tid & 63, wid = tid >> 6;              // wid in [0,8)
    const int g    = lane >> 4, q16 = lane & 15;
    const int sw7  = q16 & 7;

    int lb = ((blockIdx.x & 7) << 6) | (blockIdx.x >> 3);   // XCD-chunked (512 = 8*64)
    const int qt = lb & 15, h = (lb >> 4) & 15, b = lb >> 8;
    const int qbase = qt * 256;
    const int bh = b*HEADS + h;

    const unsigned short* kbase = Kp + (size_t)(bh*TT) * DPAD;
    const unsigned short* vbase = Vt + (size_t)(bh*DPAD) * TT;

    // per-thread staging slots: 1280 chunks over 512 threads (3rd iter: tid<256 only, wave-uniform)
    const unsigned short* gp[3]; int lo[3], lo2[3], adv[3];
    #pragma unroll
    for(int i=0;i<3;++i){
        int c = tid + i*512; if(c > 1279) c = 1279;          // clamped; guarded at use
        if(c < 640){
            int r = c/10, ch = c - r*10;
            int phys = (ch < 8) ? (ch ^ (r&7)) : (8 + ((ch&1) ^ (r&1)));
            lo[i]  = r*KSTR2 + (phys<<3);
            lo2[i] = lo[i];
            gp[i]  = kbase + (size_t)r*DPAD + ch*8;
            adv[i] = 64*DPAD;
        } else {
            int c2 = c - 640, d = c2>>3, ch = c2&7;
            int kh = ch>>2, thi = (ch>>1)&1, g0 = 4*kh + 2*(ch&1);
            lo[i]  = VOFF + d*64 + (((g0  ) ^ (d&7))<<3) + 4*thi;   // kv pairs (w=0..3)
            lo2[i] = VOFF + d*64 + (((g0+1) ^ (d&7))<<3) + 4*thi;   // kv pairs (w=4..7)
            gp[i]  = vbase + (size_t)d*TT + ch*8;
            adv[i] = 64;
        }
    }

    // Q fragments: 2 q-subtiles x 16 rows per wave; B-operand row q=q16, k-slot g*8+e
    bf16x8 qf[2][3];
    #pragma unroll
    for(int u=0;u<2;++u){
        const unsigned short* qptr = Qp + ((size_t)(bh*TT) + qbase + u*128 + wid*16 + q16) * DPAD;
        #pragma unroll
        for(int kk=0;kk<3;++kk) qf[u][kk] = *reinterpret_cast<const bf16x8*>(qptr + kk*32 + g*8);
    }

    f32x4 accO[2][5] = {};
    float m[2] = {-1e30f, -1e30f};
    float l[2] = {0.f, 0.f};

    // prologue: stage tile 0 into buf 0
    u32x4 stg[3];
    #pragma unroll
    for(int i=0;i<3;++i) if(i<2 || tid<256) stg[i] = *reinterpret_cast<const u32x4*>(gp[i]);
    #pragma unroll
    for(int i=0;i<3;++i) if(i<2 || tid<256){
        if(tid + i*512 < 640){
            *reinterpret_cast<u32x4*>(&KV[0][lo[i]]) = stg[i];
        } else {
            uint2 a; a.x = stg[i].x; a.y = stg[i].y;
            uint2 bq; bq.x = stg[i].z; bq.y = stg[i].w;
            *reinterpret_cast<uint2*>(&KV[0][lo[i]])  = a;
            *reinterpret_cast<uint2*>(&KV[0][lo2[i]]) = bq;
        }
        gp[i] += adv[i];
    }
    __syncthreads();

    for(int kt = 0; kt < 64; ++kt){
        const int cur = kt & 1;
        if(kt < 63){
            // pinned early issue: volatile asm cannot be sunk; "memory" orders before compute ds_reads
            #pragma unroll
            for(int i=0;i<3;++i) if(i<2 || tid<256)
                asm volatile("global_load_dwordx4 %0, %1, off"
                             : "=v"(stg[i]) : "v"(gp[i]) : "memory");
        }
        const unsigned short* Kb = KV[cur];
        const unsigned short* Vb = KV[cur] + VOFF;

        // S^T[kv][q] = mfma(A=K, B=Q): lane holds col q=q16, rows kv = 16t + 4g + j
        f32x4 s[2][4] = {};
        #pragma unroll
        for(int t=0;t<4;++t){
            const int row = t*16 + q16;
            bf16x8 kf0 = *reinterpret_cast<const bf16x8*>(&Kb[row*KSTR2 + ((g     ^ sw7)<<3)]);
            bf16x8 kf1 = *reinterpret_cast<const bf16x8*>(&Kb[row*KSTR2 + (((4+g) ^ sw7)<<3)]);
            // g>=2 reads K d in [64,80) here, but qf[u][2] rows d in [80,96) are memset-zero -> product 0
            bf16x8 kf2 = *reinterpret_cast<const bf16x8*>(&Kb[row*KSTR2 + ((8 + ((g&1) ^ (row&1)))<<3)]);
            s[0][t] = __builtin_amdgcn_mfma_f32_16x16x32_bf16(kf0, qf[0][0], s[0][t], 0,0,0);
            s[1][t] = __builtin_amdgcn_mfma_f32_16x16x32_bf16(kf0, qf[1][0], s[1][t], 0,0,0);
            s[0][t] = __builtin_amdgcn_mfma_f32_16x16x32_bf16(kf1, qf[0][1], s[0][t], 0,0,0);
            s[1][t] = __builtin_amdgcn_mfma_f32_16x16x32_bf16(kf1, qf[1][1], s[1][t], 0,0,0);
            s[0][t] = __builtin_amdgcn_mfma_f32_16x16x32_bf16(kf2, qf[0][2], s[0][t], 0,0,0);
            s[1][t] = __builtin_amdgcn_mfma_f32_16x16x32_bf16(kf2, qf[1][2], s[1][t], 0,0,0);
        }

        bf16x8 pf[2][2];
        #pragma unroll
        for(int u=0;u<2;++u){
            // 16-value max as max3-friendly chain
            float tm = fmaxf(fmaxf(s[u][0][0], s[u][0][1]), s[u][0][2]);
            tm = fmaxf(fmaxf(tm, s[u][0][3]), s[u][1][0]);
            tm = fmaxf(fmaxf(tm, s[u][1][1]), s[u][1][2]);
            tm = fmaxf(fmaxf(tm, s[u][1][3]), s[u][2][0]);
            tm = fmaxf(fmaxf(tm, s[u][2][1]), s[u][2][2]);
            tm = fmaxf(fmaxf(tm, s[u][2][3]), s[u][3][0]);
            tm = fmaxf(fmaxf(tm, s[u][3][1]), s[u][3][2]);
            tm = fmaxf(tm, s[u][3][3]);
            tm = fmaxf(tm, __shfl_xor(tm, 16, 64));
            tm = fmaxf(tm, __shfl_xor(tm, 32, 64));
            if(__any(tm > m[u] + 8.0f)){                       // defer-max rescale (log2 domain)
                float mn = fmaxf(m[u], tm);
                float al = __builtin_amdgcn_exp2f(m[u] - mn);
                l[u] *= al;  m[u] = mn;
                float aj[4];
                #pragma unroll
                for(int j=0;j<4;++j) aj[j] = __shfl(al, (lane & 48) | (4*g + j), 64);
                #pragma unroll
                for(int nt=0;nt<5;++nt)
                    #pragma unroll
                    for(int j=0;j<4;++j) accO[u][nt][j] *= aj[j];
            }
            // P = exp2(S-m), packed per t: dwA = kv pair (16t+4g, +1), dwB = (16t+4g+2, +3)
            unsigned dwA[4], dwB[4];
            float sum = 0.f;
            #pragma unroll
            for(int t4=0;t4<4;++t4){
                float p0 = __builtin_amdgcn_exp2f(s[u][t4][0] - m[u]);
                float p1 = __builtin_amdgcn_exp2f(s[u][t4][1] - m[u]);
                float p2 = __builtin_amdgcn_exp2f(s[u][t4][2] - m[u]);
                float p3 = __builtin_amdgcn_exp2f(s[u][t4][3] - m[u]);
                sum += (p0 + p1) + (p2 + p3);
                dwA[t4] = pkbf(p0, p1);
                dwB[t4] = pkbf(p2, p3);
            }
            sum += __shfl_xor(sum, 16, 64);
            sum += __shfl_xor(sum, 32, 64);
            l[u] += sum;
            // zero-shuffle A-fragments: sigma-permuted V columns make these the lane's own dwords
            union { unsigned w[4]; bf16x8 v; } pu0, pu1;
            pu0.w[0]=dwA[0]; pu0.w[1]=dwB[0]; pu0.w[2]=dwA[1]; pu0.w[3]=dwB[1];
            pu1.w[0]=dwA[2]; pu1.w[1]=dwB[2]; pu1.w[2]=dwA[3]; pu1.w[3]=dwB[3];
            pf[u][0] = pu0.v;  pf[u][1] = pu1.v;
        }

        // PV: vf loaded ONCE per (kh,nt), feeds both q-subtiles
        #pragma unroll
        for(int kh=0; kh<2; ++kh)
            #pragma unroll
            for(int nt=0; nt<5; ++nt){
                bf16x8 vf = *reinterpret_cast<const bf16x8*>(&Vb[(nt*16+q16)*64 + (((kh*4+g) ^ sw7)<<3)]);
                accO[0][nt] = __builtin_amdgcn_mfma_f32_16x16x32_bf16(pf[0][kh], vf, accO[0][nt], 0,0,0);
                accO[1][nt] = __builtin_amdgcn_mfma_f32_16x16x32_bf16(pf[1][kh], vf, accO[1][nt], 0,0,0);
            }

        if(kt < 63){
            // late write-back: wait for the pinned loads (issued ~1000 cyc ago), then ds_write
            asm volatile("s_waitcnt vmcnt(0)" ::: "memory");
            __builtin_amdgcn_sched_barrier(0);
            #pragma unroll
            for(int i=0;i<3;++i) if(i<2 || tid<256){
                if(tid + i*512 < 640){
                    *reinterpret_cast<u32x4*>(&KV[cur^1][lo[i]]) = stg[i];
                } else {
                    uint2 a; a.x = stg[i].x; a.y = stg[i].y;
                    uint2 bq; bq.x = stg[i].z; bq.y = stg[i].w;
                    *reinterpret_cast<uint2*>(&KV[cur^1][lo[i]])  = a;
                    *reinterpret_cast<uint2*>(&KV[cur^1][lo2[i]]) = bq;
                }
                gp[i] += adv[i];
            }
        }
        __syncthreads();
    }

    // epilogue: accO row q' = 4g+j needs l of q' (lives at lanes with lane&15 = q')
    #pragma unroll
    for(int u=0;u<2;++u){
        float linv[4];
        #pragma unroll
        for(int j=0;j<4;++j){
            float lj = __shfl(l[u], (lane & 48) | (4*g + j), 64);
            linv[j] = 1.0f / lj;
        }
        #pragma unroll
        for(int nt=0;nt<5;++nt){
            int d = nt*16 + q16;
            if(d < HDIM){
                #pragma unroll
                for(int j=0;j<4;++j){
                    int t = qbase + u*128 + wid*16 + 4*g + j;
                    AO[((size_t)(b*TT + t))*HIDDEN + h*HDIM + d] = f2b(accO[u][nt][j] * linv[j]);
                }
            }
        }
    }
}

extern "C" void kernel_launch(void* const* d_in, const int* in_sizes, int n_in,
                              void* d_out, int out_size, void* d_ws, size_t ws_size,
                              hipStream_t stream) {
    const float* x  = (const float*)d_in[0];
    const float* wq = (const float*)d_in[1];
    const float* bq = (const float*)d_in[2];
    const float* wk = (const float*)d_in[3];
    const float* bk = (const float*)d_in[4];
    const float* wv = (const float*)d_in[5];
    const float* bv = (const float*)d_in[6];
    const float* wo = (const float*)d_in[7];
    const float* bo = (const float*)d_in[8];

    char* ws = (char*)d_ws;
    const size_t szXb = (size_t)BT*HIDDEN*2;          // 18874368
    const size_t szW  = (size_t)HIDDEN*HIDDEN*2;      // 2654208
    const size_t szQp = (size_t)NB*HEADS*TT*DPAD*2;   // 25165824

    unsigned short* Xb  = (unsigned short*)(ws);
    unsigned short* WTq = (unsigned short*)(ws + szXb);
    unsigned short* WTk = (unsigned short*)(ws + szXb + szW);
    unsigned short* WTv = (unsigned short*)(ws + szXb + 2*szW);
    unsigned short* WTo = (unsigned short*)(ws + szXb + 3*szW);
    unsigned short* Qp  = (unsigned short*)(ws + szXb + 4*szW);
    unsigned short* Kp  = (unsigned short*)(ws + szXb + 4*szW + szQp);
    unsigned short* Vt  = (unsigned short*)(ws + szXb + 4*szW + 2*szQp);
    unsigned short* AO  = (unsigned short*)(ws + szXb + 4*szW + 3*szQp);

    hipMemsetAsync(Qp, 0, 3*szQp, stream);            // zero d-padding of Q, K, V (contiguous)

    k_convert_x<<<BT*HIDDEN/1024, 256, 0, stream>>>(x, Xb);
    k_wtrans<<<324, 256, 0, stream>>>(wq, WTq);
    k_wtrans<<<324, 256, 0, stream>>>(wk, WTk);
    k_wtrans<<<324, 256, 0, stream>>>(wv, WTv);
    k_wtrans<<<324, 256, 0, stream>>>(wo, WTo);

    const float qscale = (1.0f / sqrtf(72.0f)) * 1.44269504f;  // fold log2(e) for exp2 softmax
    k_gemm<0><<<576, 256, 0, stream>>>(Xb, WTq, bq, Qp, qscale);
    k_gemm<1><<<576, 256, 0, stream>>>(Xb, WTk, bk, Kp, 1.0f);
    k_gemm<2><<<576, 256, 0, stream>>>(Xb, WTv, bv, Vt, 1.0f);

    k_attn<<<NB*HEADS*(TT/256), 512, 0, stream>>>(Qp, Kp, Vt, AO);

    k_gemm<3><<<576, 256, 0, stream>>>(AO, WTo, bo, d_out, 1.0f);
}

// Round 15
// 392.026 us; speedup vs baseline: 1.5732x; 1.0043x over previous
//
#include <hip/hip_runtime.h>

#define HIDDEN 1152
#define HEADS  16
#define HDIM   72
#define DPAD   96
#define NB     2
#define TT     4096
#define BT     (NB*TT)  // 8192

#define KSTR2  80      // Ks row stride (shorts): 10 granules of 8
#define VOFF   5120    // Vs offset inside KV buffer (shorts)

typedef float  f32x4   __attribute__((ext_vector_type(4)));
typedef __bf16 bf16x8  __attribute__((ext_vector_type(8)));
typedef unsigned u32x4 __attribute__((ext_vector_type(4)));

static __device__ __forceinline__ unsigned pkbf(float a, float b){
    unsigned r;
    asm("v_cvt_pk_bf16_f32 %0, %1, %2" : "=v"(r) : "v"(a), "v"(b));
    return r;
}
static __device__ __forceinline__ unsigned short f2b(float f){
    return (unsigned short)pkbf(f, f);
}
static __device__ __forceinline__ void gld16(const unsigned short* g, unsigned short* l){
    __builtin_amdgcn_global_load_lds((const __attribute__((address_space(1))) void*)g,
                                     (__attribute__((address_space(3))) void*)l, 16, 0, 0);
}

__global__ __launch_bounds__(256) void k_convert_x(const float* __restrict__ x, unsigned short* __restrict__ xb){
    int i = (blockIdx.x*256 + threadIdx.x) * 4;
    float4 v = *reinterpret_cast<const float4*>(x + i);
    uint2 p; p.x = pkbf(v.x, v.y); p.y = pkbf(v.z, v.w);
    *reinterpret_cast<uint2*>(xb + i) = p;
}

// fused tiled transpose+convert for all 4 weights: w[k][n] (fp32) -> wt[n][k] (bf16)
__global__ __launch_bounds__(256) void k_wtrans(const float* __restrict__ wq, const float* __restrict__ wk,
                                                const float* __restrict__ wv, const float* __restrict__ wo,
                                                unsigned short* __restrict__ wt0){
    __shared__ __align__(16) unsigned short Ws[64][72];
    const int wi = blockIdx.x / 324, bi = blockIdx.x % 324;
    const float* w = wi==0 ? wq : (wi==1 ? wk : (wi==2 ? wv : wo));
    unsigned short* wt = wt0 + (size_t)wi*HIDDEN*HIDDEN;
    const int r0 = (bi / 18) * 64, c0 = (bi % 18) * 64;
    #pragma unroll
    for(int it=0; it<4; ++it){
        int idx = threadIdx.x + it*256;
        int r = idx >> 4, cq = (idx & 15) * 4;
        float4 v = *reinterpret_cast<const float4*>(w + (size_t)(r0+r)*HIDDEN + c0 + cq);
        uint2 p; p.x = pkbf(v.x, v.y); p.y = pkbf(v.z, v.w);
        *reinterpret_cast<uint2*>(&Ws[r][cq]) = p;
    }
    __syncthreads();
    #pragma unroll
    for(int it=0; it<4; ++it){
        int idx = threadIdx.x + it*256;
        int rr = idx >> 4, cq = (idx & 15) * 4;
        ushort4 o;
        o.x = Ws[cq+0][rr]; o.y = Ws[cq+1][rr]; o.z = Ws[cq+2][rr]; o.w = Ws[cq+3][rr];
        *reinterpret_cast<ushort4*>(wt + (size_t)(c0+rr)*HIDDEN + r0 + cq) = o;
    }
}

// Fused QKV GEMM: A = Xb [8192][1152], B^T = WT [3456][1152] (WTq|WTk|WTv contiguous).
// which = block-uniform 0/1/2 selects bias/scale/output layout (verified MODE 0/1/2 epilogues).
__global__ __launch_bounds__(256, 3) void k_gemm_qkv(const unsigned short* __restrict__ A,
                                                     const unsigned short* __restrict__ WT,
                                                     const float* __restrict__ bq,
                                                     const float* __restrict__ bk,
                                                     const float* __restrict__ bv,
                                                     unsigned short* __restrict__ Qp,
                                                     unsigned short* __restrict__ Kp,
                                                     unsigned short* __restrict__ Vt,
                                                     float qscale){
    __shared__ __align__(16) unsigned short As[128*32];
    __shared__ __align__(16) unsigned short Bs[128*32];
    const int tid = threadIdx.x, lane = tid & 63, wid = tid >> 6;
    const int wm = wid >> 1, wn = wid & 1;
    const int half = lane >> 4, q16 = lane & 15;
    int lb = (blockIdx.x & 7) * 216 + (blockIdx.x >> 3);      // XCD-chunked swizzle (1728 = 8*216)
    const int m0 = (lb / 27) * 128;
    const int t9 = lb % 27;
    const int which = t9 / 9;                                  // 0=Q 1=K 2=V (block-uniform)
    const int n0g = t9 * 128;                                  // global col in [0,3456)
    const int cc0 = (t9 % 9) * 128;                            // col within 1152
    const float* bias = which==0 ? bq : (which==1 ? bk : bv);
    const float scale = which==0 ? qscale : 1.0f;
    const int lr = lane >> 2, lc = (lane & 3) * 8;
    const unsigned short* ap = A  + (size_t)(m0  + wid*32 + lr)*HIDDEN + lc;
    const unsigned short* bp = WT + (size_t)(n0g + wid*32 + lr)*HIDDEN + lc;
    unsigned short* as0 = As + (wid*32     )*32 + lane*8;
    unsigned short* as1 = As + (wid*32 + 16)*32 + lane*8;
    unsigned short* bs0 = Bs + (wid*32     )*32 + lane*8;
    unsigned short* bs1 = Bs + (wid*32 + 16)*32 + lane*8;

    f32x4 acc[4][4] = {};
    for(int k0 = 0; k0 < HIDDEN; k0 += 32){
        gld16(ap + k0,             as0);
        gld16(ap + k0 + 16*HIDDEN, as1);
        gld16(bp + k0,             bs0);
        gld16(bp + k0 + 16*HIDDEN, bs1);
        __syncthreads();
        bf16x8 af[4], bf[4];
        #pragma unroll
        for(int mi=0;mi<4;++mi) af[mi] = *reinterpret_cast<const bf16x8*>(As + (wm*64+mi*16+q16)*32 + half*8);
        #pragma unroll
        for(int ni=0;ni<4;++ni) bf[ni] = *reinterpret_cast<const bf16x8*>(Bs + (wn*64+ni*16+q16)*32 + half*8);
        #pragma unroll
        for(int mi=0;mi<4;++mi)
            #pragma unroll
            for(int ni=0;ni<4;++ni)
                acc[mi][ni] = __builtin_amdgcn_mfma_f32_16x16x32_bf16(af[mi], bf[ni], acc[mi][ni], 0,0,0);
        __syncthreads();
    }
    #pragma unroll
    for(int mi=0;mi<4;++mi)
        #pragma unroll
        for(int ni=0;ni<4;++ni)
            #pragma unroll
            for(int j=0;j<4;++j){
                int row = m0 + wm*64 + mi*16 + half*4 + j;   // token index
                int col = cc0 + wn*64 + ni*16 + q16;         // output feature in [0,1152)
                float v = (acc[mi][ni][j] + bias[col]) * scale;
                int bb = row >> 12, t = row & 4095;
                int hh = col / HDIM, d = col % HDIM;
                if(which < 2){
                    unsigned short* outp = which==0 ? Qp : Kp;
                    outp[((size_t)((bb*HEADS + hh)*TT) + t)*DPAD + d] = f2b(v);
                } else {
                    Vt[((size_t)((bb*HEADS + hh)*DPAD) + d)*TT + t] = f2b(v);
                }
            }
}

// O-projection GEMM: fp32 out + bias
__global__ __launch_bounds__(256, 3) void k_gemm_o(const unsigned short* __restrict__ A,
                                                   const unsigned short* __restrict__ Bt,
                                                   const float* __restrict__ bias,
                                                   float* __restrict__ out){
    __shared__ __align__(16) unsigned short As[128*32];
    __shared__ __align__(16) unsigned short Bs[128*32];
    const int tid = threadIdx.x, lane = tid & 63, wid = tid >> 6;
    const int wm = wid >> 1, wn = wid & 1;
    const int half = lane >> 4, q16 = lane & 15;
    int lb = (blockIdx.x & 7) * 72 + (blockIdx.x >> 3);       // XCD-chunked swizzle (576 = 8*72)
    const int n0 = (lb % 9) * 128, m0 = (lb / 9) * 128;
    const int lr = lane >> 2, lc = (lane & 3) * 8;
    const unsigned short* ap = A  + (size_t)(m0 + wid*32 + lr)*HIDDEN + lc;
    const unsigned short* bp = Bt + (size_t)(n0 + wid*32 + lr)*HIDDEN + lc;
    unsigned short* as0 = As + (wid*32     )*32 + lane*8;
    unsigned short* as1 = As + (wid*32 + 16)*32 + lane*8;
    unsigned short* bs0 = Bs + (wid*32     )*32 + lane*8;
    unsigned short* bs1 = Bs + (wid*32 + 16)*32 + lane*8;

    f32x4 acc[4][4] = {};
    for(int k0 = 0; k0 < HIDDEN; k0 += 32){
        gld16(ap + k0,             as0);
        gld16(ap + k0 + 16*HIDDEN, as1);
        gld16(bp + k0,             bs0);
        gld16(bp + k0 + 16*HIDDEN, bs1);
        __syncthreads();
        bf16x8 af[4], bf[4];
        #pragma unroll
        for(int mi=0;mi<4;++mi) af[mi] = *reinterpret_cast<const bf16x8*>(As + (wm*64+mi*16+q16)*32 + half*8);
        #pragma unroll
        for(int ni=0;ni<4;++ni) bf[ni] = *reinterpret_cast<const bf16x8*>(Bs + (wn*64+ni*16+q16)*32 + half*8);
        #pragma unroll
        for(int mi=0;mi<4;++mi)
            #pragma unroll
            for(int ni=0;ni<4;++ni)
                acc[mi][ni] = __builtin_amdgcn_mfma_f32_16x16x32_bf16(af[mi], bf[ni], acc[mi][ni], 0,0,0);
        __syncthreads();
    }
    #pragma unroll
    for(int mi=0;mi<4;++mi)
        #pragma unroll
        for(int ni=0;ni<4;++ni)
            #pragma unroll
            for(int j=0;j<4;++j){
                int row = m0 + wm*64 + mi*16 + half*4 + j;
                int col = n0 + wn*64 + ni*16 + q16;
                out[(size_t)row*HIDDEN + col] = acc[mi][ni][j] + bias[col];
            }
}

// flash attention: swapped QK^T 16x16 core, asm-pinned async staging, 1 barrier/iter.
// Zero-shuffle PV via sigma-permuted V columns; 8 waves x 256 q-rows/block. (byte-identical to R14)
__global__ __launch_bounds__(512, 2) void k_attn(const unsigned short* __restrict__ Qp,
                                                 const unsigned short* __restrict__ Kp,
                                                 const unsigned short* __restrict__ Vt,
                                                 unsigned short* __restrict__ AO){
    __shared__ __align__(16) unsigned short KV[2][10240];   // [K 64x80 | V 80x64] per buf = 40 KB total
    const int tid  = threadIdx.x;
    const int lane = tid & 63, wid = tid >> 6;              // wid in [0,8)
    const int g    = lane >> 4, q16 = lane & 15;
    const int sw7  = q16 & 7;

    int lb = ((blockIdx.x & 7) << 6) | (blockIdx.x >> 3);   // XCD-chunked (512 = 8*64)
    const int qt = lb & 15, h = (lb >> 4) & 15, b = lb >> 8;
    const int qbase = qt * 256;
    const int bh = b*HEADS + h;

    const unsigned short* kbase = Kp + (size_t)(bh*TT) * DPAD;
    const unsigned short* vbase = Vt + (size_t)(bh*DPAD) * TT;

    // per-thread staging slots: 1280 chunks over 512 threads (3rd iter: tid<256 only, wave-uniform)
    const unsigned short* gp[3]; int lo[3], lo2[3], adv[3];
    #pragma unroll
    for(int i=0;i<3;++i){
        int c = tid + i*512; if(c > 1279) c = 1279;          // clamped; guarded at use
        if(c < 640){
            int r = c/10, ch = c - r*10;
            int phys = (ch < 8) ? (ch ^ (r&7)) : (8 + ((ch&1) ^ (r&1)));
            lo[i]  = r*KSTR2 + (phys<<3);
            lo2[i] = lo[i];
            gp[i]  = kbase + (size_t)r*DPAD + ch*8;
            adv[i] = 64*DPAD;
        } else {
            int c2 = c - 640, d = c2>>3, ch = c2&7;
            int kh = ch>>2, thi = (ch>>1)&1, g0 = 4*kh + 2*(ch&1);
            lo[i]  = VOFF + d*64 + (((g0  ) ^ (d&7))<<3) + 4*thi;   // kv pairs (w=0..3)
            lo2[i] = VOFF + d*64 + (((g0+1) ^ (d&7))<<3) + 4*thi;   // kv pairs (w=4..7)
            gp[i]  = vbase + (size_t)d*TT + ch*8;
            adv[i] = 64;
        }
    }

    // Q fragments: 2 q-subtiles x 16 rows per wave; B-operand row q=q16, k-slot g*8+e
    bf16x8 qf[2][3];
    #pragma unroll
    for(int u=0;u<2;++u){
        const unsigned short* qptr = Qp + ((size_t)(bh*TT) + qbase + u*128 + wid*16 + q16) * DPAD;
        #pragma unroll
        for(int kk=0;kk<3;++kk) qf[u][kk] = *reinterpret_cast<const bf16x8*>(qptr + kk*32 + g*8);
    }

    f32x4 accO[2][5] = {};
    float m[2] = {-1e30f, -1e30f};
    float l[2] = {0.f, 0.f};

    // prologue: stage tile 0 into buf 0
    u32x4 stg[3];
    #pragma unroll
    for(int i=0;i<3;++i) if(i<2 || tid<256) stg[i] = *reinterpret_cast<const u32x4*>(gp[i]);
    #pragma unroll
    for(int i=0;i<3;++i) if(i<2 || tid<256){
        if(tid + i*512 < 640){
            *reinterpret_cast<u32x4*>(&KV[0][lo[i]]) = stg[i];
        } else {
            uint2 a; a.x = stg[i].x; a.y = stg[i].y;
            uint2 bq; bq.x = stg[i].z; bq.y = stg[i].w;
            *reinterpret_cast<uint2*>(&KV[0][lo[i]])  = a;
            *reinterpret_cast<uint2*>(&KV[0][lo2[i]]) = bq;
        }
        gp[i] += adv[i];
    }
    __syncthreads();

    for(int kt = 0; kt < 64; ++kt){
        const int cur = kt & 1;
        if(kt < 63){
            #pragma unroll
            for(int i=0;i<3;++i) if(i<2 || tid<256)
                asm volatile("global_load_dwordx4 %0, %1, off"
                             : "=v"(stg[i]) : "v"(gp[i]) : "memory");
        }
        const unsigned short* Kb = KV[cur];
        const unsigned short* Vb = KV[cur] + VOFF;

        // S^T[kv][q] = mfma(A=K, B=Q): lane holds col q=q16, rows kv = 16t + 4g + j
        f32x4 s[2][4] = {};
        #pragma unroll
        for(int t=0;t<4;++t){
            const int row = t*16 + q16;
            bf16x8 kf0 = *reinterpret_cast<const bf16x8*>(&Kb[row*KSTR2 + ((g     ^ sw7)<<3)]);
            bf16x8 kf1 = *reinterpret_cast<const bf16x8*>(&Kb[row*KSTR2 + (((4+g) ^ sw7)<<3)]);
            bf16x8 kf2 = *reinterpret_cast<const bf16x8*>(&Kb[row*KSTR2 + ((8 + ((g&1) ^ (row&1)))<<3)]);
            s[0][t] = __builtin_amdgcn_mfma_f32_16x16x32_bf16(kf0, qf[0][0], s[0][t], 0,0,0);
            s[1][t] = __builtin_amdgcn_mfma_f32_16x16x32_bf16(kf0, qf[1][0], s[1][t], 0,0,0);
            s[0][t] = __builtin_amdgcn_mfma_f32_16x16x32_bf16(kf1, qf[0][1], s[0][t], 0,0,0);
            s[1][t] = __builtin_amdgcn_mfma_f32_16x16x32_bf16(kf1, qf[1][1], s[1][t], 0,0,0);
            s[0][t] = __builtin_amdgcn_mfma_f32_16x16x32_bf16(kf2, qf[0][2], s[0][t], 0,0,0);
            s[1][t] = __builtin_amdgcn_mfma_f32_16x16x32_bf16(kf2, qf[1][2], s[1][t], 0,0,0);
        }

        bf16x8 pf[2][2];
        #pragma unroll
        for(int u=0;u<2;++u){
            float tm = fmaxf(fmaxf(s[u][0][0], s[u][0][1]), s[u][0][2]);
            tm = fmaxf(fmaxf(tm, s[u][0][3]), s[u][1][0]);
            tm = fmaxf(fmaxf(tm, s[u][1][1]), s[u][1][2]);
            tm = fmaxf(fmaxf(tm, s[u][1][3]), s[u][2][0]);
            tm = fmaxf(fmaxf(tm, s[u][2][1]), s[u][2][2]);
            tm = fmaxf(fmaxf(tm, s[u][2][3]), s[u][3][0]);
            tm = fmaxf(fmaxf(tm, s[u][3][1]), s[u][3][2]);
            tm = fmaxf(tm, s[u][3][3]);
            tm = fmaxf(tm, __shfl_xor(tm, 16, 64));
            tm = fmaxf(tm, __shfl_xor(tm, 32, 64));
            if(__any(tm > m[u] + 8.0f)){                       // defer-max rescale (log2 domain)
                float mn = fmaxf(m[u], tm);
                float al = __builtin_amdgcn_exp2f(m[u] - mn);
                l[u] *= al;  m[u] = mn;
                float aj[4];
                #pragma unroll
                for(int j=0;j<4;++j) aj[j] = __shfl(al, (lane & 48) | (4*g + j), 64);
                #pragma unroll
                for(int nt=0;nt<5;++nt)
                    #pragma unroll
                    for(int j=0;j<4;++j) accO[u][nt][j] *= aj[j];
            }
            unsigned dwA[4], dwB[4];
            float sum = 0.f;
            #pragma unroll
            for(int t4=0;t4<4;++t4){
                float p0 = __builtin_amdgcn_exp2f(s[u][t4][0] - m[u]);
                float p1 = __builtin_amdgcn_exp2f(s[u][t4][1] - m[u]);
                float p2 = __builtin_amdgcn_exp2f(s[u][t4][2] - m[u]);
                float p3 = __builtin_amdgcn_exp2f(s[u][t4][3] - m[u]);
                sum += (p0 + p1) + (p2 + p3);
                dwA[t4] = pkbf(p0, p1);
                dwB[t4] = pkbf(p2, p3);
            }
            sum += __shfl_xor(sum, 16, 64);
            sum += __shfl_xor(sum, 32, 64);
            l[u] += sum;
            union { unsigned w[4]; bf16x8 v; } pu0, pu1;
            pu0.w[0]=dwA[0]; pu0.w[1]=dwB[0]; pu0.w[2]=dwA[1]; pu0.w[3]=dwB[1];
            pu1.w[0]=dwA[2]; pu1.w[1]=dwB[2]; pu1.w[2]=dwA[3]; pu1.w[3]=dwB[3];
            pf[u][0] = pu0.v;  pf[u][1] = pu1.v;
        }

        // PV: vf loaded ONCE per (kh,nt), feeds both q-subtiles
        #pragma unroll
        for(int kh=0; kh<2; ++kh)
            #pragma unroll
            for(int nt=0; nt<5; ++nt){
                bf16x8 vf = *reinterpret_cast<const bf16x8*>(&Vb[(nt*16+q16)*64 + (((kh*4+g) ^ sw7)<<3)]);
                accO[0][nt] = __builtin_amdgcn_mfma_f32_16x16x32_bf16(pf[0][kh], vf, accO[0][nt], 0,0,0);
                accO[1][nt] = __builtin_amdgcn_mfma_f32_16x16x32_bf16(pf[1][kh], vf, accO[1][nt], 0,0,0);
            }

        if(kt < 63){
            asm volatile("s_waitcnt vmcnt(0)" ::: "memory");
            __builtin_amdgcn_sched_barrier(0);
            #pragma unroll
            for(int i=0;i<3;++i) if(i<2 || tid<256){
                if(tid + i*512 < 640){
                    *reinterpret_cast<u32x4*>(&KV[cur^1][lo[i]]) = stg[i];
                } else {
                    uint2 a; a.x = stg[i].x; a.y = stg[i].y;
                    uint2 bq; bq.x = stg[i].z; bq.y = stg[i].w;
                    *reinterpret_cast<uint2*>(&KV[cur^1][lo[i]])  = a;
                    *reinterpret_cast<uint2*>(&KV[cur^1][lo2[i]]) = bq;
                }
                gp[i] += adv[i];
            }
        }
        __syncthreads();
    }

    // epilogue: accO row q' = 4g+j needs l of q' (lives at lanes with lane&15 = q')
    #pragma unroll
    for(int u=0;u<2;++u){
        float linv[4];
        #pragma unroll
        for(int j=0;j<4;++j){
            float lj = __shfl(l[u], (lane & 48) | (4*g + j), 64);
            linv[j] = 1.0f / lj;
        }
        #pragma unroll
        for(int nt=0;nt<5;++nt){
            int d = nt*16 + q16;
            if(d < HDIM){
                #pragma unroll
                for(int j=0;j<4;++j){
                    int t = qbase + u*128 + wid*16 + 4*g + j;
                    AO[((size_t)(b*TT + t))*HIDDEN + h*HDIM + d] = f2b(accO[u][nt][j] * linv[j]);
                }
            }
        }
    }
}

extern "C" void kernel_launch(void* const* d_in, const int* in_sizes, int n_in,
                              void* d_out, int out_size, void* d_ws, size_t ws_size,
                              hipStream_t stream) {
    const float* x  = (const float*)d_in[0];
    const float* wq = (const float*)d_in[1];
    const float* bq = (const float*)d_in[2];
    const float* wk = (const float*)d_in[3];
    const float* bk = (const float*)d_in[4];
    const float* wv = (const float*)d_in[5];
    const float* bv = (const float*)d_in[6];
    const float* wo = (const float*)d_in[7];
    const float* bo = (const float*)d_in[8];

    char* ws = (char*)d_ws;
    const size_t szXb = (size_t)BT*HIDDEN*2;          // 18874368
    const size_t szW  = (size_t)HIDDEN*HIDDEN*2;      // 2654208
    const size_t szQp = (size_t)NB*HEADS*TT*DPAD*2;   // 25165824

    unsigned short* Xb  = (unsigned short*)(ws);
    unsigned short* WTq = (unsigned short*)(ws + szXb);   // WTq|WTk|WTv|WTo contiguous
    unsigned short* WTo = (unsigned short*)(ws + szXb + 3*szW);
    unsigned short* Qp  = (unsigned short*)(ws + szXb + 4*szW);
    unsigned short* Kp  = (unsigned short*)(ws + szXb + 4*szW + szQp);
    unsigned short* Vt  = (unsigned short*)(ws + szXb + 4*szW + 2*szQp);
    unsigned short* AO  = (unsigned short*)(ws + szXb + 4*szW + 3*szQp);

    hipMemsetAsync(Qp, 0, 3*szQp, stream);            // zero d-padding of Q, K, V (contiguous)

    k_convert_x<<<BT*HIDDEN/1024, 256, 0, stream>>>(x, Xb);
    k_wtrans<<<1296, 256, 0, stream>>>(wq, wk, wv, wo, WTq);

    const float qscale = (1.0f / sqrtf(72.0f)) * 1.44269504f;  // fold log2(e) for exp2 softmax
    k_gemm_qkv<<<1728, 256, 0, stream>>>(Xb, WTq, bq, bk, bv, Qp, Kp, Vt, qscale);

    k_attn<<<NB*HEADS*(TT/256), 512, 0, stream>>>(Qp, Kp, Vt, AO);

    k_gemm_o<<<576, 256, 0, stream>>>(AO, WTo, bo, (float*)d_out);
}

// Round 16
// 376.951 us; speedup vs baseline: 1.6361x; 1.0400x over previous
//
#include <hip/hip_runtime.h>

#define HIDDEN 1152
#define HEADS  16
#define HDIM   72
#define DPAD   96
#define NB     2
#define TT     4096
#define BT     (NB*TT)  // 8192

#define KSTR2  80      // Ks row stride (shorts): 10 granules of 8
#define VOFF   5120    // Vs offset inside KV buffer (shorts)

typedef float  f32x4   __attribute__((ext_vector_type(4)));
typedef __bf16 bf16x8  __attribute__((ext_vector_type(8)));
typedef unsigned u32x4 __attribute__((ext_vector_type(4)));

static __device__ __forceinline__ unsigned pkbf(float a, float b){
    unsigned r;
    asm("v_cvt_pk_bf16_f32 %0, %1, %2" : "=v"(r) : "v"(a), "v"(b));
    return r;
}
static __device__ __forceinline__ unsigned short f2b(float f){
    return (unsigned short)pkbf(f, f);
}
static __device__ __forceinline__ void gld16(const unsigned short* g, unsigned short* l){
    __builtin_amdgcn_global_load_lds((const __attribute__((address_space(1))) void*)g,
                                     (__attribute__((address_space(3))) void*)l, 16, 0, 0);
}

__global__ __launch_bounds__(256) void k_convert_x(const float* __restrict__ x, unsigned short* __restrict__ xb){
    int i = (blockIdx.x*256 + threadIdx.x) * 4;
    float4 v = *reinterpret_cast<const float4*>(x + i);
    uint2 p; p.x = pkbf(v.x, v.y); p.y = pkbf(v.z, v.w);
    *reinterpret_cast<uint2*>(xb + i) = p;
}

// fused tiled transpose+convert for all 4 weights: w[k][n] (fp32) -> wt[n][k] (bf16)
__global__ __launch_bounds__(256) void k_wtrans(const float* __restrict__ wq, const float* __restrict__ wk,
                                                const float* __restrict__ wv, const float* __restrict__ wo,
                                                unsigned short* __restrict__ wt0){
    __shared__ __align__(16) unsigned short Ws[64][72];
    const int wi = blockIdx.x / 324, bi = blockIdx.x % 324;
    const float* w = wi==0 ? wq : (wi==1 ? wk : (wi==2 ? wv : wo));
    unsigned short* wt = wt0 + (size_t)wi*HIDDEN*HIDDEN;
    const int r0 = (bi / 18) * 64, c0 = (bi % 18) * 64;
    #pragma unroll
    for(int it=0; it<4; ++it){
        int idx = threadIdx.x + it*256;
        int r = idx >> 4, cq = (idx & 15) * 4;
        float4 v = *reinterpret_cast<const float4*>(w + (size_t)(r0+r)*HIDDEN + c0 + cq);
        uint2 p; p.x = pkbf(v.x, v.y); p.y = pkbf(v.z, v.w);
        *reinterpret_cast<uint2*>(&Ws[r][cq]) = p;
    }
    __syncthreads();
    #pragma unroll
    for(int it=0; it<4; ++it){
        int idx = threadIdx.x + it*256;
        int rr = idx >> 4, cq = (idx & 15) * 4;
        ushort4 o;
        o.x = Ws[cq+0][rr]; o.y = Ws[cq+1][rr]; o.z = Ws[cq+2][rr]; o.w = Ws[cq+3][rr];
        *reinterpret_cast<ushort4*>(wt + (size_t)(c0+rr)*HIDDEN + r0 + cq) = o;
    }
}

// Fused QKV GEMM: A = Xb [8192][1152], B^T = WT [3456][1152] (WTq|WTk|WTv contiguous).
// which = block-uniform 0/1/2; V epilogue transposes through LDS for coalesced [d][t] writes.
__global__ __launch_bounds__(256, 3) void k_gemm_qkv(const unsigned short* __restrict__ A,
                                                     const unsigned short* __restrict__ WT,
                                                     const float* __restrict__ bq,
                                                     const float* __restrict__ bk,
                                                     const float* __restrict__ bv,
                                                     unsigned short* __restrict__ Qp,
                                                     unsigned short* __restrict__ Kp,
                                                     unsigned short* __restrict__ Vt,
                                                     float qscale){
    __shared__ __align__(16) unsigned short S[8192];          // As|Bs in K-loop; V-transpose tile after
    unsigned short* As = S;
    unsigned short* Bs = S + 4096;
    const int tid = threadIdx.x, lane = tid & 63, wid = tid >> 6;
    const int wm = wid >> 1, wn = wid & 1;
    const int half = lane >> 4, q16 = lane & 15;
    int lb = (blockIdx.x & 7) * 216 + (blockIdx.x >> 3);      // XCD-chunked swizzle (1728 = 8*216)
    const int m0 = (lb / 27) * 128;
    const int t9 = lb % 27;
    const int which = t9 / 9;                                  // 0=Q 1=K 2=V (block-uniform)
    const int n0g = t9 * 128;                                  // global col in [0,3456)
    const int cc0 = (t9 % 9) * 128;                            // col within 1152
    const float* bias = which==0 ? bq : (which==1 ? bk : bv);
    const float scale = which==0 ? qscale : 1.0f;
    const int lr = lane >> 2, lc = (lane & 3) * 8;
    const unsigned short* ap = A  + (size_t)(m0  + wid*32 + lr)*HIDDEN + lc;
    const unsigned short* bp = WT + (size_t)(n0g + wid*32 + lr)*HIDDEN + lc;
    unsigned short* as0 = As + (wid*32     )*32 + lane*8;
    unsigned short* as1 = As + (wid*32 + 16)*32 + lane*8;
    unsigned short* bs0 = Bs + (wid*32     )*32 + lane*8;
    unsigned short* bs1 = Bs + (wid*32 + 16)*32 + lane*8;

    f32x4 acc[4][4] = {};
    for(int k0 = 0; k0 < HIDDEN; k0 += 32){
        gld16(ap + k0,             as0);
        gld16(ap + k0 + 16*HIDDEN, as1);
        gld16(bp + k0,             bs0);
        gld16(bp + k0 + 16*HIDDEN, bs1);
        __syncthreads();
        bf16x8 af[4], bf[4];
        #pragma unroll
        for(int mi=0;mi<4;++mi) af[mi] = *reinterpret_cast<const bf16x8*>(As + (wm*64+mi*16+q16)*32 + half*8);
        #pragma unroll
        for(int ni=0;ni<4;++ni) bf[ni] = *reinterpret_cast<const bf16x8*>(Bs + (wn*64+ni*16+q16)*32 + half*8);
        #pragma unroll
        for(int mi=0;mi<4;++mi)
            #pragma unroll
            for(int ni=0;ni<4;++ni)
                acc[mi][ni] = __builtin_amdgcn_mfma_f32_16x16x32_bf16(af[mi], bf[ni], acc[mi][ni], 0,0,0);
        __syncthreads();
    }
    if(which < 2){
        unsigned short* outp = which==0 ? Qp : Kp;
        #pragma unroll
        for(int mi=0;mi<4;++mi)
            #pragma unroll
            for(int ni=0;ni<4;++ni)
                #pragma unroll
                for(int j=0;j<4;++j){
                    int row = m0 + wm*64 + mi*16 + half*4 + j;
                    int col = cc0 + wn*64 + ni*16 + q16;
                    float v = (acc[mi][ni][j] + bias[col]) * scale;
                    int bb = row >> 12, t = row & 4095;
                    int hh = col / HDIM, d = col % HDIM;
                    outp[((size_t)((bb*HEADS + hh)*TT) + t)*DPAD + d] = f2b(v);
                }
    } else {
        // V: transpose 128x128 tile through LDS (two 64-row passes) for coalesced [d][t] stores
        #pragma unroll
        for(int ph=0; ph<2; ++ph){
            if(wm == ph){
                #pragma unroll
                for(int mi=0;mi<4;++mi)
                    #pragma unroll
                    for(int ni=0;ni<4;++ni)
                        #pragma unroll
                        for(int j=0;j<4;++j){
                            int rloc = mi*16 + half*4 + j;            // 0..63 within this row-half
                            int cloc = wn*64 + ni*16 + q16;           // 0..127
                            float v = acc[mi][ni][j] + bias[cc0 + cloc];
                            S[cloc*64 + (rloc ^ ((cloc&7)<<3))] = f2b(v);
                        }
            }
            __syncthreads();
            {
                int col = tid >> 1, seg = tid & 1;
                int gcol = cc0 + col, hh = gcol / HDIM, d = gcol % HDIM;
                int grow = m0 + ph*64 + seg*32;
                int bb = grow >> 12, t0 = grow & 4095;
                unsigned short* dst = Vt + ((size_t)((bb*HEADS + hh)*DPAD) + d)*TT + t0;
                #pragma unroll
                for(int kg=0; kg<4; ++kg){
                    uint4 v = *reinterpret_cast<const uint4*>(&S[col*64 + ((seg*32 + kg*8) ^ ((col&7)<<3))]);
                    *reinterpret_cast<uint4*>(dst + kg*8) = v;
                }
            }
            __syncthreads();
        }
    }
}

// O-projection GEMM: fp32 out + bias
__global__ __launch_bounds__(256, 3) void k_gemm_o(const unsigned short* __restrict__ A,
                                                   const unsigned short* __restrict__ Bt,
                                                   const float* __restrict__ bias,
                                                   float* __restrict__ out){
    __shared__ __align__(16) unsigned short As[128*32];
    __shared__ __align__(16) unsigned short Bs[128*32];
    const int tid = threadIdx.x, lane = tid & 63, wid = tid >> 6;
    const int wm = wid >> 1, wn = wid & 1;
    const int half = lane >> 4, q16 = lane & 15;
    int lb = (blockIdx.x & 7) * 72 + (blockIdx.x >> 3);       // XCD-chunked swizzle (576 = 8*72)
    const int n0 = (lb % 9) * 128, m0 = (lb / 9) * 128;
    const int lr = lane >> 2, lc = (lane & 3) * 8;
    const unsigned short* ap = A  + (size_t)(m0 + wid*32 + lr)*HIDDEN + lc;
    const unsigned short* bp = Bt + (size_t)(n0 + wid*32 + lr)*HIDDEN + lc;
    unsigned short* as0 = As + (wid*32     )*32 + lane*8;
    unsigned short* as1 = As + (wid*32 + 16)*32 + lane*8;
    unsigned short* bs0 = Bs + (wid*32     )*32 + lane*8;
    unsigned short* bs1 = Bs + (wid*32 + 16)*32 + lane*8;

    f32x4 acc[4][4] = {};
    for(int k0 = 0; k0 < HIDDEN; k0 += 32){
        gld16(ap + k0,             as0);
        gld16(ap + k0 + 16*HIDDEN, as1);
        gld16(bp + k0,             bs0);
        gld16(bp + k0 + 16*HIDDEN, bs1);
        __syncthreads();
        bf16x8 af[4], bf[4];
        #pragma unroll
        for(int mi=0;mi<4;++mi) af[mi] = *reinterpret_cast<const bf16x8*>(As + (wm*64+mi*16+q16)*32 + half*8);
        #pragma unroll
        for(int ni=0;ni<4;++ni) bf[ni] = *reinterpret_cast<const bf16x8*>(Bs + (wn*64+ni*16+q16)*32 + half*8);
        #pragma unroll
        for(int mi=0;mi<4;++mi)
            #pragma unroll
            for(int ni=0;ni<4;++ni)
                acc[mi][ni] = __builtin_amdgcn_mfma_f32_16x16x32_bf16(af[mi], bf[ni], acc[mi][ni], 0,0,0);
        __syncthreads();
    }
    #pragma unroll
    for(int mi=0;mi<4;++mi)
        #pragma unroll
        for(int ni=0;ni<4;++ni)
            #pragma unroll
            for(int j=0;j<4;++j){
                int row = m0 + wm*64 + mi*16 + half*4 + j;
                int col = n0 + wn*64 + ni*16 + q16;
                out[(size_t)row*HIDDEN + col] = acc[mi][ni][j] + bias[col];
            }
}

// flash attention: swapped QK^T 16x16 core, asm-pinned async staging, 1 barrier/iter.
// Zero-shuffle PV via sigma-permuted V columns; s_setprio(1) around MFMA clusters (T5).
__global__ __launch_bounds__(512, 2) void k_attn(const unsigned short* __restrict__ Qp,
                                                 const unsigned short* __restrict__ Kp,
                                                 const unsigned short* __restrict__ Vt,
                                                 unsigned short* __restrict__ AO){
    __shared__ __align__(16) unsigned short KV[2][10240];   // [K 64x80 | V 80x64] per buf = 40 KB total
    const int tid  = threadIdx.x;
    const int lane = tid & 63, wid = tid >> 6;              // wid in [0,8)
    const int g    = lane >> 4, q16 = lane & 15;
    const int sw7  = q16 & 7;

    int lb = ((blockIdx.x & 7) << 6) | (blockIdx.x >> 3);   // XCD-chunked (512 = 8*64)
    const int qt = lb & 15, h = (lb >> 4) & 15, b = lb >> 8;
    const int qbase = qt * 256;
    const int bh = b*HEADS + h;

    const unsigned short* kbase = Kp + (size_t)(bh*TT) * DPAD;
    const unsigned short* vbase = Vt + (size_t)(bh*DPAD) * TT;

    // per-thread staging slots: 1280 chunks over 512 threads (3rd iter: tid<256 only, wave-uniform)
    const unsigned short* gp[3]; int lo[3], lo2[3], adv[3];
    #pragma unroll
    for(int i=0;i<3;++i){
        int c = tid + i*512; if(c > 1279) c = 1279;          // clamped; guarded at use
        if(c < 640){
            int r = c/10, ch = c - r*10;
            int phys = (ch < 8) ? (ch ^ (r&7)) : (8 + ((ch&1) ^ (r&1)));
            lo[i]  = r*KSTR2 + (phys<<3);
            lo2[i] = lo[i];
            gp[i]  = kbase + (size_t)r*DPAD + ch*8;
            adv[i] = 64*DPAD;
        } else {
            int c2 = c - 640, d = c2>>3, ch = c2&7;
            int kh = ch>>2, thi = (ch>>1)&1, g0 = 4*kh + 2*(ch&1);
            lo[i]  = VOFF + d*64 + (((g0  ) ^ (d&7))<<3) + 4*thi;   // kv pairs (w=0..3)
            lo2[i] = VOFF + d*64 + (((g0+1) ^ (d&7))<<3) + 4*thi;   // kv pairs (w=4..7)
            gp[i]  = vbase + (size_t)d*TT + ch*8;
            adv[i] = 64;
        }
    }

    // Q fragments: 2 q-subtiles x 16 rows per wave; B-operand row q=q16, k-slot g*8+e
    bf16x8 qf[2][3];
    #pragma unroll
    for(int u=0;u<2;++u){
        const unsigned short* qptr = Qp + ((size_t)(bh*TT) + qbase + u*128 + wid*16 + q16) * DPAD;
        #pragma unroll
        for(int kk=0;kk<3;++kk) qf[u][kk] = *reinterpret_cast<const bf16x8*>(qptr + kk*32 + g*8);
    }

    f32x4 accO[2][5] = {};
    float m[2] = {-1e30f, -1e30f};
    float l[2] = {0.f, 0.f};

    // prologue: stage tile 0 into buf 0
    u32x4 stg[3];
    #pragma unroll
    for(int i=0;i<3;++i) if(i<2 || tid<256) stg[i] = *reinterpret_cast<const u32x4*>(gp[i]);
    #pragma unroll
    for(int i=0;i<3;++i) if(i<2 || tid<256){
        if(tid + i*512 < 640){
            *reinterpret_cast<u32x4*>(&KV[0][lo[i]]) = stg[i];
        } else {
            uint2 a; a.x = stg[i].x; a.y = stg[i].y;
            uint2 bq; bq.x = stg[i].z; bq.y = stg[i].w;
            *reinterpret_cast<uint2*>(&KV[0][lo[i]])  = a;
            *reinterpret_cast<uint2*>(&KV[0][lo2[i]]) = bq;
        }
        gp[i] += adv[i];
    }
    __syncthreads();

    for(int kt = 0; kt < 64; ++kt){
        const int cur = kt & 1;
        if(kt < 63){
            #pragma unroll
            for(int i=0;i<3;++i) if(i<2 || tid<256)
                asm volatile("global_load_dwordx4 %0, %1, off"
                             : "=v"(stg[i]) : "v"(gp[i]) : "memory");
        }
        const unsigned short* Kb = KV[cur];
        const unsigned short* Vb = KV[cur] + VOFF;

        // S^T[kv][q] = mfma(A=K, B=Q): lane holds col q=q16, rows kv = 16t + 4g + j
        f32x4 s[2][4] = {};
        __builtin_amdgcn_s_setprio(1);
        #pragma unroll
        for(int t=0;t<4;++t){
            const int row = t*16 + q16;
            bf16x8 kf0 = *reinterpret_cast<const bf16x8*>(&Kb[row*KSTR2 + ((g     ^ sw7)<<3)]);
            bf16x8 kf1 = *reinterpret_cast<const bf16x8*>(&Kb[row*KSTR2 + (((4+g) ^ sw7)<<3)]);
            bf16x8 kf2 = *reinterpret_cast<const bf16x8*>(&Kb[row*KSTR2 + ((8 + ((g&1) ^ (row&1)))<<3)]);
            s[0][t] = __builtin_amdgcn_mfma_f32_16x16x32_bf16(kf0, qf[0][0], s[0][t], 0,0,0);
            s[1][t] = __builtin_amdgcn_mfma_f32_16x16x32_bf16(kf0, qf[1][0], s[1][t], 0,0,0);
            s[0][t] = __builtin_amdgcn_mfma_f32_16x16x32_bf16(kf1, qf[0][1], s[0][t], 0,0,0);
            s[1][t] = __builtin_amdgcn_mfma_f32_16x16x32_bf16(kf1, qf[1][1], s[1][t], 0,0,0);
            s[0][t] = __builtin_amdgcn_mfma_f32_16x16x32_bf16(kf2, qf[0][2], s[0][t], 0,0,0);
            s[1][t] = __builtin_amdgcn_mfma_f32_16x16x32_bf16(kf2, qf[1][2], s[1][t], 0,0,0);
        }
        __builtin_amdgcn_s_setprio(0);

        bf16x8 pf[2][2];
        #pragma unroll
        for(int u=0;u<2;++u){
            float tm = fmaxf(fmaxf(s[u][0][0], s[u][0][1]), s[u][0][2]);
            tm = fmaxf(fmaxf(tm, s[u][0][3]), s[u][1][0]);
            tm = fmaxf(fmaxf(tm, s[u][1][1]), s[u][1][2]);
            tm = fmaxf(fmaxf(tm, s[u][1][3]), s[u][2][0]);
            tm = fmaxf(fmaxf(tm, s[u][2][1]), s[u][2][2]);
            tm = fmaxf(fmaxf(tm, s[u][2][3]), s[u][3][0]);
            tm = fmaxf(fmaxf(tm, s[u][3][1]), s[u][3][2]);
            tm = fmaxf(tm, s[u][3][3]);
            tm = fmaxf(tm, __shfl_xor(tm, 16, 64));
            tm = fmaxf(tm, __shfl_xor(tm, 32, 64));
            if(__any(tm > m[u] + 8.0f)){                       // defer-max rescale (log2 domain)
                float mn = fmaxf(m[u], tm);
                float al = __builtin_amdgcn_exp2f(m[u] - mn);
                l[u] *= al;  m[u] = mn;
                float aj[4];
                #pragma unroll
                for(int j=0;j<4;++j) aj[j] = __shfl(al, (lane & 48) | (4*g + j), 64);
                #pragma unroll
                for(int nt=0;nt<5;++nt)
                    #pragma unroll
                    for(int j=0;j<4;++j) accO[u][nt][j] *= aj[j];
            }
            unsigned dwA[4], dwB[4];
            float sum = 0.f;
            #pragma unroll
            for(int t4=0;t4<4;++t4){
                float p0 = __builtin_amdgcn_exp2f(s[u][t4][0] - m[u]);
                float p1 = __builtin_amdgcn_exp2f(s[u][t4][1] - m[u]);
                float p2 = __builtin_amdgcn_exp2f(s[u][t4][2] - m[u]);
                float p3 = __builtin_amdgcn_exp2f(s[u][t4][3] - m[u]);
                sum += (p0 + p1) + (p2 + p3);
                dwA[t4] = pkbf(p0, p1);
                dwB[t4] = pkbf(p2, p3);
            }
            sum += __shfl_xor(sum, 16, 64);
            sum += __shfl_xor(sum, 32, 64);
            l[u] += sum;
            union { unsigned w[4]; bf16x8 v; } pu0, pu1;
            pu0.w[0]=dwA[0]; pu0.w[1]=dwB[0]; pu0.w[2]=dwA[1]; pu0.w[3]=dwB[1];
            pu1.w[0]=dwA[2]; pu1.w[1]=dwB[2]; pu1.w[2]=dwA[3]; pu1.w[3]=dwB[3];
            pf[u][0] = pu0.v;  pf[u][1] = pu1.v;
        }

        // PV: vf loaded ONCE per (kh,nt), feeds both q-subtiles
        __builtin_amdgcn_s_setprio(1);
        #pragma unroll
        for(int kh=0; kh<2; ++kh)
            #pragma unroll
            for(int nt=0; nt<5; ++nt){
                bf16x8 vf = *reinterpret_cast<const bf16x8*>(&Vb[(nt*16+q16)*64 + (((kh*4+g) ^ sw7)<<3)]);
                accO[0][nt] = __builtin_amdgcn_mfma_f32_16x16x32_bf16(pf[0][kh], vf, accO[0][nt], 0,0,0);
                accO[1][nt] = __builtin_amdgcn_mfma_f32_16x16x32_bf16(pf[1][kh], vf, accO[1][nt], 0,0,0);
            }
        __builtin_amdgcn_s_setprio(0);

        if(kt < 63){
            asm volatile("s_waitcnt vmcnt(0)" ::: "memory");
            __builtin_amdgcn_sched_barrier(0);
            #pragma unroll
            for(int i=0;i<3;++i) if(i<2 || tid<256){
                if(tid + i*512 < 640){
                    *reinterpret_cast<u32x4*>(&KV[cur^1][lo[i]]) = stg[i];
                } else {
                    uint2 a; a.x = stg[i].x; a.y = stg[i].y;
                    uint2 bq; bq.x = stg[i].z; bq.y = stg[i].w;
                    *reinterpret_cast<uint2*>(&KV[cur^1][lo[i]])  = a;
                    *reinterpret_cast<uint2*>(&KV[cur^1][lo2[i]]) = bq;
                }
                gp[i] += adv[i];
            }
        }
        __syncthreads();
    }

    // epilogue: accO row q' = 4g+j needs l of q' (lives at lanes with lane&15 = q')
    #pragma unroll
    for(int u=0;u<2;++u){
        float linv[4];
        #pragma unroll
        for(int j=0;j<4;++j){
            float lj = __shfl(l[u], (lane & 48) | (4*g + j), 64);
            linv[j] = 1.0f / lj;
        }
        #pragma unroll
        for(int nt=0;nt<5;++nt){
            int d = nt*16 + q16;
            if(d < HDIM){
                #pragma unroll
                for(int j=0;j<4;++j){
                    int t = qbase + u*128 + wid*16 + 4*g + j;
                    AO[((size_t)(b*TT + t))*HIDDEN + h*HDIM + d] = f2b(accO[u][nt][j] * linv[j]);
                }
            }
        }
    }
}

extern "C" void kernel_launch(void* const* d_in, const int* in_sizes, int n_in,
                              void* d_out, int out_size, void* d_ws, size_t ws_size,
                              hipStream_t stream) {
    const float* x  = (const float*)d_in[0];
    const float* wq = (const float*)d_in[1];
    const float* bq = (const float*)d_in[2];
    const float* wk = (const float*)d_in[3];
    const float* bk = (const float*)d_in[4];
    const float* wv = (const float*)d_in[5];
    const float* bv = (const float*)d_in[6];
    const float* wo = (const float*)d_in[7];
    const float* bo = (const float*)d_in[8];

    char* ws = (char*)d_ws;
    const size_t szXb = (size_t)BT*HIDDEN*2;          // 18874368
    const size_t szW  = (size_t)HIDDEN*HIDDEN*2;      // 2654208
    const size_t szQp = (size_t)NB*HEADS*TT*DPAD*2;   // 25165824

    unsigned short* Xb  = (unsigned short*)(ws);
    unsigned short* WTq = (unsigned short*)(ws + szXb);   // WTq|WTk|WTv|WTo contiguous
    unsigned short* WTo = (unsigned short*)(ws + szXb + 3*szW);
    unsigned short* Qp  = (unsigned short*)(ws + szXb + 4*szW);
    unsigned short* Kp  = (unsigned short*)(ws + szXb + 4*szW + szQp);
    unsigned short* Vt  = (unsigned short*)(ws + szXb + 4*szW + 2*szQp);
    unsigned short* AO  = (unsigned short*)(ws + szXb + 4*szW + 3*szQp);

    hipMemsetAsync(Qp, 0, 3*szQp, stream);            // zero d-padding of Q, K, V (contiguous)

    k_convert_x<<<BT*HIDDEN/1024, 256, 0, stream>>>(x, Xb);
    k_wtrans<<<1296, 256, 0, stream>>>(wq, wk, wv, wo, WTq);

    const float qscale = (1.0f / sqrtf(72.0f)) * 1.44269504f;  // fold log2(e) for exp2 softmax
    k_gemm_qkv<<<1728, 256, 0, stream>>>(Xb, WTq, bq, bk, bv, Qp, Kp, Vt, qscale);

    k_attn<<<NB*HEADS*(TT/256), 512, 0, stream>>>(Qp, Kp, Vt, AO);

    k_gemm_o<<<576, 256, 0, stream>>>(AO, WTo, bo, (float*)d_out);
}

// Round 17
// 366.107 us; speedup vs baseline: 1.6846x; 1.0296x over previous
//
#include <hip/hip_runtime.h>

#define HIDDEN 1152
#define HEADS  16
#define HDIM   72
#define DPAD   96
#define NB     2
#define TT     4096
#define BT     (NB*TT)  // 8192

#define KSTR2  80      // Ks row stride (shorts): 10 granules of 8
#define VOFF   5120    // Vs offset inside KV buffer (shorts)

typedef float  f32x4   __attribute__((ext_vector_type(4)));
typedef __bf16 bf16x8  __attribute__((ext_vector_type(8)));
typedef unsigned u32x4 __attribute__((ext_vector_type(4)));

static __device__ __forceinline__ unsigned pkbf(float a, float b){
    unsigned r;
    asm("v_cvt_pk_bf16_f32 %0, %1, %2" : "=v"(r) : "v"(a), "v"(b));
    return r;
}
static __device__ __forceinline__ unsigned short f2b(float f){
    return (unsigned short)pkbf(f, f);
}
static __device__ __forceinline__ void gld16(const unsigned short* g, unsigned short* l){
    __builtin_amdgcn_global_load_lds((const __attribute__((address_space(1))) void*)g,
                                     (__attribute__((address_space(3))) void*)l, 16, 0, 0);
}

__global__ __launch_bounds__(256) void k_convert_x(const float* __restrict__ x, unsigned short* __restrict__ xb){
    int i = (blockIdx.x*256 + threadIdx.x) * 4;
    float4 v = *reinterpret_cast<const float4*>(x + i);
    uint2 p; p.x = pkbf(v.x, v.y); p.y = pkbf(v.z, v.w);
    *reinterpret_cast<uint2*>(xb + i) = p;
}

// fused tiled transpose+convert for all 4 weights: w[k][n] (fp32) -> wt[n][k] (bf16)
__global__ __launch_bounds__(256) void k_wtrans(const float* __restrict__ wq, const float* __restrict__ wk,
                                                const float* __restrict__ wv, const float* __restrict__ wo,
                                                unsigned short* __restrict__ wt0){
    __shared__ __align__(16) unsigned short Ws[64][72];
    const int wi = blockIdx.x / 324, bi = blockIdx.x % 324;
    const float* w = wi==0 ? wq : (wi==1 ? wk : (wi==2 ? wv : wo));
    unsigned short* wt = wt0 + (size_t)wi*HIDDEN*HIDDEN;
    const int r0 = (bi / 18) * 64, c0 = (bi % 18) * 64;
    #pragma unroll
    for(int it=0; it<4; ++it){
        int idx = threadIdx.x + it*256;
        int r = idx >> 4, cq = (idx & 15) * 4;
        float4 v = *reinterpret_cast<const float4*>(w + (size_t)(r0+r)*HIDDEN + c0 + cq);
        uint2 p; p.x = pkbf(v.x, v.y); p.y = pkbf(v.z, v.w);
        *reinterpret_cast<uint2*>(&Ws[r][cq]) = p;
    }
    __syncthreads();
    #pragma unroll
    for(int it=0; it<4; ++it){
        int idx = threadIdx.x + it*256;
        int rr = idx >> 4, cq = (idx & 15) * 4;
        ushort4 o;
        o.x = Ws[cq+0][rr]; o.y = Ws[cq+1][rr]; o.z = Ws[cq+2][rr]; o.w = Ws[cq+3][rr];
        *reinterpret_cast<ushort4*>(wt + (size_t)(c0+rr)*HIDDEN + r0 + cq) = o;
    }
}

// Fused QKV GEMM: A = Xb [8192][1152], B^T = WT [3456][1152] (WTq|WTk|WTv contiguous).
// which = block-uniform 0/1/2; V epilogue transposes through LDS for coalesced [d][t] writes.
__global__ __launch_bounds__(256, 3) void k_gemm_qkv(const unsigned short* __restrict__ A,
                                                     const unsigned short* __restrict__ WT,
                                                     const float* __restrict__ bq,
                                                     const float* __restrict__ bk,
                                                     const float* __restrict__ bv,
                                                     unsigned short* __restrict__ Qp,
                                                     unsigned short* __restrict__ Kp,
                                                     unsigned short* __restrict__ Vt,
                                                     float qscale){
    __shared__ __align__(16) unsigned short S[8192];          // As|Bs in K-loop; V-transpose tile after
    unsigned short* As = S;
    unsigned short* Bs = S + 4096;
    const int tid = threadIdx.x, lane = tid & 63, wid = tid >> 6;
    const int wm = wid >> 1, wn = wid & 1;
    const int half = lane >> 4, q16 = lane & 15;
    int lb = (blockIdx.x & 7) * 216 + (blockIdx.x >> 3);      // XCD-chunked swizzle (1728 = 8*216)
    const int m0 = (lb / 27) * 128;
    const int t9 = lb % 27;
    const int which = t9 / 9;                                  // 0=Q 1=K 2=V (block-uniform)
    const int n0g = t9 * 128;                                  // global col in [0,3456)
    const int cc0 = (t9 % 9) * 128;                            // col within 1152
    const float* bias = which==0 ? bq : (which==1 ? bk : bv);
    const float scale = which==0 ? qscale : 1.0f;
    const int lr = lane >> 2, lc = (lane & 3) * 8;
    const unsigned short* ap = A  + (size_t)(m0  + wid*32 + lr)*HIDDEN + lc;
    const unsigned short* bp = WT + (size_t)(n0g + wid*32 + lr)*HIDDEN + lc;
    unsigned short* as0 = As + (wid*32     )*32 + lane*8;
    unsigned short* as1 = As + (wid*32 + 16)*32 + lane*8;
    unsigned short* bs0 = Bs + (wid*32     )*32 + lane*8;
    unsigned short* bs1 = Bs + (wid*32 + 16)*32 + lane*8;

    f32x4 acc[4][4] = {};
    for(int k0 = 0; k0 < HIDDEN; k0 += 32){
        gld16(ap + k0,             as0);
        gld16(ap + k0 + 16*HIDDEN, as1);
        gld16(bp + k0,             bs0);
        gld16(bp + k0 + 16*HIDDEN, bs1);
        __syncthreads();
        bf16x8 af[4], bf[4];
        #pragma unroll
        for(int mi=0;mi<4;++mi) af[mi] = *reinterpret_cast<const bf16x8*>(As + (wm*64+mi*16+q16)*32 + half*8);
        #pragma unroll
        for(int ni=0;ni<4;++ni) bf[ni] = *reinterpret_cast<const bf16x8*>(Bs + (wn*64+ni*16+q16)*32 + half*8);
        #pragma unroll
        for(int mi=0;mi<4;++mi)
            #pragma unroll
            for(int ni=0;ni<4;++ni)
                acc[mi][ni] = __builtin_amdgcn_mfma_f32_16x16x32_bf16(af[mi], bf[ni], acc[mi][ni], 0,0,0);
        __syncthreads();
    }
    if(which < 2){
        unsigned short* outp = which==0 ? Qp : Kp;
        #pragma unroll
        for(int mi=0;mi<4;++mi)
            #pragma unroll
            for(int ni=0;ni<4;++ni)
                #pragma unroll
                for(int j=0;j<4;++j){
                    int row = m0 + wm*64 + mi*16 + half*4 + j;
                    int col = cc0 + wn*64 + ni*16 + q16;
                    float v = (acc[mi][ni][j] + bias[col]) * scale;
                    int bb = row >> 12, t = row & 4095;
                    int hh = col / HDIM, d = col % HDIM;
                    outp[((size_t)((bb*HEADS + hh)*TT) + t)*DPAD + d] = f2b(v);
                }
    } else {
        // V: transpose 128x128 tile through LDS (two 64-row passes) for coalesced [d][t] stores
        #pragma unroll
        for(int ph=0; ph<2; ++ph){
            if(wm == ph){
                #pragma unroll
                for(int mi=0;mi<4;++mi)
                    #pragma unroll
                    for(int ni=0;ni<4;++ni)
                        #pragma unroll
                        for(int j=0;j<4;++j){
                            int rloc = mi*16 + half*4 + j;            // 0..63 within this row-half
                            int cloc = wn*64 + ni*16 + q16;           // 0..127
                            float v = acc[mi][ni][j] + bias[cc0 + cloc];
                            S[cloc*64 + (rloc ^ ((cloc&7)<<3))] = f2b(v);
                        }
            }
            __syncthreads();
            {
                int col = tid >> 1, seg = tid & 1;
                int gcol = cc0 + col, hh = gcol / HDIM, d = gcol % HDIM;
                int grow = m0 + ph*64 + seg*32;
                int bb = grow >> 12, t0 = grow & 4095;
                unsigned short* dst = Vt + ((size_t)((bb*HEADS + hh)*DPAD) + d)*TT + t0;
                #pragma unroll
                for(int kg=0; kg<4; ++kg){
                    uint4 v = *reinterpret_cast<const uint4*>(&S[col*64 + ((seg*32 + kg*8) ^ ((col&7)<<3))]);
                    *reinterpret_cast<uint4*>(dst + kg*8) = v;
                }
            }
            __syncthreads();
        }
    }
}

// O-projection GEMM: fp32 out + bias
__global__ __launch_bounds__(256, 3) void k_gemm_o(const unsigned short* __restrict__ A,
                                                   const unsigned short* __restrict__ Bt,
                                                   const float* __restrict__ bias,
                                                   float* __restrict__ out){
    __shared__ __align__(16) unsigned short As[128*32];
    __shared__ __align__(16) unsigned short Bs[128*32];
    const int tid = threadIdx.x, lane = tid & 63, wid = tid >> 6;
    const int wm = wid >> 1, wn = wid & 1;
    const int half = lane >> 4, q16 = lane & 15;
    int lb = (blockIdx.x & 7) * 72 + (blockIdx.x >> 3);       // XCD-chunked swizzle (576 = 8*72)
    const int n0 = (lb % 9) * 128, m0 = (lb / 9) * 128;
    const int lr = lane >> 2, lc = (lane & 3) * 8;
    const unsigned short* ap = A  + (size_t)(m0 + wid*32 + lr)*HIDDEN + lc;
    const unsigned short* bp = Bt + (size_t)(n0 + wid*32 + lr)*HIDDEN + lc;
    unsigned short* as0 = As + (wid*32     )*32 + lane*8;
    unsigned short* as1 = As + (wid*32 + 16)*32 + lane*8;
    unsigned short* bs0 = Bs + (wid*32     )*32 + lane*8;
    unsigned short* bs1 = Bs + (wid*32 + 16)*32 + lane*8;

    f32x4 acc[4][4] = {};
    for(int k0 = 0; k0 < HIDDEN; k0 += 32){
        gld16(ap + k0,             as0);
        gld16(ap + k0 + 16*HIDDEN, as1);
        gld16(bp + k0,             bs0);
        gld16(bp + k0 + 16*HIDDEN, bs1);
        __syncthreads();
        bf16x8 af[4], bf[4];
        #pragma unroll
        for(int mi=0;mi<4;++mi) af[mi] = *reinterpret_cast<const bf16x8*>(As + (wm*64+mi*16+q16)*32 + half*8);
        #pragma unroll
        for(int ni=0;ni<4;++ni) bf[ni] = *reinterpret_cast<const bf16x8*>(Bs + (wn*64+ni*16+q16)*32 + half*8);
        #pragma unroll
        for(int mi=0;mi<4;++mi)
            #pragma unroll
            for(int ni=0;ni<4;++ni)
                acc[mi][ni] = __builtin_amdgcn_mfma_f32_16x16x32_bf16(af[mi], bf[ni], acc[mi][ni], 0,0,0);
        __syncthreads();
    }
    #pragma unroll
    for(int mi=0;mi<4;++mi)
        #pragma unroll
        for(int ni=0;ni<4;++ni)
            #pragma unroll
            for(int j=0;j<4;++j){
                int row = m0 + wm*64 + mi*16 + half*4 + j;
                int col = n0 + wn*64 + ni*16 + q16;
                out[(size_t)row*HIDDEN + col] = acc[mi][ni][j] + bias[col];
            }
}

// flash attention: swapped QK^T 16x16 core, asm-pinned async staging, 1 barrier/iter.
// Zero-shuffle PV via sigma-permuted V columns. R17: max-reduce shuffles moved inside the
// rare rescale branch (ballot-implied max), l kept as per-lane partial (epilogue reduce).
__global__ __launch_bounds__(512, 2) void k_attn(const unsigned short* __restrict__ Qp,
                                                 const unsigned short* __restrict__ Kp,
                                                 const unsigned short* __restrict__ Vt,
                                                 unsigned short* __restrict__ AO){
    __shared__ __align__(16) unsigned short KV[2][10240];   // [K 64x80 | V 80x64] per buf = 40 KB total
    const int tid  = threadIdx.x;
    const int lane = tid & 63, wid = tid >> 6;              // wid in [0,8)
    const int g    = lane >> 4, q16 = lane & 15;
    const int sw7  = q16 & 7;

    int lb = ((blockIdx.x & 7) << 6) | (blockIdx.x >> 3);   // XCD-chunked (512 = 8*64)
    const int qt = lb & 15, h = (lb >> 4) & 15, b = lb >> 8;
    const int qbase = qt * 256;
    const int bh = b*HEADS + h;

    const unsigned short* kbase = Kp + (size_t)(bh*TT) * DPAD;
    const unsigned short* vbase = Vt + (size_t)(bh*DPAD) * TT;

    // per-thread staging slots: 1280 chunks over 512 threads (3rd iter: tid<256 only, wave-uniform)
    const unsigned short* gp[3]; int lo[3], lo2[3], adv[3];
    #pragma unroll
    for(int i=0;i<3;++i){
        int c = tid + i*512; if(c > 1279) c = 1279;          // clamped; guarded at use
        if(c < 640){
            int r = c/10, ch = c - r*10;
            int phys = (ch < 8) ? (ch ^ (r&7)) : (8 + ((ch&1) ^ (r&1)));
            lo[i]  = r*KSTR2 + (phys<<3);
            lo2[i] = lo[i];
            gp[i]  = kbase + (size_t)r*DPAD + ch*8;
            adv[i] = 64*DPAD;
        } else {
            int c2 = c - 640, d = c2>>3, ch = c2&7;
            int kh = ch>>2, thi = (ch>>1)&1, g0 = 4*kh + 2*(ch&1);
            lo[i]  = VOFF + d*64 + (((g0  ) ^ (d&7))<<3) + 4*thi;   // kv pairs (w=0..3)
            lo2[i] = VOFF + d*64 + (((g0+1) ^ (d&7))<<3) + 4*thi;   // kv pairs (w=4..7)
            gp[i]  = vbase + (size_t)d*TT + ch*8;
            adv[i] = 64;
        }
    }

    // Q fragments: 2 q-subtiles x 16 rows per wave; B-operand row q=q16, k-slot g*8+e
    bf16x8 qf[2][3];
    #pragma unroll
    for(int u=0;u<2;++u){
        const unsigned short* qptr = Qp + ((size_t)(bh*TT) + qbase + u*128 + wid*16 + q16) * DPAD;
        #pragma unroll
        for(int kk=0;kk<3;++kk) qf[u][kk] = *reinterpret_cast<const bf16x8*>(qptr + kk*32 + g*8);
    }

    f32x4 accO[2][5] = {};
    float m[2] = {-1e30f, -1e30f};
    float l[2] = {0.f, 0.f};                                // per-lane PARTIAL sums (epilogue reduce)

    // prologue: stage tile 0 into buf 0
    u32x4 stg[3];
    #pragma unroll
    for(int i=0;i<3;++i) if(i<2 || tid<256) stg[i] = *reinterpret_cast<const u32x4*>(gp[i]);
    #pragma unroll
    for(int i=0;i<3;++i) if(i<2 || tid<256){
        if(tid + i*512 < 640){
            *reinterpret_cast<u32x4*>(&KV[0][lo[i]]) = stg[i];
        } else {
            uint2 a; a.x = stg[i].x; a.y = stg[i].y;
            uint2 bq; bq.x = stg[i].z; bq.y = stg[i].w;
            *reinterpret_cast<uint2*>(&KV[0][lo[i]])  = a;
            *reinterpret_cast<uint2*>(&KV[0][lo2[i]]) = bq;
        }
        gp[i] += adv[i];
    }
    __syncthreads();

    for(int kt = 0; kt < 64; ++kt){
        const int cur = kt & 1;
        if(kt < 63){
            #pragma unroll
            for(int i=0;i<3;++i) if(i<2 || tid<256)
                asm volatile("global_load_dwordx4 %0, %1, off"
                             : "=v"(stg[i]) : "v"(gp[i]) : "memory");
        }
        const unsigned short* Kb = KV[cur];
        const unsigned short* Vb = KV[cur] + VOFF;

        // S^T[kv][q] = mfma(A=K, B=Q): lane holds col q=q16, rows kv = 16t + 4g + j
        f32x4 s[2][4] = {};
        __builtin_amdgcn_s_setprio(1);
        #pragma unroll
        for(int t=0;t<4;++t){
            const int row = t*16 + q16;
            bf16x8 kf0 = *reinterpret_cast<const bf16x8*>(&Kb[row*KSTR2 + ((g     ^ sw7)<<3)]);
            bf16x8 kf1 = *reinterpret_cast<const bf16x8*>(&Kb[row*KSTR2 + (((4+g) ^ sw7)<<3)]);
            bf16x8 kf2 = *reinterpret_cast<const bf16x8*>(&Kb[row*KSTR2 + ((8 + ((g&1) ^ (row&1)))<<3)]);
            s[0][t] = __builtin_amdgcn_mfma_f32_16x16x32_bf16(kf0, qf[0][0], s[0][t], 0,0,0);
            s[1][t] = __builtin_amdgcn_mfma_f32_16x16x32_bf16(kf0, qf[1][0], s[1][t], 0,0,0);
            s[0][t] = __builtin_amdgcn_mfma_f32_16x16x32_bf16(kf1, qf[0][1], s[0][t], 0,0,0);
            s[1][t] = __builtin_amdgcn_mfma_f32_16x16x32_bf16(kf1, qf[1][1], s[1][t], 0,0,0);
            s[0][t] = __builtin_amdgcn_mfma_f32_16x16x32_bf16(kf2, qf[0][2], s[0][t], 0,0,0);
            s[1][t] = __builtin_amdgcn_mfma_f32_16x16x32_bf16(kf2, qf[1][2], s[1][t], 0,0,0);
        }
        __builtin_amdgcn_s_setprio(0);

        bf16x8 pf[2][2];
        #pragma unroll
        for(int u=0;u<2;++u){
            // per-lane max over this lane's 16 kv; NO shuffles in the common path.
            // __any over 64 lanes makes the check equivalent to (reduced_max > m + 8).
            float tm = fmaxf(fmaxf(s[u][0][0], s[u][0][1]), s[u][0][2]);
            tm = fmaxf(fmaxf(tm, s[u][0][3]), s[u][1][0]);
            tm = fmaxf(fmaxf(tm, s[u][1][1]), s[u][1][2]);
            tm = fmaxf(fmaxf(tm, s[u][1][3]), s[u][2][0]);
            tm = fmaxf(fmaxf(tm, s[u][2][1]), s[u][2][2]);
            tm = fmaxf(fmaxf(tm, s[u][2][3]), s[u][3][0]);
            tm = fmaxf(fmaxf(tm, s[u][3][1]), s[u][3][2]);
            tm = fmaxf(tm, s[u][3][3]);
            if(__any(tm > m[u] + 8.0f)){                       // defer-max rescale (log2 domain), rare
                tm = fmaxf(tm, __shfl_xor(tm, 16, 64));        // full reduce only when rescaling
                tm = fmaxf(tm, __shfl_xor(tm, 32, 64));
                float mn = fmaxf(m[u], tm);
                float al = __builtin_amdgcn_exp2f(m[u] - mn);
                l[u] *= al;  m[u] = mn;                        // partial l scales identically
                float aj[4];
                #pragma unroll
                for(int j=0;j<4;++j) aj[j] = __shfl(al, (lane & 48) | (4*g + j), 64);
                #pragma unroll
                for(int nt=0;nt<5;++nt)
                    #pragma unroll
                    for(int j=0;j<4;++j) accO[u][nt][j] *= aj[j];
            }
            unsigned dwA[4], dwB[4];
            float sum = 0.f;
            #pragma unroll
            for(int t4=0;t4<4;++t4){
                float p0 = __builtin_amdgcn_exp2f(s[u][t4][0] - m[u]);
                float p1 = __builtin_amdgcn_exp2f(s[u][t4][1] - m[u]);
                float p2 = __builtin_amdgcn_exp2f(s[u][t4][2] - m[u]);
                float p3 = __builtin_amdgcn_exp2f(s[u][t4][3] - m[u]);
                sum += (p0 + p1) + (p2 + p3);
                dwA[t4] = pkbf(p0, p1);
                dwB[t4] = pkbf(p2, p3);
            }
            l[u] += sum;                                       // per-lane partial; reduced at epilogue
            union { unsigned w[4]; bf16x8 v; } pu0, pu1;
            pu0.w[0]=dwA[0]; pu0.w[1]=dwB[0]; pu0.w[2]=dwA[1]; pu0.w[3]=dwB[1];
            pu1.w[0]=dwA[2]; pu1.w[1]=dwB[2]; pu1.w[2]=dwA[3]; pu1.w[3]=dwB[3];
            pf[u][0] = pu0.v;  pf[u][1] = pu1.v;
        }

        // PV: vf loaded ONCE per (kh,nt), feeds both q-subtiles
        __builtin_amdgcn_s_setprio(1);
        #pragma unroll
        for(int kh=0; kh<2; ++kh)
            #pragma unroll
            for(int nt=0; nt<5; ++nt){
                bf16x8 vf = *reinterpret_cast<const bf16x8*>(&Vb[(nt*16+q16)*64 + (((kh*4+g) ^ sw7)<<3)]);
                accO[0][nt] = __builtin_amdgcn_mfma_f32_16x16x32_bf16(pf[0][kh], vf, accO[0][nt], 0,0,0);
                accO[1][nt] = __builtin_amdgcn_mfma_f32_16x16x32_bf16(pf[1][kh], vf, accO[1][nt], 0,0,0);
            }
        __builtin_amdgcn_s_setprio(0);

        if(kt < 63){
            asm volatile("s_waitcnt vmcnt(0)" ::: "memory");
            __builtin_amdgcn_sched_barrier(0);
            #pragma unroll
            for(int i=0;i<3;++i) if(i<2 || tid<256){
                if(tid + i*512 < 640){
                    *reinterpret_cast<u32x4*>(&KV[cur^1][lo[i]]) = stg[i];
                } else {
                    uint2 a; a.x = stg[i].x; a.y = stg[i].y;
                    uint2 bq; bq.x = stg[i].z; bq.y = stg[i].w;
                    *reinterpret_cast<uint2*>(&KV[cur^1][lo[i]])  = a;
                    *reinterpret_cast<uint2*>(&KV[cur^1][lo2[i]]) = bq;
                }
                gp[i] += adv[i];
            }
        }
        __syncthreads();
    }

    // epilogue: reduce per-lane partial l across the 4 lanes sharing q, then normalize
    #pragma unroll
    for(int u=0;u<2;++u){
        float lt = l[u];
        lt += __shfl_xor(lt, 16, 64);
        lt += __shfl_xor(lt, 32, 64);
        float linv[4];
        #pragma unroll
        for(int j=0;j<4;++j){
            float lj = __shfl(lt, (lane & 48) | (4*g + j), 64);
            linv[j] = 1.0f / lj;
        }
        #pragma unroll
        for(int nt=0;nt<5;++nt){
            int d = nt*16 + q16;
            if(d < HDIM){
                #pragma unroll
                for(int j=0;j<4;++j){
                    int t = qbase + u*128 + wid*16 + 4*g + j;
                    AO[((size_t)(b*TT + t))*HIDDEN + h*HDIM + d] = f2b(accO[u][nt][j] * linv[j]);
                }
            }
        }
    }
}

extern "C" void kernel_launch(void* const* d_in, const int* in_sizes, int n_in,
                              void* d_out, int out_size, void* d_ws, size_t ws_size,
                              hipStream_t stream) {
    const float* x  = (const float*)d_in[0];
    const float* wq = (const float*)d_in[1];
    const float* bq = (const float*)d_in[2];
    const float* wk = (const float*)d_in[3];
    const float* bk = (const float*)d_in[4];
    const float* wv = (const float*)d_in[5];
    const float* bv = (const float*)d_in[6];
    const float* wo = (const float*)d_in[7];
    const float* bo = (const float*)d_in[8];

    char* ws = (char*)d_ws;
    const size_t szXb = (size_t)BT*HIDDEN*2;          // 18874368
    const size_t szW  = (size_t)HIDDEN*HIDDEN*2;      // 2654208
    const size_t szQp = (size_t)NB*HEADS*TT*DPAD*2;   // 25165824

    unsigned short* Xb  = (unsigned short*)(ws);
    unsigned short* WTq = (unsigned short*)(ws + szXb);   // WTq|WTk|WTv|WTo contiguous
    unsigned short* WTo = (unsigned short*)(ws + szXb + 3*szW);
    unsigned short* Qp  = (unsigned short*)(ws + szXb + 4*szW);
    unsigned short* Kp  = (unsigned short*)(ws + szXb + 4*szW + szQp);
    unsigned short* Vt  = (unsigned short*)(ws + szXb + 4*szW + 2*szQp);
    unsigned short* AO  = (unsigned short*)(ws + szXb + 4*szW + 3*szQp);

    hipMemsetAsync(Qp, 0, 3*szQp, stream);            // zero d-padding of Q, K, V (contiguous)

    k_convert_x<<<BT*HIDDEN/1024, 256, 0, stream>>>(x, Xb);
    k_wtrans<<<1296, 256, 0, stream>>>(wq, wk, wv, wo, WTq);

    const float qscale = (1.0f / sqrtf(72.0f)) * 1.44269504f;  // fold log2(e) for exp2 softmax
    k_gemm_qkv<<<1728, 256, 0, stream>>>(Xb, WTq, bq, bk, bv, Qp, Kp, Vt, qscale);

    k_attn<<<NB*HEADS*(TT/256), 512, 0, stream>>>(Qp, Kp, Vt, AO);

    k_gemm_o<<<576, 256, 0, stream>>>(AO, WTo, bo, (float*)d_out);
}

// Round 18
// 361.043 us; speedup vs baseline: 1.7082x; 1.0140x over previous
//
#include <hip/hip_runtime.h>

#define HIDDEN 1152
#define HEADS  16
#define HDIM   72
#define DPAD   96
#define NB     2
#define TT     4096
#define BT     (NB*TT)  // 8192

#define KSTR2  80      // Ks row stride (shorts): 10 granules of 8
#define VOFF   5120    // Vs offset inside KV buffer (shorts)

typedef float  f32x4   __attribute__((ext_vector_type(4)));
typedef __bf16 bf16x8  __attribute__((ext_vector_type(8)));
typedef unsigned u32x4 __attribute__((ext_vector_type(4)));

static __device__ __forceinline__ unsigned pkbf(float a, float b){
    unsigned r;
    asm("v_cvt_pk_bf16_f32 %0, %1, %2" : "=v"(r) : "v"(a), "v"(b));
    return r;
}
static __device__ __forceinline__ unsigned short f2b(float f){
    return (unsigned short)pkbf(f, f);
}
static __device__ __forceinline__ void gld16(const unsigned short* g, unsigned short* l){
    __builtin_amdgcn_global_load_lds((const __attribute__((address_space(1))) void*)g,
                                     (__attribute__((address_space(3))) void*)l, 16, 0, 0);
}

__global__ __launch_bounds__(256) void k_convert_x(const float* __restrict__ x, unsigned short* __restrict__ xb){
    int i = (blockIdx.x*256 + threadIdx.x) * 4;
    float4 v = *reinterpret_cast<const float4*>(x + i);
    uint2 p; p.x = pkbf(v.x, v.y); p.y = pkbf(v.z, v.w);
    *reinterpret_cast<uint2*>(xb + i) = p;
}

// targeted pad-zeroing (replaces 75.5 MB memset with 6.3 MB):
// Q rows need zeros at d in [80,96) (pair with duplicated K granules in g>=2 kf2 slots);
// K rows need zeros at d in [72,80) (granule-9 reads pairing real Q values).
// V pads feed only discarded output columns -> no zeroing required.
__global__ __launch_bounds__(256) void k_padzero(unsigned short* __restrict__ Qp,
                                                 unsigned short* __restrict__ Kp){
    int row = blockIdx.x*256 + threadIdx.x;       // 131072 rows = NB*HEADS*TT
    uint4 z = {0,0,0,0};
    unsigned short* q = Qp + (size_t)row*DPAD + 80;
    *reinterpret_cast<uint4*>(q)     = z;
    *reinterpret_cast<uint4*>(q + 8) = z;
    *reinterpret_cast<uint4*>(Kp + (size_t)row*DPAD + 72) = z;
}

// fused tiled transpose+convert for all 4 weights: w[k][n] (fp32) -> wt[n][k] (bf16)
__global__ __launch_bounds__(256) void k_wtrans(const float* __restrict__ wq, const float* __restrict__ wk,
                                                const float* __restrict__ wv, const float* __restrict__ wo,
                                                unsigned short* __restrict__ wt0){
    __shared__ __align__(16) unsigned short Ws[64][72];
    const int wi = blockIdx.x / 324, bi = blockIdx.x % 324;
    const float* w = wi==0 ? wq : (wi==1 ? wk : (wi==2 ? wv : wo));
    unsigned short* wt = wt0 + (size_t)wi*HIDDEN*HIDDEN;
    const int r0 = (bi / 18) * 64, c0 = (bi % 18) * 64;
    #pragma unroll
    for(int it=0; it<4; ++it){
        int idx = threadIdx.x + it*256;
        int r = idx >> 4, cq = (idx & 15) * 4;
        float4 v = *reinterpret_cast<const float4*>(w + (size_t)(r0+r)*HIDDEN + c0 + cq);
        uint2 p; p.x = pkbf(v.x, v.y); p.y = pkbf(v.z, v.w);
        *reinterpret_cast<uint2*>(&Ws[r][cq]) = p;
    }
    __syncthreads();
    #pragma unroll
    for(int it=0; it<4; ++it){
        int idx = threadIdx.x + it*256;
        int rr = idx >> 4, cq = (idx & 15) * 4;
        ushort4 o;
        o.x = Ws[cq+0][rr]; o.y = Ws[cq+1][rr]; o.z = Ws[cq+2][rr]; o.w = Ws[cq+3][rr];
        *reinterpret_cast<ushort4*>(wt + (size_t)(c0+rr)*HIDDEN + r0 + cq) = o;
    }
}

// Fused QKV GEMM: A = Xb [8192][1152], B^T = WT [3456][1152] (WTq|WTk|WTv contiguous).
// which = block-uniform 0/1/2; V epilogue transposes through LDS for coalesced [d][t] writes.
__global__ __launch_bounds__(256, 3) void k_gemm_qkv(const unsigned short* __restrict__ A,
                                                     const unsigned short* __restrict__ WT,
                                                     const float* __restrict__ bq,
                                                     const float* __restrict__ bk,
                                                     const float* __restrict__ bv,
                                                     unsigned short* __restrict__ Qp,
                                                     unsigned short* __restrict__ Kp,
                                                     unsigned short* __restrict__ Vt,
                                                     float qscale){
    __shared__ __align__(16) unsigned short S[8192];          // As|Bs in K-loop; V-transpose tile after
    unsigned short* As = S;
    unsigned short* Bs = S + 4096;
    const int tid = threadIdx.x, lane = tid & 63, wid = tid >> 6;
    const int wm = wid >> 1, wn = wid & 1;
    const int half = lane >> 4, q16 = lane & 15;
    int lb = (blockIdx.x & 7) * 216 + (blockIdx.x >> 3);      // XCD-chunked swizzle (1728 = 8*216)
    const int m0 = (lb / 27) * 128;
    const int t9 = lb % 27;
    const int which = t9 / 9;                                  // 0=Q 1=K 2=V (block-uniform)
    const int n0g = t9 * 128;                                  // global col in [0,3456)
    const int cc0 = (t9 % 9) * 128;                            // col within 1152
    const float* bias = which==0 ? bq : (which==1 ? bk : bv);
    const float scale = which==0 ? qscale : 1.0f;
    const int lr = lane >> 2, lc = (lane & 3) * 8;
    const unsigned short* ap = A  + (size_t)(m0  + wid*32 + lr)*HIDDEN + lc;
    const unsigned short* bp = WT + (size_t)(n0g + wid*32 + lr)*HIDDEN + lc;
    unsigned short* as0 = As + (wid*32     )*32 + lane*8;
    unsigned short* as1 = As + (wid*32 + 16)*32 + lane*8;
    unsigned short* bs0 = Bs + (wid*32     )*32 + lane*8;
    unsigned short* bs1 = Bs + (wid*32 + 16)*32 + lane*8;

    f32x4 acc[4][4] = {};
    for(int k0 = 0; k0 < HIDDEN; k0 += 32){
        gld16(ap + k0,             as0);
        gld16(ap + k0 + 16*HIDDEN, as1);
        gld16(bp + k0,             bs0);
        gld16(bp + k0 + 16*HIDDEN, bs1);
        __syncthreads();
        bf16x8 af[4], bf[4];
        #pragma unroll
        for(int mi=0;mi<4;++mi) af[mi] = *reinterpret_cast<const bf16x8*>(As + (wm*64+mi*16+q16)*32 + half*8);
        #pragma unroll
        for(int ni=0;ni<4;++ni) bf[ni] = *reinterpret_cast<const bf16x8*>(Bs + (wn*64+ni*16+q16)*32 + half*8);
        #pragma unroll
        for(int mi=0;mi<4;++mi)
            #pragma unroll
            for(int ni=0;ni<4;++ni)
                acc[mi][ni] = __builtin_amdgcn_mfma_f32_16x16x32_bf16(af[mi], bf[ni], acc[mi][ni], 0,0,0);
        __syncthreads();
    }
    if(which < 2){
        unsigned short* outp = which==0 ? Qp : Kp;
        #pragma unroll
        for(int mi=0;mi<4;++mi)
            #pragma unroll
            for(int ni=0;ni<4;++ni)
                #pragma unroll
                for(int j=0;j<4;++j){
                    int row = m0 + wm*64 + mi*16 + half*4 + j;
                    int col = cc0 + wn*64 + ni*16 + q16;
                    float v = (acc[mi][ni][j] + bias[col]) * scale;
                    int bb = row >> 12, t = row & 4095;
                    int hh = col / HDIM, d = col % HDIM;
                    outp[((size_t)((bb*HEADS + hh)*TT) + t)*DPAD + d] = f2b(v);
                }
    } else {
        // V: transpose 128x128 tile through LDS (two 64-row passes) for coalesced [d][t] stores
        #pragma unroll
        for(int ph=0; ph<2; ++ph){
            if(wm == ph){
                #pragma unroll
                for(int mi=0;mi<4;++mi)
                    #pragma unroll
                    for(int ni=0;ni<4;++ni)
                        #pragma unroll
                        for(int j=0;j<4;++j){
                            int rloc = mi*16 + half*4 + j;            // 0..63 within this row-half
                            int cloc = wn*64 + ni*16 + q16;           // 0..127
                            float v = acc[mi][ni][j] + bias[cc0 + cloc];
                            S[cloc*64 + (rloc ^ ((cloc&7)<<3))] = f2b(v);
                        }
            }
            __syncthreads();
            {
                int col = tid >> 1, seg = tid & 1;
                int gcol = cc0 + col, hh = gcol / HDIM, d = gcol % HDIM;
                int grow = m0 + ph*64 + seg*32;
                int bb = grow >> 12, t0 = grow & 4095;
                unsigned short* dst = Vt + ((size_t)((bb*HEADS + hh)*DPAD) + d)*TT + t0;
                #pragma unroll
                for(int kg=0; kg<4; ++kg){
                    uint4 v = *reinterpret_cast<const uint4*>(&S[col*64 + ((seg*32 + kg*8) ^ ((col&7)<<3))]);
                    *reinterpret_cast<uint4*>(dst + kg*8) = v;
                }
            }
            __syncthreads();
        }
    }
}

// O-projection GEMM: fp32 out + bias
__global__ __launch_bounds__(256, 3) void k_gemm_o(const unsigned short* __restrict__ A,
                                                   const unsigned short* __restrict__ Bt,
                                                   const float* __restrict__ bias,
                                                   float* __restrict__ out){
    __shared__ __align__(16) unsigned short As[128*32];
    __shared__ __align__(16) unsigned short Bs[128*32];
    const int tid = threadIdx.x, lane = tid & 63, wid = tid >> 6;
    const int wm = wid >> 1, wn = wid & 1;
    const int half = lane >> 4, q16 = lane & 15;
    int lb = (blockIdx.x & 7) * 72 + (blockIdx.x >> 3);       // XCD-chunked swizzle (576 = 8*72)
    const int n0 = (lb % 9) * 128, m0 = (lb / 9) * 128;
    const int lr = lane >> 2, lc = (lane & 3) * 8;
    const unsigned short* ap = A  + (size_t)(m0 + wid*32 + lr)*HIDDEN + lc;
    const unsigned short* bp = Bt + (size_t)(n0 + wid*32 + lr)*HIDDEN + lc;
    unsigned short* as0 = As + (wid*32     )*32 + lane*8;
    unsigned short* as1 = As + (wid*32 + 16)*32 + lane*8;
    unsigned short* bs0 = Bs + (wid*32     )*32 + lane*8;
    unsigned short* bs1 = Bs + (wid*32 + 16)*32 + lane*8;

    f32x4 acc[4][4] = {};
    for(int k0 = 0; k0 < HIDDEN; k0 += 32){
        gld16(ap + k0,             as0);
        gld16(ap + k0 + 16*HIDDEN, as1);
        gld16(bp + k0,             bs0);
        gld16(bp + k0 + 16*HIDDEN, bs1);
        __syncthreads();
        bf16x8 af[4], bf[4];
        #pragma unroll
        for(int mi=0;mi<4;++mi) af[mi] = *reinterpret_cast<const bf16x8*>(As + (wm*64+mi*16+q16)*32 + half*8);
        #pragma unroll
        for(int ni=0;ni<4;++ni) bf[ni] = *reinterpret_cast<const bf16x8*>(Bs + (wn*64+ni*16+q16)*32 + half*8);
        #pragma unroll
        for(int mi=0;mi<4;++mi)
            #pragma unroll
            for(int ni=0;ni<4;++ni)
                acc[mi][ni] = __builtin_amdgcn_mfma_f32_16x16x32_bf16(af[mi], bf[ni], acc[mi][ni], 0,0,0);
        __syncthreads();
    }
    #pragma unroll
    for(int mi=0;mi<4;++mi)
        #pragma unroll
        for(int ni=0;ni<4;++ni)
            #pragma unroll
            for(int j=0;j<4;++j){
                int row = m0 + wm*64 + mi*16 + half*4 + j;
                int col = n0 + wn*64 + ni*16 + q16;
                out[(size_t)row*HIDDEN + col] = acc[mi][ni][j] + bias[col];
            }
}

// flash attention: swapped QK^T 16x16 core, asm-pinned async staging, 1 barrier/iter.
// Zero-shuffle PV via sigma-permuted V columns; branch-gated max-reduce, partial-l epilogue reduce.
__global__ __launch_bounds__(512, 2) void k_attn(const unsigned short* __restrict__ Qp,
                                                 const unsigned short* __restrict__ Kp,
                                                 const unsigned short* __restrict__ Vt,
                                                 unsigned short* __restrict__ AO){
    __shared__ __align__(16) unsigned short KV[2][10240];   // [K 64x80 | V 80x64] per buf = 40 KB total
    const int tid  = threadIdx.x;
    const int lane = tid & 63, wid = tid >> 6;              // wid in [0,8)
    const int g    = lane >> 4, q16 = lane & 15;
    const int sw7  = q16 & 7;

    int lb = ((blockIdx.x & 7) << 6) | (blockIdx.x >> 3);   // XCD-chunked (512 = 8*64)
    const int qt = lb & 15, h = (lb >> 4) & 15, b = lb >> 8;
    const int qbase = qt * 256;
    const int bh = b*HEADS + h;

    const unsigned short* kbase = Kp + (size_t)(bh*TT) * DPAD;
    const unsigned short* vbase = Vt + (size_t)(bh*DPAD) * TT;

    // per-thread staging slots: 1280 chunks over 512 threads (3rd iter: tid<256 only, wave-uniform)
    const unsigned short* gp[3]; int lo[3], lo2[3], adv[3];
    #pragma unroll
    for(int i=0;i<3;++i){
        int c = tid + i*512; if(c > 1279) c = 1279;          // clamped; guarded at use
        if(c < 640){
            int r = c/10, ch = c - r*10;
            int phys = (ch < 8) ? (ch ^ (r&7)) : (8 + ((ch&1) ^ (r&1)));
            lo[i]  = r*KSTR2 + (phys<<3);
            lo2[i] = lo[i];
            gp[i]  = kbase + (size_t)r*DPAD + ch*8;
            adv[i] = 64*DPAD;
        } else {
            int c2 = c - 640, d = c2>>3, ch = c2&7;
            int kh = ch>>2, thi = (ch>>1)&1, g0 = 4*kh + 2*(ch&1);
            lo[i]  = VOFF + d*64 + (((g0  ) ^ (d&7))<<3) + 4*thi;   // kv pairs (w=0..3)
            lo2[i] = VOFF + d*64 + (((g0+1) ^ (d&7))<<3) + 4*thi;   // kv pairs (w=4..7)
            gp[i]  = vbase + (size_t)d*TT + ch*8;
            adv[i] = 64;
        }
    }

    // Q fragments: 2 q-subtiles x 16 rows per wave; B-operand row q=q16, k-slot g*8+e
    bf16x8 qf[2][3];
    #pragma unroll
    for(int u=0;u<2;++u){
        const unsigned short* qptr = Qp + ((size_t)(bh*TT) + qbase + u*128 + wid*16 + q16) * DPAD;
        #pragma unroll
        for(int kk=0;kk<3;++kk) qf[u][kk] = *reinterpret_cast<const bf16x8*>(qptr + kk*32 + g*8);
    }

    f32x4 accO[2][5] = {};
    float m[2] = {-1e30f, -1e30f};
    float l[2] = {0.f, 0.f};                                // per-lane PARTIAL sums (epilogue reduce)

    // prologue: stage tile 0 into buf 0
    u32x4 stg[3];
    #pragma unroll
    for(int i=0;i<3;++i) if(i<2 || tid<256) stg[i] = *reinterpret_cast<const u32x4*>(gp[i]);
    #pragma unroll
    for(int i=0;i<3;++i) if(i<2 || tid<256){
        if(tid + i*512 < 640){
            *reinterpret_cast<u32x4*>(&KV[0][lo[i]]) = stg[i];
        } else {
            uint2 a; a.x = stg[i].x; a.y = stg[i].y;
            uint2 bq; bq.x = stg[i].z; bq.y = stg[i].w;
            *reinterpret_cast<uint2*>(&KV[0][lo[i]])  = a;
            *reinterpret_cast<uint2*>(&KV[0][lo2[i]]) = bq;
        }
        gp[i] += adv[i];
    }
    __syncthreads();

    for(int kt = 0; kt < 64; ++kt){
        const int cur = kt & 1;
        if(kt < 63){
            #pragma unroll
            for(int i=0;i<3;++i) if(i<2 || tid<256)
                asm volatile("global_load_dwordx4 %0, %1, off"
                             : "=v"(stg[i]) : "v"(gp[i]) : "memory");
        }
        const unsigned short* Kb = KV[cur];
        const unsigned short* Vb = KV[cur] + VOFF;

        // S^T[kv][q] = mfma(A=K, B=Q): lane holds col q=q16, rows kv = 16t + 4g + j
        f32x4 s[2][4] = {};
        __builtin_amdgcn_s_setprio(1);
        #pragma unroll
        for(int t=0;t<4;++t){
            const int row = t*16 + q16;
            bf16x8 kf0 = *reinterpret_cast<const bf16x8*>(&Kb[row*KSTR2 + ((g     ^ sw7)<<3)]);
            bf16x8 kf1 = *reinterpret_cast<const bf16x8*>(&Kb[row*KSTR2 + (((4+g) ^ sw7)<<3)]);
            bf16x8 kf2 = *reinterpret_cast<const bf16x8*>(&Kb[row*KSTR2 + ((8 + ((g&1) ^ (row&1)))<<3)]);
            s[0][t] = __builtin_amdgcn_mfma_f32_16x16x32_bf16(kf0, qf[0][0], s[0][t], 0,0,0);
            s[1][t] = __builtin_amdgcn_mfma_f32_16x16x32_bf16(kf0, qf[1][0], s[1][t], 0,0,0);
            s[0][t] = __builtin_amdgcn_mfma_f32_16x16x32_bf16(kf1, qf[0][1], s[0][t], 0,0,0);
            s[1][t] = __builtin_amdgcn_mfma_f32_16x16x32_bf16(kf1, qf[1][1], s[1][t], 0,0,0);
            s[0][t] = __builtin_amdgcn_mfma_f32_16x16x32_bf16(kf2, qf[0][2], s[0][t], 0,0,0);
            s[1][t] = __builtin_amdgcn_mfma_f32_16x16x32_bf16(kf2, qf[1][2], s[1][t], 0,0,0);
        }
        __builtin_amdgcn_s_setprio(0);

        bf16x8 pf[2][2];
        #pragma unroll
        for(int u=0;u<2;++u){
            // per-lane max over this lane's 16 kv; NO shuffles in the common path.
            // __any over 64 lanes makes the check equivalent to (reduced_max > m + 8).
            float tm = fmaxf(fmaxf(s[u][0][0], s[u][0][1]), s[u][0][2]);
            tm = fmaxf(fmaxf(tm, s[u][0][3]), s[u][1][0]);
            tm = fmaxf(fmaxf(tm, s[u][1][1]), s[u][1][2]);
            tm = fmaxf(fmaxf(tm, s[u][1][3]), s[u][2][0]);
            tm = fmaxf(fmaxf(tm, s[u][2][1]), s[u][2][2]);
            tm = fmaxf(fmaxf(tm, s[u][2][3]), s[u][3][0]);
            tm = fmaxf(fmaxf(tm, s[u][3][1]), s[u][3][2]);
            tm = fmaxf(tm, s[u][3][3]);
            if(__any(tm > m[u] + 8.0f)){                       // defer-max rescale (log2 domain), rare
                tm = fmaxf(tm, __shfl_xor(tm, 16, 64));        // full reduce only when rescaling
                tm = fmaxf(tm, __shfl_xor(tm, 32, 64));
                float mn = fmaxf(m[u], tm);
                float al = __builtin_amdgcn_exp2f(m[u] - mn);
                l[u] *= al;  m[u] = mn;                        // partial l scales identically
                float aj[4];
                #pragma unroll
                for(int j=0;j<4;++j) aj[j] = __shfl(al, (lane & 48) | (4*g + j), 64);
                #pragma unroll
                for(int nt=0;nt<5;++nt)
                    #pragma unroll
                    for(int j=0;j<4;++j) accO[u][nt][j] *= aj[j];
            }
            unsigned dwA[4], dwB[4];
            float sum = 0.f;
            #pragma unroll
            for(int t4=0;t4<4;++t4){
                float p0 = __builtin_amdgcn_exp2f(s[u][t4][0] - m[u]);
                float p1 = __builtin_amdgcn_exp2f(s[u][t4][1] - m[u]);
                float p2 = __builtin_amdgcn_exp2f(s[u][t4][2] - m[u]);
                float p3 = __builtin_amdgcn_exp2f(s[u][t4][3] - m[u]);
                sum += (p0 + p1) + (p2 + p3);
                dwA[t4] = pkbf(p0, p1);
                dwB[t4] = pkbf(p2, p3);
            }
            l[u] += sum;                                       // per-lane partial; reduced at epilogue
            union { unsigned w[4]; bf16x8 v; } pu0, pu1;
            pu0.w[0]=dwA[0]; pu0.w[1]=dwB[0]; pu0.w[2]=dwA[1]; pu0.w[3]=dwB[1];
            pu1.w[0]=dwA[2]; pu1.w[1]=dwB[2]; pu1.w[2]=dwA[3]; pu1.w[3]=dwB[3];
            pf[u][0] = pu0.v;  pf[u][1] = pu1.v;
        }

        // PV: vf loaded ONCE per (kh,nt), feeds both q-subtiles
        __builtin_amdgcn_s_setprio(1);
        #pragma unroll
        for(int kh=0; kh<2; ++kh)
            #pragma unroll
            for(int nt=0; nt<5; ++nt){
                bf16x8 vf = *reinterpret_cast<const bf16x8*>(&Vb[(nt*16+q16)*64 + (((kh*4+g) ^ sw7)<<3)]);
                accO[0][nt] = __builtin_amdgcn_mfma_f32_16x16x32_bf16(pf[0][kh], vf, accO[0][nt], 0,0,0);
                accO[1][nt] = __builtin_amdgcn_mfma_f32_16x16x32_bf16(pf[1][kh], vf, accO[1][nt], 0,0,0);
            }
        __builtin_amdgcn_s_setprio(0);

        if(kt < 63){
            asm volatile("s_waitcnt vmcnt(0)" ::: "memory");
            __builtin_amdgcn_sched_barrier(0);
            #pragma unroll
            for(int i=0;i<3;++i) if(i<2 || tid<256){
                if(tid + i*512 < 640){
                    *reinterpret_cast<u32x4*>(&KV[cur^1][lo[i]]) = stg[i];
                } else {
                    uint2 a; a.x = stg[i].x; a.y = stg[i].y;
                    uint2 bq; bq.x = stg[i].z; bq.y = stg[i].w;
                    *reinterpret_cast<uint2*>(&KV[cur^1][lo[i]])  = a;
                    *reinterpret_cast<uint2*>(&KV[cur^1][lo2[i]]) = bq;
                }
                gp[i] += adv[i];
            }
        }
        __syncthreads();
    }

    // epilogue: reduce per-lane partial l across the 4 lanes sharing q, then normalize
    #pragma unroll
    for(int u=0;u<2;++u){
        float lt = l[u];
        lt += __shfl_xor(lt, 16, 64);
        lt += __shfl_xor(lt, 32, 64);
        float linv[4];
        #pragma unroll
        for(int j=0;j<4;++j){
            float lj = __shfl(lt, (lane & 48) | (4*g + j), 64);
            linv[j] = 1.0f / lj;
        }
        #pragma unroll
        for(int nt=0;nt<5;++nt){
            int d = nt*16 + q16;
            if(d < HDIM){
                #pragma unroll
                for(int j=0;j<4;++j){
                    int t = qbase + u*128 + wid*16 + 4*g + j;
                    AO[((size_t)(b*TT + t))*HIDDEN + h*HDIM + d] = f2b(accO[u][nt][j] * linv[j]);
                }
            }
        }
    }
}

extern "C" void kernel_launch(void* const* d_in, const int* in_sizes, int n_in,
                              void* d_out, int out_size, void* d_ws, size_t ws_size,
                              hipStream_t stream) {
    const float* x  = (const float*)d_in[0];
    const float* wq = (const float*)d_in[1];
    const float* bq = (const float*)d_in[2];
    const float* wk = (const float*)d_in[3];
    const float* bk = (const float*)d_in[4];
    const float* wv = (const float*)d_in[5];
    const float* bv = (const float*)d_in[6];
    const float* wo = (const float*)d_in[7];
    const float* bo = (const float*)d_in[8];

    char* ws = (char*)d_ws;
    const size_t szXb = (size_t)BT*HIDDEN*2;          // 18874368
    const size_t szW  = (size_t)HIDDEN*HIDDEN*2;      // 2654208
    const size_t szQp = (size_t)NB*HEADS*TT*DPAD*2;   // 25165824

    unsigned short* Xb  = (unsigned short*)(ws);
    unsigned short* WTq = (unsigned short*)(ws + szXb);   // WTq|WTk|WTv|WTo contiguous
    unsigned short* WTo = (unsigned short*)(ws + szXb + 3*szW);
    unsigned short* Qp  = (unsigned short*)(ws + szXb + 4*szW);
    unsigned short* Kp  = (unsigned short*)(ws + szXb + 4*szW + szQp);
    unsigned short* Vt  = (unsigned short*)(ws + szXb + 4*szW + 2*szQp);
    unsigned short* AO  = (unsigned short*)(ws + szXb + 4*szW + 3*szQp);

    k_convert_x<<<BT*HIDDEN/1024, 256, 0, stream>>>(x, Xb);
    k_padzero<<<512, 256, 0, stream>>>(Qp, Kp);       // targeted pad zeros (replaces 75 MB memset)
    k_wtrans<<<1296, 256, 0, stream>>>(wq, wk, wv, wo, WTq);

    const float qscale = (1.0f / sqrtf(72.0f)) * 1.44269504f;  // fold log2(e) for exp2 softmax
    k_gemm_qkv<<<1728, 256, 0, stream>>>(Xb, WTq, bq, bk, bv, Qp, Kp, Vt, qscale);

    k_attn<<<NB*HEADS*(TT/256), 512, 0, stream>>>(Qp, Kp, Vt, AO);

    k_gemm_o<<<576, 256, 0, stream>>>(AO, WTo, bo, (float*)d_out);
}